// Round 12
// baseline (308.960 us; speedup 1.0000x reference)
//
#include <hip/hip_runtime.h>
#include <hip/hip_bf16.h>

#define BATCH 32768
#define NELEM 65536   // 2 * BATCH
#define FSTRIDE 584   // feat row stride (578 cols + 6 zeroed pad cols)

typedef unsigned short u16;
typedef unsigned int u32;
typedef __attribute__((ext_vector_type(8))) short bf16x8;
typedef __attribute__((ext_vector_type(4))) float f32x4;

__device__ __forceinline__ float bf2f(u16 u) {
    union { u32 u; float f; } c; c.u = ((u32)u) << 16; return c.f;
}
__device__ __forceinline__ u16 f2bf(float f) {
    union { float f; u32 u; } c; c.f = f;
    u32 x = c.u;
    u32 r = (x + 0x7fffu + ((x >> 16) & 1u)) >> 16;  // RNE
    return (u16)r;
}

// ---------------- K0: weight prep ---------------------------------------
__global__ __launch_bounds__(256) void k0_prep(const float* __restrict__ pw,
        const float* __restrict__ w2, const float* __restrict__ w3,
        const float* __restrict__ h2w, const float* __restrict__ h1w,
        u16* __restrict__ pwT, u16* __restrict__ w2r, u16* __restrict__ w3r,
        u16* __restrict__ h2hi, u16* __restrict__ h2lo,
        u16* __restrict__ h1hi, u16* __restrict__ h1lo) {
    int idx = blockIdx.x * 256 + threadIdx.x;
    if (idx < 38912) {
        int j = idx / 608, kk = idx - j * 608;
        float v = 0.f;
        if (kk < 576) {
            int p = kk >> 6, oc = kk & 63;
            v = pw[j * 578 + oc * 9 + p];
        } else if (kk < 578) {
            v = pw[j * 578 + kk];
        }
        pwT[idx] = f2bf(v);
    } else if (idx < 40960) {
        int i = idx - 38912;
        int oc = i >> 6, rem = i & 63, tap = rem >> 4, ic = rem & 15;
        w2r[i] = f2bf(w2[oc * 64 + ic * 4 + tap]);
    } else if (idx < 49152) {
        int i = idx - 40960;
        int oc = i >> 7, rem = i & 127, tap = rem >> 5, ic = rem & 31;
        w3r[i] = f2bf(w3[oc * 128 + ic * 4 + tap]);
    } else if (idx < 65536) {
        int i = idx - 49152;
        float v = h2w[i];
        u16 hi = f2bf(v);
        h2hi[i] = hi;
        h2lo[i] = f2bf(v - bf2f(hi));
    } else if (idx < 86016) {
        int i = idx - 65536;
        int j = i / 160, k = i - j * 160;
        float v = (k < 132) ? h1w[j * 132 + k] : 0.f;
        u16 hi = f2bf(v);
        h1hi[i] = hi;
        h1lo[i] = f2bf(v - bf2f(hi));
    }
}

// ---------------- K1: conv1 (pad1,k2) + relu + maxpool2 -> bf16 --------
// Block = 16 elems. Frame staged ZERO-PADDED 9x9x3 in LDS -> all 27 patch
// reads are unconditional ds_read at immediate offsets (no bounds selects,
// no per-read addressing). Same fp32 accumulation order as the validated
// kernel -> bit-identical output. Stride 244 keeps <=2-way banking.
__global__ __launch_bounds__(256) void k1_conv1(const int* __restrict__ frame,
        const float* __restrict__ w1, const float* __restrict__ b1,
        u16* __restrict__ pooled1b) {
    __shared__ float fr[16 * 244];   // [elem][((y+1)*9+(x+1))*3 + c]
    int t = threadIdx.x;
    int e0 = blockIdx.x * 16;
    // zero the whole region (976 float4)
    #pragma unroll
    for (int i = 0; i < 4; ++i) {
        int o4 = i * 256 + t;
        if (o4 < 976) *(float4*)(fr + o4 * 4) = make_float4(0.f, 0.f, 0.f, 0.f);
    }
    __syncthreads();
    // fill interior (2352 values, coalesced global reads)
    #pragma unroll
    for (int i = 0; i < 10; ++i) {
        int idx = i * 256 + t;
        if (idx < 2352) {
            int le = idx / 147, r = idx - le * 147;
            int cell = r / 3, c = r - cell * 3;
            int y = cell / 7, x = cell - y * 7;
            fr[le * 244 + ((y + 1) * 9 + (x + 1)) * 3 + c] = (float)frame[e0 * 147 + idx];
        }
    }
    __syncthreads();
    int le = t >> 4, pos = t & 15;
    int py = pos >> 2, px = pos & 3;
    // patch base: input (2py-1, 2px-1) -> padded (2py, 2px)
    const float* pb = fr + le * 244 + py * 54 + px * 6;
    float patch[3][3][3];  // [c][dy][dx], 27 unconditional loads, imm offsets
    #pragma unroll
    for (int dy = 0; dy < 3; ++dy)
        #pragma unroll
        for (int dx = 0; dx < 3; ++dx)
            #pragma unroll
            for (int c = 0; c < 3; ++c)
                patch[c][dy][dx] = pb[dy * 27 + dx * 3 + c];
    union { u16 s[16]; uint4 q[2]; } ob;
    #pragma unroll
    for (int oc = 0; oc < 16; ++oc) {
        float bias = b1[oc];
        float m = 0.0f;  // post-relu values >= 0
        #pragma unroll
        for (int sy = 0; sy < 2; ++sy)
        #pragma unroll
        for (int sx = 0; sx < 2; ++sx) {
            float acc = bias;
            #pragma unroll
            for (int ic = 0; ic < 3; ++ic)
            #pragma unroll
            for (int ky = 0; ky < 2; ++ky)
            #pragma unroll
            for (int kx = 0; kx < 2; ++kx)
                acc += patch[ic][sy + ky][sx + kx] * w1[oc * 12 + ic * 4 + ky * 2 + kx];
            acc = fmaxf(acc, 0.0f);
            m = fmaxf(m, acc);
        }
        ob.s[oc] = f2bf(m);
    }
    uint4* outp = (uint4*)(pooled1b + (e0 + le) * 256 + pos * 16);
    outp[0] = ob.q[0];
    outp[1] = ob.q[1];
}

// ---------------- K2: conv2+relu+maxpool fused via MFMA, LDS-free ------
#define K2_WAVES 4096
__global__ __launch_bounds__(256) void k2_conv2_mfma(const u16* __restrict__ pooled1b,
        const u16* __restrict__ w2r, const float* __restrict__ b2,
        u16* __restrict__ pooled2) {
    int t = threadIdx.x;
    int l = t & 63;
    int col = l & 15;
    int kg = l >> 4;
    int wv = (blockIdx.x * 256 + t) >> 6;

    bf16x8 bfrag[2][2];
    #pragma unroll
    for (int s = 0; s < 2; ++s)
        #pragma unroll
        for (int nt = 0; nt < 2; ++nt)
            bfrag[s][nt] = *(const bf16x8*)(w2r + (nt * 16 + col) * 64 + s * 32 + kg * 8);
    float bias[2] = { b2[col], b2[16 + col] };

    int oy = col >> 2, ox = col & 3;
    int aoff[2]; bool aok[2];
    #pragma unroll
    for (int s = 0; s < 2; ++s) {
        int tap = 2 * s + (kg >> 1);
        int ky = tap >> 1, kx = tap & 1;
        int iy = oy - 1 + ky, ix = ox - 1 + kx;
        aok[s] = (iy >= 0 && ix >= 0);
        aoff[s] = (iy * 4 + ix) * 16 + (kg & 1) * 8;
    }

    for (int e = wv; e < NELEM; e += K2_WAVES) {
        const u16* pbase = pooled1b + e * 256;
        bf16x8 a0 = {0,0,0,0,0,0,0,0}, a1 = {0,0,0,0,0,0,0,0};
        if (aok[0]) a0 = *(const bf16x8*)(pbase + aoff[0]);
        if (aok[1]) a1 = *(const bf16x8*)(pbase + aoff[1]);
        f32x4 acc0 = {0.f,0.f,0.f,0.f}, acc1 = {0.f,0.f,0.f,0.f};
        acc0 = __builtin_amdgcn_mfma_f32_16x16x32_bf16(a0, bfrag[0][0], acc0, 0, 0, 0);
        acc1 = __builtin_amdgcn_mfma_f32_16x16x32_bf16(a0, bfrag[0][1], acc1, 0, 0, 0);
        acc0 = __builtin_amdgcn_mfma_f32_16x16x32_bf16(a1, bfrag[1][0], acc0, 0, 0, 0);
        acc1 = __builtin_amdgcn_mfma_f32_16x16x32_bf16(a1, bfrag[1][1], acc1, 0, 0, 0);
        #pragma unroll
        for (int nt = 0; nt < 2; ++nt) {
            f32x4 acc = nt ? acc1 : acc0;
            float b = bias[nt];
            float m0 = fmaxf(fmaxf(acc[0] + b, 0.f), fmaxf(acc[1] + b, 0.f));
            float m1 = fmaxf(fmaxf(acc[2] + b, 0.f), fmaxf(acc[3] + b, 0.f));
            float p0 = fmaxf(m0, __shfl_xor(m0, 16, 64));
            float p1 = fmaxf(m1, __shfl_xor(m1, 16, 64));
            if ((kg & 1) == 0) {
                int q = (kg >> 1) * 2;
                u16* op = pooled2 + e * 128 + nt * 16 + col;
                op[q * 32]       = f2bf(p0);
                op[(q + 1) * 32] = f2bf(p1);
            }
        }
    }
}

// ---------------- K3: conv3+relu via MFMA, LDS-free --------------------
#define K3_WAVES 4096
__global__ __launch_bounds__(256) void k3_conv3_mfma(const u16* __restrict__ pooled2,
        const u16* __restrict__ w3r, const float* __restrict__ b3,
        u16* __restrict__ feat) {
    int t = threadIdx.x;
    int l = t & 63;
    int col = l & 15;
    int kg = l >> 4;
    int wv = (blockIdx.x * 256 + t) >> 6;
    const int NTILE = (NELEM * 9) / 16;  // 36864

    bf16x8 bfrag[4][4];
    #pragma unroll
    for (int s = 0; s < 4; ++s)
        #pragma unroll
        for (int nt = 0; nt < 4; ++nt)
            bfrag[s][nt] = *(const bf16x8*)(w3r + (nt * 16 + col) * 128 + s * 32 + kg * 8);
    float bias[4];
    #pragma unroll
    for (int nt = 0; nt < 4; ++nt) bias[nt] = b3[nt * 16 + col];

    for (int mt = wv; mt < NTILE; mt += K3_WAVES) {
        int m0 = mt * 16;
        int m = m0 + col;
        u32 elem = (u32)(((unsigned long long)(u32)m * 954437177ull) >> 33); // m/9
        int p = m - (int)elem * 9;
        int oy = (p * 86) >> 8;
        int ox = p - 3 * oy;
        const u16* pbase = pooled2 + (size_t)elem * 128 + kg * 8;
        f32x4 acc[4];
        #pragma unroll
        for (int nt = 0; nt < 4; ++nt) {
            acc[nt][0] = 0.f; acc[nt][1] = 0.f; acc[nt][2] = 0.f; acc[nt][3] = 0.f;
        }
        #pragma unroll
        for (int s = 0; s < 4; ++s) {
            int ky = s >> 1, kx = s & 1;
            int iy = oy - 1 + ky, ix = ox - 1 + kx;
            bf16x8 a = {0,0,0,0,0,0,0,0};
            if (iy >= 0 && iy <= 1 && ix >= 0 && ix <= 1)
                a = *(const bf16x8*)(pbase + (iy * 2 + ix) * 32);
            #pragma unroll
            for (int nt = 0; nt < 4; ++nt)
                acc[nt] = __builtin_amdgcn_mfma_f32_16x16x32_bf16(a, bfrag[s][nt], acc[nt], 0, 0, 0);
        }
        #pragma unroll
        for (int r = 0; r < 4; ++r) {
            int mr = m0 + kg * 4 + r;
            u32 er = (u32)(((unsigned long long)(u32)mr * 954437177ull) >> 33);
            int pr = mr - (int)er * 9;
            u16* fb = feat + (size_t)er * FSTRIDE + pr * 64;
            #pragma unroll
            for (int nt = 0; nt < 4; ++nt)
                fb[nt * 16 + col] = f2bf(fmaxf(acc[nt][r] + bias[nt], 0.f));
        }
    }
}

// ---------------- K3b: feat tail cols 576..583 -------------------------
__global__ __launch_bounds__(256) void k3_tail(const int* __restrict__ ccol,
        const int* __restrict__ cobj, u16* __restrict__ feat) {
    int e = blockIdx.x * 256 + threadIdx.x;
    union { u16 s[8]; uint4 q; } b;
    b.s[0] = f2bf((float)ccol[e]);
    b.s[1] = f2bf((float)cobj[e]);
    #pragma unroll
    for (int i = 2; i < 8; ++i) b.s[i] = 0;
    *(uint4*)(feat + (size_t)e * FSTRIDE + 576) = b.q;
}

// ---------------- K4: proj via MFMA, LDS-free -> emb fp32 --------------
__global__ __launch_bounds__(256) void k4_proj_mfma(const u16* __restrict__ feat,
        const u16* __restrict__ pwT, const float* __restrict__ pb,
        float* __restrict__ emb) {
    int t = threadIdx.x;
    int l = t & 63;
    int w = t >> 6;
    int m0 = blockIdx.x * 64 + w * 16;
    int col = l & 15;
    int kg = l >> 4;
    const u16* arow = feat + (size_t)(m0 + col) * FSTRIDE + kg * 8;
    const u16* brow = pwT + col * 608 + kg * 8;

    f32x4 acc[4];
    #pragma unroll
    for (int i = 0; i < 4; ++i) {
        acc[i][0] = 0.f; acc[i][1] = 0.f; acc[i][2] = 0.f; acc[i][3] = 0.f;
    }

    #pragma unroll 4
    for (int k0 = 0; k0 < 608; k0 += 32) {
        bf16x8 a;
        if (k0 + kg * 8 < 584) {
            a = *(const bf16x8*)(arow + k0);
        } else {
            #pragma unroll
            for (int j = 0; j < 8; ++j) a[j] = 0;
        }
        bf16x8 b0 = *(const bf16x8*)(brow + k0);
        bf16x8 b1 = *(const bf16x8*)(brow + 16 * 608 + k0);
        bf16x8 b2 = *(const bf16x8*)(brow + 32 * 608 + k0);
        bf16x8 b3 = *(const bf16x8*)(brow + 48 * 608 + k0);
        acc[0] = __builtin_amdgcn_mfma_f32_16x16x32_bf16(a, b0, acc[0], 0, 0, 0);
        acc[1] = __builtin_amdgcn_mfma_f32_16x16x32_bf16(a, b1, acc[1], 0, 0, 0);
        acc[2] = __builtin_amdgcn_mfma_f32_16x16x32_bf16(a, b2, acc[2], 0, 0, 0);
        acc[3] = __builtin_amdgcn_mfma_f32_16x16x32_bf16(a, b3, acc[3], 0, 0, 0);
    }

    #pragma unroll
    for (int nt = 0; nt < 4; ++nt) {
        float pbv = pb[nt * 16 + col];
        #pragma unroll
        for (int r = 0; r < 4; ++r) {
            int row = m0 + kg * 4 + r;
            emb[row * 64 + nt * 16 + col] = fmaxf(acc[nt][r] + pbv, 0.f);
        }
    }
}

// ---------------- K5: dir_pos deltas -> extras[b][4] fp32 ---------------
__global__ __launch_bounds__(256) void k5_extras(const int* __restrict__ frame,
        float* __restrict__ extras) {
    int b = blockIdx.x * 256 + threadIdx.x;
    int d[2]; float posy[2], posx[2];
    for (int f = 0; f < 2; ++f) {
        const int* fb = frame + (size_t)(f * BATCH + b) * 147;
        int idx = 49;
        for (int cell = 0; cell < 49; ++cell) {
            int v = fb[cell * 3];
            if (idx == 49 && v == 10) idx = cell;
        }
        if (idx < 49) {
            d[f] = fb[idx * 3 + 2] & 3;
            posy[f] = (float)(idx / 7) / 6.0f;
            posx[f] = (float)(idx % 7) / 6.0f;
        } else {
            d[f] = 0; posy[f] = 0.5f; posx[f] = 0.5f;
        }
    }
    int delta = (d[1] - d[0] + 4) & 3;
    const float ANG = (float)(2.0 * 3.14159 / 4.0);
    float angle = (float)delta * ANG;
    float4 o;
    o.x = sinf(angle);
    o.y = cosf(angle);
    o.z = posy[1] - posy[0];
    o.w = posx[1] - posx[0];
    *(float4*)(extras + b * 4) = o;
}

// ---------------- K5b: pack comb[32768][160] fp32 ----------------------
__global__ __launch_bounds__(256) void k5b_pack(const float* __restrict__ emb,
        const float* __restrict__ extras, float* __restrict__ comb) {
    int t = threadIdx.x;
    int b = blockIdx.x * 8 + (t >> 5);
    int q = t & 31;
    float4 v;
    if (q < 16) v = *(const float4*)(emb + (size_t)b * 64 + q * 4);
    else        v = *(const float4*)(emb + (size_t)(BATCH + b) * 64 + (q - 16) * 4);
    *(float4*)(comb + (size_t)b * 160 + q * 4) = v;
    if (t < 64) {
        int b2 = blockIdx.x * 8 + (t >> 3);
        int q2 = t & 7;
        float4 z = make_float4(0.f, 0.f, 0.f, 0.f);
        if (q2 == 0) z = *(const float4*)(extras + (size_t)b2 * 4);
        *(float4*)(comb + (size_t)b2 * 160 + 128 + q2 * 4) = z;
    }
}

__device__ __forceinline__ void split8(const float* __restrict__ x,
                                       bf16x8& hi, bf16x8& lo) {
    #pragma unroll
    for (int j = 0; j < 8; ++j) {
        u16 h = f2bf(x[j]);
        hi[j] = (short)h;
        lo[j] = (short)f2bf(x[j] - bf2f(h));
    }
}

// ---------------- K6a: h1 GEMM via split-bf16 MFMA (no LN) -------------
__global__ __launch_bounds__(256) void k6_h1_gemm(const float* __restrict__ in,
        const u16* __restrict__ whi, const u16* __restrict__ wlo,
        const float* __restrict__ bias, float* __restrict__ out) {
    int t = threadIdx.x;
    int l = t & 63;
    int col = l & 15;
    int kg = l >> 4;
    int m0 = blockIdx.x * 64 + (t >> 6) * 16;
    const float* arow = in + (size_t)(m0 + col) * 160 + kg * 8;
    const u16* bh = whi + col * 160 + kg * 8;
    const u16* bl = wlo + col * 160 + kg * 8;

    f32x4 acc[8];
    #pragma unroll
    for (int nt = 0; nt < 8; ++nt) {
        acc[nt][0] = 0.f; acc[nt][1] = 0.f; acc[nt][2] = 0.f; acc[nt][3] = 0.f;
    }
    #pragma unroll
    for (int s = 0; s < 5; ++s) {
        float x[8];
        #pragma unroll
        for (int j = 0; j < 8; ++j) x[j] = arow[s * 32 + j];
        bf16x8 ahi, alo;
        split8(x, ahi, alo);
        #pragma unroll
        for (int nt = 0; nt < 8; ++nt) {
            bf16x8 bhiF = *(const bf16x8*)(bh + nt * 2560 + s * 32);
            bf16x8 bloF = *(const bf16x8*)(bl + nt * 2560 + s * 32);
            acc[nt] = __builtin_amdgcn_mfma_f32_16x16x32_bf16(ahi, bhiF, acc[nt], 0, 0, 0);
            acc[nt] = __builtin_amdgcn_mfma_f32_16x16x32_bf16(alo, bhiF, acc[nt], 0, 0, 0);
            acc[nt] = __builtin_amdgcn_mfma_f32_16x16x32_bf16(ahi, bloF, acc[nt], 0, 0, 0);
        }
    }
    #pragma unroll
    for (int nt = 0; nt < 8; ++nt) {
        float bv = bias[nt * 16 + col];
        #pragma unroll
        for (int r = 0; r < 4; ++r) {
            int m = m0 + kg * 4 + r;
            out[m * 128 + nt * 16 + col] = acc[nt][r] + bv;
        }
    }
}

// ---------------- K6b: LayerNorm + relu, wave per row ------------------
__global__ __launch_bounds__(256) void k6_ln(const float* __restrict__ h,
        const float* __restrict__ lng, const float* __restrict__ lnb,
        float* __restrict__ out) {
    int w = (blockIdx.x * 256 + threadIdx.x) >> 6;
    int l = threadIdx.x & 63;
    const float* row = h + (size_t)w * 128 + l * 2;
    float2 v = *(const float2*)row;
    float s = v.x + v.y;
    s += __shfl_xor(s, 1, 64);
    s += __shfl_xor(s, 2, 64);
    s += __shfl_xor(s, 4, 64);
    s += __shfl_xor(s, 8, 64);
    s += __shfl_xor(s, 16, 64);
    s += __shfl_xor(s, 32, 64);
    float mu = s * (1.0f / 128.0f);
    float d0 = v.x - mu, d1 = v.y - mu;
    float vs = d0 * d0 + d1 * d1;
    vs += __shfl_xor(vs, 1, 64);
    vs += __shfl_xor(vs, 2, 64);
    vs += __shfl_xor(vs, 4, 64);
    vs += __shfl_xor(vs, 8, 64);
    vs += __shfl_xor(vs, 16, 64);
    vs += __shfl_xor(vs, 32, 64);
    float rs = rsqrtf(vs * (1.0f / 128.0f) + 1e-5f);
    float2 o;
    o.x = fmaxf(d0 * rs * lng[l * 2]     + lnb[l * 2],     0.f);
    o.y = fmaxf(d1 * rs * lng[l * 2 + 1] + lnb[l * 2 + 1], 0.f);
    *(float2*)(out + (size_t)w * 128 + l * 2) = o;
}

// ---------------- K7: h2 via split-bf16 MFMA (fp32 in/out) -------------
__global__ __launch_bounds__(256) void k7_h2_mfma(const float* __restrict__ in,
        const u16* __restrict__ whi, const u16* __restrict__ wlo,
        const float* __restrict__ bias, float* __restrict__ out) {
    int t = threadIdx.x;
    int l = t & 63;
    int col = l & 15;
    int kg = l >> 4;
    int m0 = blockIdx.x * 64 + (t >> 6) * 16;
    const float* arow = in + (size_t)(m0 + col) * 128 + kg * 8;
    const u16* bh = whi + col * 128 + kg * 8;
    const u16* bl = wlo + col * 128 + kg * 8;

    f32x4 acc[8];
    #pragma unroll
    for (int nt = 0; nt < 8; ++nt) {
        acc[nt][0] = 0.f; acc[nt][1] = 0.f; acc[nt][2] = 0.f; acc[nt][3] = 0.f;
    }
    #pragma unroll
    for (int s = 0; s < 4; ++s) {
        float x[8];
        #pragma unroll
        for (int j = 0; j < 8; ++j) x[j] = arow[s * 32 + j];
        bf16x8 ahi, alo;
        split8(x, ahi, alo);
        #pragma unroll
        for (int nt = 0; nt < 8; ++nt) {
            bf16x8 bhiF = *(const bf16x8*)(bh + nt * 2048 + s * 32);
            bf16x8 bloF = *(const bf16x8*)(bl + nt * 2048 + s * 32);
            acc[nt] = __builtin_amdgcn_mfma_f32_16x16x32_bf16(ahi, bhiF, acc[nt], 0, 0, 0);
            acc[nt] = __builtin_amdgcn_mfma_f32_16x16x32_bf16(alo, bhiF, acc[nt], 0, 0, 0);
            acc[nt] = __builtin_amdgcn_mfma_f32_16x16x32_bf16(ahi, bloF, acc[nt], 0, 0, 0);
        }
    }
    #pragma unroll
    for (int nt = 0; nt < 8; ++nt) {
        float bv = bias[nt * 16 + col];
        #pragma unroll
        for (int r = 0; r < 4; ++r) {
            int m = m0 + kg * 4 + r;
            out[m * 128 + nt * 16 + col] = fmaxf(acc[nt][r] + bv, 0.f);
        }
    }
}

// ---------------- K8: h3 [32768x128]@[128->7], thread = row, fp32 ------
__global__ __launch_bounds__(256) void k8_h3(const float* __restrict__ in,
        const float* __restrict__ w, const float* __restrict__ bias,
        float* __restrict__ out) {
    int r = blockIdx.x * 256 + threadIdx.x;
    float acc[7];
    #pragma unroll
    for (int j = 0; j < 7; ++j) acc[j] = bias[j];
    const float* row = in + (size_t)r * 128;
    #pragma unroll 4
    for (int c = 0; c < 32; ++c) {
        float4 v = *(const float4*)(row + c * 4);
        #pragma unroll
        for (int j = 0; j < 7; ++j) {
            acc[j] += v.x * w[j * 128 + c * 4 + 0];
            acc[j] += v.y * w[j * 128 + c * 4 + 1];
            acc[j] += v.z * w[j * 128 + c * 4 + 2];
            acc[j] += v.w * w[j * 128 + c * 4 + 3];
        }
    }
    #pragma unroll
    for (int j = 0; j < 7; ++j) out[r * 7 + j] = acc[j];
}

extern "C" void kernel_launch(void* const* d_in, const int* in_sizes, int n_in,
                              void* d_out, int out_size, void* d_ws, size_t ws_size,
                              hipStream_t stream) {
    const int*   frame = (const int*)d_in[0];
    const int*   ccol  = (const int*)d_in[1];
    const int*   cobj  = (const int*)d_in[2];
    const float* w1    = (const float*)d_in[3];
    const float* b1    = (const float*)d_in[4];
    const float* w2    = (const float*)d_in[5];
    const float* b2    = (const float*)d_in[6];
    const float* w3    = (const float*)d_in[7];
    const float* b3    = (const float*)d_in[8];
    const float* pw    = (const float*)d_in[9];
    const float* pb    = (const float*)d_in[10];
    const float* h1w   = (const float*)d_in[11];
    const float* h1b   = (const float*)d_in[12];
    const float* lng   = (const float*)d_in[13];
    const float* lnb   = (const float*)d_in[14];
    const float* h2w   = (const float*)d_in[15];
    const float* h2b   = (const float*)d_in[16];
    const float* h3w   = (const float*)d_in[17];
    const float* h3b   = (const float*)d_in[18];
    float* out = (float*)d_out;

    char* ws = (char*)d_ws;
    u16*   pooled1b = (u16*)(ws + 0);                    // 32 MB
    float* emb      = (float*)(ws + 0);                  // 16 MB (after k2)
    float* extras   = (float*)(ws + 16777216);           // 512 KB
    u16*   pooled2  = (u16*)(ws + 33554432);             // 16 MB
    float* h1out    = (float*)(ws + 33554432);           // 16 MB (after k3)
    u16*   feat     = (u16*)(ws + 50331648);             // 76.5 MB
    float* h2out    = (float*)(ws + 50331648);           // 16 MB (after k4)
    float* comb     = (float*)(ws + 73400320);           // 21 MB (after k4)
    float* h1pre    = (float*)(ws + 95420416);           // 16 MB (after k4)
    u16*   pwT      = (u16*)(ws + 132120576);            // 77824 B
    u16*   w2r      = (u16*)(ws + 132120576 + 131072);   // 4096 B
    u16*   w3r      = (u16*)(ws + 132120576 + 139264);   // 16384 B
    u16*   h2hi     = (u16*)(ws + 132120576 + 163840);   // 32768 B
    u16*   h2lo     = (u16*)(ws + 132120576 + 196608);   // 32768 B
    u16*   h1hi     = (u16*)(ws + 132120576 + 229376);   // 40960 B
    u16*   h1lo     = (u16*)(ws + 132120576 + 270336);   // 40960 B

    k0_prep<<<336, 256, 0, stream>>>(pw, w2, w3, h2w, h1w,
                                     pwT, w2r, w3r, h2hi, h2lo, h1hi, h1lo);
    k1_conv1<<<4096, 256, 0, stream>>>(frame, w1, b1, pooled1b);
    k2_conv2_mfma<<<1024, 256, 0, stream>>>(pooled1b, w2r, b2, pooled2);
    k3_conv3_mfma<<<1024, 256, 0, stream>>>(pooled2, w3r, b3, feat);
    k3_tail<<<256, 256, 0, stream>>>(ccol, cobj, feat);
    k4_proj_mfma<<<1024, 256, 0, stream>>>(feat, pwT, pb, emb);
    k5_extras<<<128, 256, 0, stream>>>(frame, extras);
    k5b_pack<<<4096, 256, 0, stream>>>(emb, extras, comb);
    k6_h1_gemm<<<512, 256, 0, stream>>>(comb, h1hi, h1lo, h1b, h1pre);
    k6_ln<<<8192, 256, 0, stream>>>(h1pre, lng, lnb, h1out);
    k7_h2_mfma<<<512, 256, 0, stream>>>(h1out, h2hi, h2lo, h2b, h2out);
    k8_h3<<<128, 256, 0, stream>>>(h2out, h3w, h3b, out);
}

// Round 13
// 305.426 us; speedup vs baseline: 1.0116x; 1.0116x over previous
//
#include <hip/hip_runtime.h>
#include <hip/hip_bf16.h>

#define BATCH 32768
#define NELEM 65536   // 2 * BATCH
#define FSTRIDE 584   // feat row stride (578 cols + 6 zeroed pad cols)

typedef unsigned short u16;
typedef unsigned int u32;
typedef __attribute__((ext_vector_type(8))) short bf16x8;
typedef __attribute__((ext_vector_type(4))) float f32x4;

__device__ __forceinline__ float bf2f(u16 u) {
    union { u32 u; float f; } c; c.u = ((u32)u) << 16; return c.f;
}
__device__ __forceinline__ u16 f2bf(float f) {
    union { float f; u32 u; } c; c.f = f;
    u32 x = c.u;
    u32 r = (x + 0x7fffu + ((x >> 16) & 1u)) >> 16;  // RNE
    return (u16)r;
}

// ---------------- K0: weight prep ---------------------------------------
__global__ __launch_bounds__(256) void k0_prep(const float* __restrict__ pw,
        const float* __restrict__ w2, const float* __restrict__ w3,
        const float* __restrict__ h2w, const float* __restrict__ h1w,
        u16* __restrict__ pwT, u16* __restrict__ w2r, u16* __restrict__ w3r,
        u16* __restrict__ h2hi, u16* __restrict__ h2lo,
        u16* __restrict__ h1hi, u16* __restrict__ h1lo) {
    int idx = blockIdx.x * 256 + threadIdx.x;
    if (idx < 38912) {
        int j = idx / 608, kk = idx - j * 608;
        float v = 0.f;
        if (kk < 576) {
            int p = kk >> 6, oc = kk & 63;
            v = pw[j * 578 + oc * 9 + p];
        } else if (kk < 578) {
            v = pw[j * 578 + kk];
        }
        pwT[idx] = f2bf(v);
    } else if (idx < 40960) {
        int i = idx - 38912;
        int oc = i >> 6, rem = i & 63, tap = rem >> 4, ic = rem & 15;
        w2r[i] = f2bf(w2[oc * 64 + ic * 4 + tap]);
    } else if (idx < 49152) {
        int i = idx - 40960;
        int oc = i >> 7, rem = i & 127, tap = rem >> 5, ic = rem & 31;
        w3r[i] = f2bf(w3[oc * 128 + ic * 4 + tap]);
    } else if (idx < 65536) {
        int i = idx - 49152;
        float v = h2w[i];
        u16 hi = f2bf(v);
        h2hi[i] = hi;
        h2lo[i] = f2bf(v - bf2f(hi));
    } else if (idx < 86016) {
        int i = idx - 65536;
        int j = i / 160, k = i - j * 160;
        float v = (k < 132) ? h1w[j * 132 + k] : 0.f;
        u16 hi = f2bf(v);
        h1hi[i] = hi;
        h1lo[i] = f2bf(v - bf2f(hi));
    }
}

// ---------------- K1: conv1 (pad1,k2) + relu + maxpool2 -> bf16 --------
// Padded 9x9x3 LDS frame. Per pool-sub-position: load 12-tap patch, PIN
// in VGPRs via empty asm (defeats compiler re-folding loads into each
// FMA — VGPR_Count=28 in R12 showed patch was never register-resident),
// then 16 oc x 12 FMA. Accumulation order identical to validated kernel
// (ic,ky,kx per acc; same relu/fmax chain) -> bit-identical output.
__global__ __launch_bounds__(256) void k1_conv1(const int* __restrict__ frame,
        const float* __restrict__ w1, const float* __restrict__ b1,
        u16* __restrict__ pooled1b) {
    __shared__ float fr[16 * 244];   // [elem][((y+1)*9+(x+1))*3 + c]
    int t = threadIdx.x;
    int e0 = blockIdx.x * 16;
    #pragma unroll
    for (int i = 0; i < 4; ++i) {
        int o4 = i * 256 + t;
        if (o4 < 976) *(float4*)(fr + o4 * 4) = make_float4(0.f, 0.f, 0.f, 0.f);
    }
    __syncthreads();
    #pragma unroll
    for (int i = 0; i < 10; ++i) {
        int idx = i * 256 + t;
        if (idx < 2352) {
            int le = idx / 147, r = idx - le * 147;
            int cell = r / 3, c = r - cell * 3;
            int y = cell / 7, x = cell - y * 7;
            fr[le * 244 + ((y + 1) * 9 + (x + 1)) * 3 + c] = (float)frame[e0 * 147 + idx];
        }
    }
    __syncthreads();
    int le = t >> 4, pos = t & 15;
    int py = pos >> 2, px = pos & 3;
    float m[16];
    #pragma unroll
    for (int oc = 0; oc < 16; ++oc) m[oc] = 0.f;
    #pragma unroll
    for (int sy = 0; sy < 2; ++sy)
    #pragma unroll
    for (int sx = 0; sx < 2; ++sx) {
        int cy = 2 * py + sy, cx = 2 * px + sx;
        const float* pb = fr + le * 244 + (cy * 9 + cx) * 3;
        float p[12];  // p[(ky*2+kx)*3+c] = padded(cy+ky, cx+kx, c)
        #pragma unroll
        for (int ky = 0; ky < 2; ++ky)
            #pragma unroll
            for (int kx = 0; kx < 2; ++kx)
                #pragma unroll
                for (int c = 0; c < 3; ++c)
                    p[(ky * 2 + kx) * 3 + c] = pb[ky * 27 + kx * 3 + c];
        #pragma unroll
        for (int i = 0; i < 12; ++i) asm volatile("" : "+v"(p[i]));  // pin
        #pragma unroll
        for (int oc = 0; oc < 16; ++oc) {
            float acc = b1[oc];
            #pragma unroll
            for (int ic = 0; ic < 3; ++ic)
                #pragma unroll
                for (int ky = 0; ky < 2; ++ky)
                    #pragma unroll
                    for (int kx = 0; kx < 2; ++kx)
                        acc += p[(ky * 2 + kx) * 3 + ic] * w1[oc * 12 + ic * 4 + ky * 2 + kx];
            m[oc] = fmaxf(m[oc], fmaxf(acc, 0.0f));
        }
    }
    union { u16 s[16]; uint4 q[2]; } ob;
    #pragma unroll
    for (int oc = 0; oc < 16; ++oc) ob.s[oc] = f2bf(m[oc]);
    uint4* outp = (uint4*)(pooled1b + (e0 + le) * 256 + pos * 16);
    outp[0] = ob.q[0];
    outp[1] = ob.q[1];
}

// ---------------- K2: conv2+relu+maxpool fused via MFMA, LDS-free ------
#define K2_WAVES 4096
__global__ __launch_bounds__(256) void k2_conv2_mfma(const u16* __restrict__ pooled1b,
        const u16* __restrict__ w2r, const float* __restrict__ b2,
        u16* __restrict__ pooled2) {
    int t = threadIdx.x;
    int l = t & 63;
    int col = l & 15;
    int kg = l >> 4;
    int wv = (blockIdx.x * 256 + t) >> 6;

    bf16x8 bfrag[2][2];
    #pragma unroll
    for (int s = 0; s < 2; ++s)
        #pragma unroll
        for (int nt = 0; nt < 2; ++nt)
            bfrag[s][nt] = *(const bf16x8*)(w2r + (nt * 16 + col) * 64 + s * 32 + kg * 8);
    float bias[2] = { b2[col], b2[16 + col] };

    int oy = col >> 2, ox = col & 3;
    int aoff[2]; bool aok[2];
    #pragma unroll
    for (int s = 0; s < 2; ++s) {
        int tap = 2 * s + (kg >> 1);
        int ky = tap >> 1, kx = tap & 1;
        int iy = oy - 1 + ky, ix = ox - 1 + kx;
        aok[s] = (iy >= 0 && ix >= 0);
        aoff[s] = (iy * 4 + ix) * 16 + (kg & 1) * 8;
    }

    for (int e = wv; e < NELEM; e += K2_WAVES) {
        const u16* pbase = pooled1b + e * 256;
        bf16x8 a0 = {0,0,0,0,0,0,0,0}, a1 = {0,0,0,0,0,0,0,0};
        if (aok[0]) a0 = *(const bf16x8*)(pbase + aoff[0]);
        if (aok[1]) a1 = *(const bf16x8*)(pbase + aoff[1]);
        f32x4 acc0 = {0.f,0.f,0.f,0.f}, acc1 = {0.f,0.f,0.f,0.f};
        acc0 = __builtin_amdgcn_mfma_f32_16x16x32_bf16(a0, bfrag[0][0], acc0, 0, 0, 0);
        acc1 = __builtin_amdgcn_mfma_f32_16x16x32_bf16(a0, bfrag[0][1], acc1, 0, 0, 0);
        acc0 = __builtin_amdgcn_mfma_f32_16x16x32_bf16(a1, bfrag[1][0], acc0, 0, 0, 0);
        acc1 = __builtin_amdgcn_mfma_f32_16x16x32_bf16(a1, bfrag[1][1], acc1, 0, 0, 0);
        #pragma unroll
        for (int nt = 0; nt < 2; ++nt) {
            f32x4 acc = nt ? acc1 : acc0;
            float b = bias[nt];
            float m0 = fmaxf(fmaxf(acc[0] + b, 0.f), fmaxf(acc[1] + b, 0.f));
            float m1 = fmaxf(fmaxf(acc[2] + b, 0.f), fmaxf(acc[3] + b, 0.f));
            float p0 = fmaxf(m0, __shfl_xor(m0, 16, 64));
            float p1 = fmaxf(m1, __shfl_xor(m1, 16, 64));
            if ((kg & 1) == 0) {
                int q = (kg >> 1) * 2;
                u16* op = pooled2 + e * 128 + nt * 16 + col;
                op[q * 32]       = f2bf(p0);
                op[(q + 1) * 32] = f2bf(p1);
            }
        }
    }
}

// ---------------- K3: conv3+relu via MFMA, LDS-free --------------------
#define K3_WAVES 4096
__global__ __launch_bounds__(256) void k3_conv3_mfma(const u16* __restrict__ pooled2,
        const u16* __restrict__ w3r, const float* __restrict__ b3,
        u16* __restrict__ feat) {
    int t = threadIdx.x;
    int l = t & 63;
    int col = l & 15;
    int kg = l >> 4;
    int wv = (blockIdx.x * 256 + t) >> 6;
    const int NTILE = (NELEM * 9) / 16;  // 36864

    bf16x8 bfrag[4][4];
    #pragma unroll
    for (int s = 0; s < 4; ++s)
        #pragma unroll
        for (int nt = 0; nt < 4; ++nt)
            bfrag[s][nt] = *(const bf16x8*)(w3r + (nt * 16 + col) * 128 + s * 32 + kg * 8);
    float bias[4];
    #pragma unroll
    for (int nt = 0; nt < 4; ++nt) bias[nt] = b3[nt * 16 + col];

    for (int mt = wv; mt < NTILE; mt += K3_WAVES) {
        int m0 = mt * 16;
        int m = m0 + col;
        u32 elem = (u32)(((unsigned long long)(u32)m * 954437177ull) >> 33); // m/9
        int p = m - (int)elem * 9;
        int oy = (p * 86) >> 8;
        int ox = p - 3 * oy;
        const u16* pbase = pooled2 + (size_t)elem * 128 + kg * 8;
        f32x4 acc[4];
        #pragma unroll
        for (int nt = 0; nt < 4; ++nt) {
            acc[nt][0] = 0.f; acc[nt][1] = 0.f; acc[nt][2] = 0.f; acc[nt][3] = 0.f;
        }
        #pragma unroll
        for (int s = 0; s < 4; ++s) {
            int ky = s >> 1, kx = s & 1;
            int iy = oy - 1 + ky, ix = ox - 1 + kx;
            bf16x8 a = {0,0,0,0,0,0,0,0};
            if (iy >= 0 && iy <= 1 && ix >= 0 && ix <= 1)
                a = *(const bf16x8*)(pbase + (iy * 2 + ix) * 32);
            #pragma unroll
            for (int nt = 0; nt < 4; ++nt)
                acc[nt] = __builtin_amdgcn_mfma_f32_16x16x32_bf16(a, bfrag[s][nt], acc[nt], 0, 0, 0);
        }
        #pragma unroll
        for (int r = 0; r < 4; ++r) {
            int mr = m0 + kg * 4 + r;
            u32 er = (u32)(((unsigned long long)(u32)mr * 954437177ull) >> 33);
            int pr = mr - (int)er * 9;
            u16* fb = feat + (size_t)er * FSTRIDE + pr * 64;
            #pragma unroll
            for (int nt = 0; nt < 4; ++nt)
                fb[nt * 16 + col] = f2bf(fmaxf(acc[nt][r] + bias[nt], 0.f));
        }
    }
}

// ---------------- K3b: feat tail cols 576..583 -------------------------
__global__ __launch_bounds__(256) void k3_tail(const int* __restrict__ ccol,
        const int* __restrict__ cobj, u16* __restrict__ feat) {
    int e = blockIdx.x * 256 + threadIdx.x;
    union { u16 s[8]; uint4 q; } b;
    b.s[0] = f2bf((float)ccol[e]);
    b.s[1] = f2bf((float)cobj[e]);
    #pragma unroll
    for (int i = 2; i < 8; ++i) b.s[i] = 0;
    *(uint4*)(feat + (size_t)e * FSTRIDE + 576) = b.q;
}

// ---------------- K4: proj via MFMA -> writes comb[b][0..127] directly --
// row < BATCH  -> comb[row][col]        (curr embedding)
// row >= BATCH -> comb[row-BATCH][64+col] (next embedding)
// Each wave's 16 rows lie on one side of BATCH (32768 % 16 == 0).
__global__ __launch_bounds__(256) void k4_proj_mfma(const u16* __restrict__ feat,
        const u16* __restrict__ pwT, const float* __restrict__ pb,
        float* __restrict__ comb) {
    int t = threadIdx.x;
    int l = t & 63;
    int w = t >> 6;
    int m0 = blockIdx.x * 64 + w * 16;
    int col = l & 15;
    int kg = l >> 4;
    const u16* arow = feat + (size_t)(m0 + col) * FSTRIDE + kg * 8;
    const u16* brow = pwT + col * 608 + kg * 8;

    f32x4 acc[4];
    #pragma unroll
    for (int i = 0; i < 4; ++i) {
        acc[i][0] = 0.f; acc[i][1] = 0.f; acc[i][2] = 0.f; acc[i][3] = 0.f;
    }

    #pragma unroll 4
    for (int k0 = 0; k0 < 608; k0 += 32) {
        bf16x8 a;
        if (k0 + kg * 8 < 584) {
            a = *(const bf16x8*)(arow + k0);
        } else {
            #pragma unroll
            for (int j = 0; j < 8; ++j) a[j] = 0;
        }
        bf16x8 b0 = *(const bf16x8*)(brow + k0);
        bf16x8 b1 = *(const bf16x8*)(brow + 16 * 608 + k0);
        bf16x8 b2 = *(const bf16x8*)(brow + 32 * 608 + k0);
        bf16x8 b3 = *(const bf16x8*)(brow + 48 * 608 + k0);
        acc[0] = __builtin_amdgcn_mfma_f32_16x16x32_bf16(a, b0, acc[0], 0, 0, 0);
        acc[1] = __builtin_amdgcn_mfma_f32_16x16x32_bf16(a, b1, acc[1], 0, 0, 0);
        acc[2] = __builtin_amdgcn_mfma_f32_16x16x32_bf16(a, b2, acc[2], 0, 0, 0);
        acc[3] = __builtin_amdgcn_mfma_f32_16x16x32_bf16(a, b3, acc[3], 0, 0, 0);
    }

    float* outbase = (m0 < BATCH) ? (comb + (size_t)m0 * 160)
                                  : (comb + (size_t)(m0 - BATCH) * 160 + 64);
    #pragma unroll
    for (int nt = 0; nt < 4; ++nt) {
        float pbv = pb[nt * 16 + col];
        #pragma unroll
        for (int r = 0; r < 4; ++r) {
            outbase[(kg * 4 + r) * 160 + nt * 16 + col] = fmaxf(acc[nt][r] + pbv, 0.f);
        }
    }
}

// ---------------- K5: dir_pos deltas -> comb[b][128..159] --------------
__global__ __launch_bounds__(256) void k5_extras(const int* __restrict__ frame,
        float* __restrict__ comb) {
    int b = blockIdx.x * 256 + threadIdx.x;
    int d[2]; float posy[2], posx[2];
    for (int f = 0; f < 2; ++f) {
        const int* fb = frame + (size_t)(f * BATCH + b) * 147;
        int idx = 49;
        for (int cell = 0; cell < 49; ++cell) {
            int v = fb[cell * 3];
            if (idx == 49 && v == 10) idx = cell;
        }
        if (idx < 49) {
            d[f] = fb[idx * 3 + 2] & 3;
            posy[f] = (float)(idx / 7) / 6.0f;
            posx[f] = (float)(idx % 7) / 6.0f;
        } else {
            d[f] = 0; posy[f] = 0.5f; posx[f] = 0.5f;
        }
    }
    int delta = (d[1] - d[0] + 4) & 3;
    const float ANG = (float)(2.0 * 3.14159 / 4.0);
    float angle = (float)delta * ANG;
    float4 o;
    o.x = sinf(angle);
    o.y = cosf(angle);
    o.z = posy[1] - posy[0];
    o.w = posx[1] - posx[0];
    float* cb = comb + (size_t)b * 160 + 128;
    *(float4*)cb = o;
    float4 z = make_float4(0.f, 0.f, 0.f, 0.f);
    #pragma unroll
    for (int i = 1; i < 8; ++i) *(float4*)(cb + i * 4) = z;
}

__device__ __forceinline__ void split8(const float* __restrict__ x,
                                       bf16x8& hi, bf16x8& lo) {
    #pragma unroll
    for (int j = 0; j < 8; ++j) {
        u16 h = f2bf(x[j]);
        hi[j] = (short)h;
        lo[j] = (short)f2bf(x[j] - bf2f(h));
    }
}

// ---------------- K6a: h1 GEMM via split-bf16 MFMA (no LN) -------------
__global__ __launch_bounds__(256) void k6_h1_gemm(const float* __restrict__ in,
        const u16* __restrict__ whi, const u16* __restrict__ wlo,
        const float* __restrict__ bias, float* __restrict__ out) {
    int t = threadIdx.x;
    int l = t & 63;
    int col = l & 15;
    int kg = l >> 4;
    int m0 = blockIdx.x * 64 + (t >> 6) * 16;
    const float* arow = in + (size_t)(m0 + col) * 160 + kg * 8;
    const u16* bh = whi + col * 160 + kg * 8;
    const u16* bl = wlo + col * 160 + kg * 8;

    f32x4 acc[8];
    #pragma unroll
    for (int nt = 0; nt < 8; ++nt) {
        acc[nt][0] = 0.f; acc[nt][1] = 0.f; acc[nt][2] = 0.f; acc[nt][3] = 0.f;
    }
    #pragma unroll
    for (int s = 0; s < 5; ++s) {
        float x[8];
        #pragma unroll
        for (int j = 0; j < 8; ++j) x[j] = arow[s * 32 + j];
        bf16x8 ahi, alo;
        split8(x, ahi, alo);
        #pragma unroll
        for (int nt = 0; nt < 8; ++nt) {
            bf16x8 bhiF = *(const bf16x8*)(bh + nt * 2560 + s * 32);
            bf16x8 bloF = *(const bf16x8*)(bl + nt * 2560 + s * 32);
            acc[nt] = __builtin_amdgcn_mfma_f32_16x16x32_bf16(ahi, bhiF, acc[nt], 0, 0, 0);
            acc[nt] = __builtin_amdgcn_mfma_f32_16x16x32_bf16(alo, bhiF, acc[nt], 0, 0, 0);
            acc[nt] = __builtin_amdgcn_mfma_f32_16x16x32_bf16(ahi, bloF, acc[nt], 0, 0, 0);
        }
    }
    #pragma unroll
    for (int nt = 0; nt < 8; ++nt) {
        float bv = bias[nt * 16 + col];
        #pragma unroll
        for (int r = 0; r < 4; ++r) {
            int m = m0 + kg * 4 + r;
            out[m * 128 + nt * 16 + col] = acc[nt][r] + bv;
        }
    }
}

// ---------------- K6b: LayerNorm + relu, wave per row ------------------
__global__ __launch_bounds__(256) void k6_ln(const float* __restrict__ h,
        const float* __restrict__ lng, const float* __restrict__ lnb,
        float* __restrict__ out) {
    int w = (blockIdx.x * 256 + threadIdx.x) >> 6;
    int l = threadIdx.x & 63;
    const float* row = h + (size_t)w * 128 + l * 2;
    float2 v = *(const float2*)row;
    float s = v.x + v.y;
    s += __shfl_xor(s, 1, 64);
    s += __shfl_xor(s, 2, 64);
    s += __shfl_xor(s, 4, 64);
    s += __shfl_xor(s, 8, 64);
    s += __shfl_xor(s, 16, 64);
    s += __shfl_xor(s, 32, 64);
    float mu = s * (1.0f / 128.0f);
    float d0 = v.x - mu, d1 = v.y - mu;
    float vs = d0 * d0 + d1 * d1;
    vs += __shfl_xor(vs, 1, 64);
    vs += __shfl_xor(vs, 2, 64);
    vs += __shfl_xor(vs, 4, 64);
    vs += __shfl_xor(vs, 8, 64);
    vs += __shfl_xor(vs, 16, 64);
    vs += __shfl_xor(vs, 32, 64);
    float rs = rsqrtf(vs * (1.0f / 128.0f) + 1e-5f);
    float2 o;
    o.x = fmaxf(d0 * rs * lng[l * 2]     + lnb[l * 2],     0.f);
    o.y = fmaxf(d1 * rs * lng[l * 2 + 1] + lnb[l * 2 + 1], 0.f);
    *(float2*)(out + (size_t)w * 128 + l * 2) = o;
}

// ---------------- K7: h2 via split-bf16 MFMA (fp32 in/out) -------------
__global__ __launch_bounds__(256) void k7_h2_mfma(const float* __restrict__ in,
        const u16* __restrict__ whi, const u16* __restrict__ wlo,
        const float* __restrict__ bias, float* __restrict__ out) {
    int t = threadIdx.x;
    int l = t & 63;
    int col = l & 15;
    int kg = l >> 4;
    int m0 = blockIdx.x * 64 + (t >> 6) * 16;
    const float* arow = in + (size_t)(m0 + col) * 128 + kg * 8;
    const u16* bh = whi + col * 128 + kg * 8;
    const u16* bl = wlo + col * 128 + kg * 8;

    f32x4 acc[8];
    #pragma unroll
    for (int nt = 0; nt < 8; ++nt) {
        acc[nt][0] = 0.f; acc[nt][1] = 0.f; acc[nt][2] = 0.f; acc[nt][3] = 0.f;
    }
    #pragma unroll
    for (int s = 0; s < 4; ++s) {
        float x[8];
        #pragma unroll
        for (int j = 0; j < 8; ++j) x[j] = arow[s * 32 + j];
        bf16x8 ahi, alo;
        split8(x, ahi, alo);
        #pragma unroll
        for (int nt = 0; nt < 8; ++nt) {
            bf16x8 bhiF = *(const bf16x8*)(bh + nt * 2048 + s * 32);
            bf16x8 bloF = *(const bf16x8*)(bl + nt * 2048 + s * 32);
            acc[nt] = __builtin_amdgcn_mfma_f32_16x16x32_bf16(ahi, bhiF, acc[nt], 0, 0, 0);
            acc[nt] = __builtin_amdgcn_mfma_f32_16x16x32_bf16(alo, bhiF, acc[nt], 0, 0, 0);
            acc[nt] = __builtin_amdgcn_mfma_f32_16x16x32_bf16(ahi, bloF, acc[nt], 0, 0, 0);
        }
    }
    #pragma unroll
    for (int nt = 0; nt < 8; ++nt) {
        float bv = bias[nt * 16 + col];
        #pragma unroll
        for (int r = 0; r < 4; ++r) {
            int m = m0 + kg * 4 + r;
            out[m * 128 + nt * 16 + col] = fmaxf(acc[nt][r] + bv, 0.f);
        }
    }
}

// ---------------- K8: h3 [32768x128]@[128->7], thread = row, fp32 ------
__global__ __launch_bounds__(256) void k8_h3(const float* __restrict__ in,
        const float* __restrict__ w, const float* __restrict__ bias,
        float* __restrict__ out) {
    int r = blockIdx.x * 256 + threadIdx.x;
    float acc[7];
    #pragma unroll
    for (int j = 0; j < 7; ++j) acc[j] = bias[j];
    const float* row = in + (size_t)r * 128;
    #pragma unroll 4
    for (int c = 0; c < 32; ++c) {
        float4 v = *(const float4*)(row + c * 4);
        #pragma unroll
        for (int j = 0; j < 7; ++j) {
            acc[j] += v.x * w[j * 128 + c * 4 + 0];
            acc[j] += v.y * w[j * 128 + c * 4 + 1];
            acc[j] += v.z * w[j * 128 + c * 4 + 2];
            acc[j] += v.w * w[j * 128 + c * 4 + 3];
        }
    }
    #pragma unroll
    for (int j = 0; j < 7; ++j) out[r * 7 + j] = acc[j];
}

extern "C" void kernel_launch(void* const* d_in, const int* in_sizes, int n_in,
                              void* d_out, int out_size, void* d_ws, size_t ws_size,
                              hipStream_t stream) {
    const int*   frame = (const int*)d_in[0];
    const int*   ccol  = (const int*)d_in[1];
    const int*   cobj  = (const int*)d_in[2];
    const float* w1    = (const float*)d_in[3];
    const float* b1    = (const float*)d_in[4];
    const float* w2    = (const float*)d_in[5];
    const float* b2    = (const float*)d_in[6];
    const float* w3    = (const float*)d_in[7];
    const float* b3    = (const float*)d_in[8];
    const float* pw    = (const float*)d_in[9];
    const float* pb    = (const float*)d_in[10];
    const float* h1w   = (const float*)d_in[11];
    const float* h1b   = (const float*)d_in[12];
    const float* lng   = (const float*)d_in[13];
    const float* lnb   = (const float*)d_in[14];
    const float* h2w   = (const float*)d_in[15];
    const float* h2b   = (const float*)d_in[16];
    const float* h3w   = (const float*)d_in[17];
    const float* h3b   = (const float*)d_in[18];
    float* out = (float*)d_out;

    char* ws = (char*)d_ws;
    // Region A [0,32MB): pooled1b (k1->k2); then comb fp32 21MB (k4/k5->k6a)
    // Region B [32MB,48MB): pooled2 (k2->k3); then h1out fp32 (k6b->k7)
    // Region C [48MB,124.5MB): feat (k3->k4); then h2out (48..64, k7->k8),
    //          h1pre (91..107, k6a->k6b)
    // Region D [126MB+): converted weights (k0 -> consumers)
    u16*   pooled1b = (u16*)(ws + 0);                    // 32 MB
    float* comb     = (float*)(ws + 0);                  // 21 MB (after k2)
    u16*   pooled2  = (u16*)(ws + 33554432);             // 16 MB
    float* h1out    = (float*)(ws + 33554432);           // 16 MB (after k3)
    u16*   feat     = (u16*)(ws + 50331648);             // 76.5 MB
    float* h2out    = (float*)(ws + 50331648);           // 16 MB (after k4)
    float* h1pre    = (float*)(ws + 95420416);           // 16 MB (after k4)
    u16*   pwT      = (u16*)(ws + 132120576);            // 77824 B
    u16*   w2r      = (u16*)(ws + 132120576 + 131072);   // 4096 B
    u16*   w3r      = (u16*)(ws + 132120576 + 139264);   // 16384 B
    u16*   h2hi     = (u16*)(ws + 132120576 + 163840);   // 32768 B
    u16*   h2lo     = (u16*)(ws + 132120576 + 196608);   // 32768 B
    u16*   h1hi     = (u16*)(ws + 132120576 + 229376);   // 40960 B
    u16*   h1lo     = (u16*)(ws + 132120576 + 270336);   // 40960 B

    k0_prep<<<336, 256, 0, stream>>>(pw, w2, w3, h2w, h1w,
                                     pwT, w2r, w3r, h2hi, h2lo, h1hi, h1lo);
    k1_conv1<<<4096, 256, 0, stream>>>(frame, w1, b1, pooled1b);
    k2_conv2_mfma<<<1024, 256, 0, stream>>>(pooled1b, w2r, b2, pooled2);
    k3_conv3_mfma<<<1024, 256, 0, stream>>>(pooled2, w3r, b3, feat);
    k3_tail<<<256, 256, 0, stream>>>(ccol, cobj, feat);
    k4_proj_mfma<<<1024, 256, 0, stream>>>(feat, pwT, pb, comb);
    k5_extras<<<128, 256, 0, stream>>>(frame, comb);
    k6_h1_gemm<<<512, 256, 0, stream>>>(comb, h1hi, h1lo, h1b, h1pre);
    k6_ln<<<8192, 256, 0, stream>>>(h1pre, lng, lnb, h1out);
    k7_h2_mfma<<<512, 256, 0, stream>>>(h1out, h2hi, h2lo, h2b, h2out);
    k8_h3<<<128, 256, 0, stream>>>(h2out, h3w, h3b, out);
}

// Round 14
// 293.010 us; speedup vs baseline: 1.0544x; 1.0424x over previous
//
#include <hip/hip_runtime.h>
#include <hip/hip_bf16.h>

#define BATCH 32768
#define NELEM 65536   // 2 * BATCH
#define FSTRIDE 584   // feat row stride (578 cols + 6 zeroed pad cols)

typedef unsigned short u16;
typedef unsigned int u32;
typedef __attribute__((ext_vector_type(8))) short bf16x8;
typedef __attribute__((ext_vector_type(4))) float f32x4;

__device__ __forceinline__ float bf2f(u16 u) {
    union { u32 u; float f; } c; c.u = ((u32)u) << 16; return c.f;
}
__device__ __forceinline__ u16 f2bf(float f) {
    union { float f; u32 u; } c; c.f = f;
    u32 x = c.u;
    u32 r = (x + 0x7fffu + ((x >> 16) & 1u)) >> 16;  // RNE
    return (u16)r;
}

// ---------------- K0: weight prep ---------------------------------------
// pwT: [64][608]; w2r/w3r conv reorders; h1/h2 split-bf16 planes;
// w1hi/w1lo: [16][32] split-bf16 conv1 weights, K-layout k = ky*16+kx*8+c
// (c>=3 slots ZERO — matching A-fragment don't-care slots).
__global__ __launch_bounds__(256) void k0_prep(const float* __restrict__ pw,
        const float* __restrict__ w2, const float* __restrict__ w3,
        const float* __restrict__ h2w, const float* __restrict__ h1w,
        const float* __restrict__ w1,
        u16* __restrict__ pwT, u16* __restrict__ w2r, u16* __restrict__ w3r,
        u16* __restrict__ h2hi, u16* __restrict__ h2lo,
        u16* __restrict__ h1hi, u16* __restrict__ h1lo,
        u16* __restrict__ w1hi, u16* __restrict__ w1lo) {
    int idx = blockIdx.x * 256 + threadIdx.x;
    if (idx < 38912) {
        int j = idx / 608, kk = idx - j * 608;
        float v = 0.f;
        if (kk < 576) {
            int p = kk >> 6, oc = kk & 63;
            v = pw[j * 578 + oc * 9 + p];
        } else if (kk < 578) {
            v = pw[j * 578 + kk];
        }
        pwT[idx] = f2bf(v);
    } else if (idx < 40960) {
        int i = idx - 38912;
        int oc = i >> 6, rem = i & 63, tap = rem >> 4, ic = rem & 15;
        w2r[i] = f2bf(w2[oc * 64 + ic * 4 + tap]);
    } else if (idx < 49152) {
        int i = idx - 40960;
        int oc = i >> 7, rem = i & 127, tap = rem >> 5, ic = rem & 31;
        w3r[i] = f2bf(w3[oc * 128 + ic * 4 + tap]);
    } else if (idx < 65536) {
        int i = idx - 49152;
        float v = h2w[i];
        u16 hi = f2bf(v);
        h2hi[i] = hi;
        h2lo[i] = f2bf(v - bf2f(hi));
    } else if (idx < 86016) {
        int i = idx - 65536;
        int j = i / 160, k = i - j * 160;
        float v = (k < 132) ? h1w[j * 132 + k] : 0.f;
        u16 hi = f2bf(v);
        h1hi[i] = hi;
        h1lo[i] = f2bf(v - bf2f(hi));
    } else if (idx < 86528) {
        int i = idx - 86016;               // [oc16][k32]
        int oc = i >> 5, k = i & 31;
        int ky = k >> 4, kx = (k >> 3) & 1, c = k & 7;
        float v = (c < 3) ? w1[oc * 12 + c * 4 + ky * 2 + kx] : 0.f;
        u16 hi = f2bf(v);
        w1hi[i] = hi;
        w1lo[i] = f2bf(v - bf2f(hi));
    }
}

// ---------------- K1: conv1+relu+maxpool via MFMA ----------------------
// Block = 16 elems. Frame staged zero-padded 9x9x(8-slot) bf16 in LDS
// (ints 0..10 bf16-exact). Implicit GEMM: M = 64 conv pos (4 tiles),
// N = 16 oc, K = 32 (k = ky*16+kx*8+c; c>=3 weight-zeroed). Split-bf16
// weights -> fp32-exact conv. A-frag = one aligned ds_read_b128/lane.
// Pool: x-pair = reg pair (r^1), y-pair = shfl_xor(32) (kg^2).
__global__ __launch_bounds__(256) void k1_conv1_mfma(const int* __restrict__ frame,
        const u16* __restrict__ w1hi, const u16* __restrict__ w1lo,
        const float* __restrict__ b1, u16* __restrict__ pooled1b) {
    __shared__ u16 fr[16 * 656];   // [elem][(y)*72 + (x)*8 + c], padded 9x9
    int t = threadIdx.x;
    int e0 = blockIdx.x * 16;
    #pragma unroll
    for (int i = 0; i < 6; ++i) {
        int o = i * 256 + t;
        if (o < 1312) *(uint4*)(fr + o * 8) = make_uint4(0u, 0u, 0u, 0u);
    }
    __syncthreads();
    #pragma unroll
    for (int i = 0; i < 10; ++i) {
        int idx = i * 256 + t;
        if (idx < 2352) {
            int le = idx / 147, r = idx - le * 147;
            int cell = r / 3, c = r - cell * 3;
            int y = cell / 7, x = cell - y * 7;
            fr[le * 656 + (y + 1) * 72 + (x + 1) * 8 + c] = f2bf((float)frame[e0 * 147 + idx]);
        }
    }
    __syncthreads();
    int l = t & 63;
    int wv = t >> 6;
    int col = l & 15;                     // = oc (B/C) and A-row-in-tile
    int kg = l >> 4;
    bf16x8 bhi = *(const bf16x8*)(w1hi + col * 32 + kg * 8);
    bf16x8 blo = *(const bf16x8*)(w1lo + col * 32 + kg * 8);
    float bias = b1[col];
    int ky = kg >> 1, kx = kg & 1;
    bool writer = (kg < 2);
    #pragma unroll
    for (int q = 0; q < 4; ++q) {
        int le = wv * 4 + q;
        const u16* eb = fr + le * 656;
        u16* op = pooled1b + (size_t)(e0 + le) * 256;
        #pragma unroll
        for (int mt = 0; mt < 4; ++mt) {
            int posA = mt * 16 + col;
            int oy = posA >> 3, ox = posA & 7;
            bf16x8 a = *(const bf16x8*)(eb + (oy + ky) * 72 + (ox + kx) * 8);
            f32x4 acc = {0.f, 0.f, 0.f, 0.f};
            acc = __builtin_amdgcn_mfma_f32_16x16x32_bf16(a, bhi, acc, 0, 0, 0);
            acc = __builtin_amdgcn_mfma_f32_16x16x32_bf16(a, blo, acc, 0, 0, 0);
            // C rows: pos = mt*16 + kg*4 + r
            float x0 = fmaxf(acc[0] + bias, 0.f);
            float x1 = fmaxf(acc[1] + bias, 0.f);
            float x2 = fmaxf(acc[2] + bias, 0.f);
            float x3 = fmaxf(acc[3] + bias, 0.f);
            float y0 = fmaxf(x0, x1);                 // x-pair (r^1)
            float y1 = fmaxf(x2, x3);
            float m0 = fmaxf(y0, __shfl_xor(y0, 32, 64));  // y-pair (kg^2)
            float m1 = fmaxf(y1, __shfl_xor(y1, 32, 64));
            if (writer) {
                op[(mt * 4 + kg * 2 + 0) * 16 + col] = f2bf(m0);
                op[(mt * 4 + kg * 2 + 1) * 16 + col] = f2bf(m1);
            }
        }
    }
}

// ---------------- K2: conv2+relu+maxpool fused via MFMA, LDS-free ------
#define K2_WAVES 4096
__global__ __launch_bounds__(256) void k2_conv2_mfma(const u16* __restrict__ pooled1b,
        const u16* __restrict__ w2r, const float* __restrict__ b2,
        u16* __restrict__ pooled2) {
    int t = threadIdx.x;
    int l = t & 63;
    int col = l & 15;
    int kg = l >> 4;
    int wv = (blockIdx.x * 256 + t) >> 6;

    bf16x8 bfrag[2][2];
    #pragma unroll
    for (int s = 0; s < 2; ++s)
        #pragma unroll
        for (int nt = 0; nt < 2; ++nt)
            bfrag[s][nt] = *(const bf16x8*)(w2r + (nt * 16 + col) * 64 + s * 32 + kg * 8);
    float bias[2] = { b2[col], b2[16 + col] };

    int oy = col >> 2, ox = col & 3;
    int aoff[2]; bool aok[2];
    #pragma unroll
    for (int s = 0; s < 2; ++s) {
        int tap = 2 * s + (kg >> 1);
        int ky = tap >> 1, kx = tap & 1;
        int iy = oy - 1 + ky, ix = ox - 1 + kx;
        aok[s] = (iy >= 0 && ix >= 0);
        aoff[s] = (iy * 4 + ix) * 16 + (kg & 1) * 8;
    }

    for (int e = wv; e < NELEM; e += K2_WAVES) {
        const u16* pbase = pooled1b + e * 256;
        bf16x8 a0 = {0,0,0,0,0,0,0,0}, a1 = {0,0,0,0,0,0,0,0};
        if (aok[0]) a0 = *(const bf16x8*)(pbase + aoff[0]);
        if (aok[1]) a1 = *(const bf16x8*)(pbase + aoff[1]);
        f32x4 acc0 = {0.f,0.f,0.f,0.f}, acc1 = {0.f,0.f,0.f,0.f};
        acc0 = __builtin_amdgcn_mfma_f32_16x16x32_bf16(a0, bfrag[0][0], acc0, 0, 0, 0);
        acc1 = __builtin_amdgcn_mfma_f32_16x16x32_bf16(a0, bfrag[0][1], acc1, 0, 0, 0);
        acc0 = __builtin_amdgcn_mfma_f32_16x16x32_bf16(a1, bfrag[1][0], acc0, 0, 0, 0);
        acc1 = __builtin_amdgcn_mfma_f32_16x16x32_bf16(a1, bfrag[1][1], acc1, 0, 0, 0);
        #pragma unroll
        for (int nt = 0; nt < 2; ++nt) {
            f32x4 acc = nt ? acc1 : acc0;
            float b = bias[nt];
            float m0 = fmaxf(fmaxf(acc[0] + b, 0.f), fmaxf(acc[1] + b, 0.f));
            float m1 = fmaxf(fmaxf(acc[2] + b, 0.f), fmaxf(acc[3] + b, 0.f));
            float p0 = fmaxf(m0, __shfl_xor(m0, 16, 64));
            float p1 = fmaxf(m1, __shfl_xor(m1, 16, 64));
            if ((kg & 1) == 0) {
                int q = (kg >> 1) * 2;
                u16* op = pooled2 + e * 128 + nt * 16 + col;
                op[q * 32]       = f2bf(p0);
                op[(q + 1) * 32] = f2bf(p1);
            }
        }
    }
}

// ---------------- K3: conv3+relu via MFMA, LDS-free --------------------
#define K3_WAVES 4096
__global__ __launch_bounds__(256) void k3_conv3_mfma(const u16* __restrict__ pooled2,
        const u16* __restrict__ w3r, const float* __restrict__ b3,
        u16* __restrict__ feat) {
    int t = threadIdx.x;
    int l = t & 63;
    int col = l & 15;
    int kg = l >> 4;
    int wv = (blockIdx.x * 256 + t) >> 6;
    const int NTILE = (NELEM * 9) / 16;  // 36864

    bf16x8 bfrag[4][4];
    #pragma unroll
    for (int s = 0; s < 4; ++s)
        #pragma unroll
        for (int nt = 0; nt < 4; ++nt)
            bfrag[s][nt] = *(const bf16x8*)(w3r + (nt * 16 + col) * 128 + s * 32 + kg * 8);
    float bias[4];
    #pragma unroll
    for (int nt = 0; nt < 4; ++nt) bias[nt] = b3[nt * 16 + col];

    for (int mt = wv; mt < NTILE; mt += K3_WAVES) {
        int m0 = mt * 16;
        int m = m0 + col;
        u32 elem = (u32)(((unsigned long long)(u32)m * 954437177ull) >> 33); // m/9
        int p = m - (int)elem * 9;
        int oy = (p * 86) >> 8;
        int ox = p - 3 * oy;
        const u16* pbase = pooled2 + (size_t)elem * 128 + kg * 8;
        f32x4 acc[4];
        #pragma unroll
        for (int nt = 0; nt < 4; ++nt) {
            acc[nt][0] = 0.f; acc[nt][1] = 0.f; acc[nt][2] = 0.f; acc[nt][3] = 0.f;
        }
        #pragma unroll
        for (int s = 0; s < 4; ++s) {
            int ky = s >> 1, kx = s & 1;
            int iy = oy - 1 + ky, ix = ox - 1 + kx;
            bf16x8 a = {0,0,0,0,0,0,0,0};
            if (iy >= 0 && iy <= 1 && ix >= 0 && ix <= 1)
                a = *(const bf16x8*)(pbase + (iy * 2 + ix) * 32);
            #pragma unroll
            for (int nt = 0; nt < 4; ++nt)
                acc[nt] = __builtin_amdgcn_mfma_f32_16x16x32_bf16(a, bfrag[s][nt], acc[nt], 0, 0, 0);
        }
        #pragma unroll
        for (int r = 0; r < 4; ++r) {
            int mr = m0 + kg * 4 + r;
            u32 er = (u32)(((unsigned long long)(u32)mr * 954437177ull) >> 33);
            int pr = mr - (int)er * 9;
            u16* fb = feat + (size_t)er * FSTRIDE + pr * 64;
            #pragma unroll
            for (int nt = 0; nt < 4; ++nt)
                fb[nt * 16 + col] = f2bf(fmaxf(acc[nt][r] + bias[nt], 0.f));
        }
    }
}

// ---------------- K3b: feat tail cols 576..583 -------------------------
__global__ __launch_bounds__(256) void k3_tail(const int* __restrict__ ccol,
        const int* __restrict__ cobj, u16* __restrict__ feat) {
    int e = blockIdx.x * 256 + threadIdx.x;
    union { u16 s[8]; uint4 q; } b;
    b.s[0] = f2bf((float)ccol[e]);
    b.s[1] = f2bf((float)cobj[e]);
    #pragma unroll
    for (int i = 2; i < 8; ++i) b.s[i] = 0;
    *(uint4*)(feat + (size_t)e * FSTRIDE + 576) = b.q;
}

// ---------------- K4: proj via MFMA -> writes comb[b][0..127] directly --
__global__ __launch_bounds__(256) void k4_proj_mfma(const u16* __restrict__ feat,
        const u16* __restrict__ pwT, const float* __restrict__ pb,
        float* __restrict__ comb) {
    int t = threadIdx.x;
    int l = t & 63;
    int w = t >> 6;
    int m0 = blockIdx.x * 64 + w * 16;
    int col = l & 15;
    int kg = l >> 4;
    const u16* arow = feat + (size_t)(m0 + col) * FSTRIDE + kg * 8;
    const u16* brow = pwT + col * 608 + kg * 8;

    f32x4 acc[4];
    #pragma unroll
    for (int i = 0; i < 4; ++i) {
        acc[i][0] = 0.f; acc[i][1] = 0.f; acc[i][2] = 0.f; acc[i][3] = 0.f;
    }

    #pragma unroll 4
    for (int k0 = 0; k0 < 608; k0 += 32) {
        bf16x8 a;
        if (k0 + kg * 8 < 584) {
            a = *(const bf16x8*)(arow + k0);
        } else {
            #pragma unroll
            for (int j = 0; j < 8; ++j) a[j] = 0;
        }
        bf16x8 b0 = *(const bf16x8*)(brow + k0);
        bf16x8 b1 = *(const bf16x8*)(brow + 16 * 608 + k0);
        bf16x8 b2 = *(const bf16x8*)(brow + 32 * 608 + k0);
        bf16x8 b3 = *(const bf16x8*)(brow + 48 * 608 + k0);
        acc[0] = __builtin_amdgcn_mfma_f32_16x16x32_bf16(a, b0, acc[0], 0, 0, 0);
        acc[1] = __builtin_amdgcn_mfma_f32_16x16x32_bf16(a, b1, acc[1], 0, 0, 0);
        acc[2] = __builtin_amdgcn_mfma_f32_16x16x32_bf16(a, b2, acc[2], 0, 0, 0);
        acc[3] = __builtin_amdgcn_mfma_f32_16x16x32_bf16(a, b3, acc[3], 0, 0, 0);
    }

    float* outbase = (m0 < BATCH) ? (comb + (size_t)m0 * 160)
                                  : (comb + (size_t)(m0 - BATCH) * 160 + 64);
    #pragma unroll
    for (int nt = 0; nt < 4; ++nt) {
        float pbv = pb[nt * 16 + col];
        #pragma unroll
        for (int r = 0; r < 4; ++r) {
            outbase[(kg * 4 + r) * 160 + nt * 16 + col] = fmaxf(acc[nt][r] + pbv, 0.f);
        }
    }
}

// ---------------- K5: dir_pos deltas -> comb[b][128..159] --------------
__global__ __launch_bounds__(256) void k5_extras(const int* __restrict__ frame,
        float* __restrict__ comb) {
    int b = blockIdx.x * 256 + threadIdx.x;
    int d[2]; float posy[2], posx[2];
    for (int f = 0; f < 2; ++f) {
        const int* fb = frame + (size_t)(f * BATCH + b) * 147;
        int idx = 49;
        for (int cell = 0; cell < 49; ++cell) {
            int v = fb[cell * 3];
            if (idx == 49 && v == 10) idx = cell;
        }
        if (idx < 49) {
            d[f] = fb[idx * 3 + 2] & 3;
            posy[f] = (float)(idx / 7) / 6.0f;
            posx[f] = (float)(idx % 7) / 6.0f;
        } else {
            d[f] = 0; posy[f] = 0.5f; posx[f] = 0.5f;
        }
    }
    int delta = (d[1] - d[0] + 4) & 3;
    const float ANG = (float)(2.0 * 3.14159 / 4.0);
    float angle = (float)delta * ANG;
    float4 o;
    o.x = sinf(angle);
    o.y = cosf(angle);
    o.z = posy[1] - posy[0];
    o.w = posx[1] - posx[0];
    float* cb = comb + (size_t)b * 160 + 128;
    *(float4*)cb = o;
    float4 z = make_float4(0.f, 0.f, 0.f, 0.f);
    #pragma unroll
    for (int i = 1; i < 8; ++i) *(float4*)(cb + i * 4) = z;
}

__device__ __forceinline__ void split8(const float* __restrict__ x,
                                       bf16x8& hi, bf16x8& lo) {
    #pragma unroll
    for (int j = 0; j < 8; ++j) {
        u16 h = f2bf(x[j]);
        hi[j] = (short)h;
        lo[j] = (short)f2bf(x[j] - bf2f(h));
    }
}

// ---------------- K6a: h1 GEMM via split-bf16 MFMA (no LN) -------------
__global__ __launch_bounds__(256) void k6_h1_gemm(const float* __restrict__ in,
        const u16* __restrict__ whi, const u16* __restrict__ wlo,
        const float* __restrict__ bias, float* __restrict__ out) {
    int t = threadIdx.x;
    int l = t & 63;
    int col = l & 15;
    int kg = l >> 4;
    int m0 = blockIdx.x * 64 + (t >> 6) * 16;
    const float* arow = in + (size_t)(m0 + col) * 160 + kg * 8;
    const u16* bh = whi + col * 160 + kg * 8;
    const u16* bl = wlo + col * 160 + kg * 8;

    f32x4 acc[8];
    #pragma unroll
    for (int nt = 0; nt < 8; ++nt) {
        acc[nt][0] = 0.f; acc[nt][1] = 0.f; acc[nt][2] = 0.f; acc[nt][3] = 0.f;
    }
    #pragma unroll
    for (int s = 0; s < 5; ++s) {
        float x[8];
        #pragma unroll
        for (int j = 0; j < 8; ++j) x[j] = arow[s * 32 + j];
        bf16x8 ahi, alo;
        split8(x, ahi, alo);
        #pragma unroll
        for (int nt = 0; nt < 8; ++nt) {
            bf16x8 bhiF = *(const bf16x8*)(bh + nt * 2560 + s * 32);
            bf16x8 bloF = *(const bf16x8*)(bl + nt * 2560 + s * 32);
            acc[nt] = __builtin_amdgcn_mfma_f32_16x16x32_bf16(ahi, bhiF, acc[nt], 0, 0, 0);
            acc[nt] = __builtin_amdgcn_mfma_f32_16x16x32_bf16(alo, bhiF, acc[nt], 0, 0, 0);
            acc[nt] = __builtin_amdgcn_mfma_f32_16x16x32_bf16(ahi, bloF, acc[nt], 0, 0, 0);
        }
    }
    #pragma unroll
    for (int nt = 0; nt < 8; ++nt) {
        float bv = bias[nt * 16 + col];
        #pragma unroll
        for (int r = 0; r < 4; ++r) {
            int m = m0 + kg * 4 + r;
            out[m * 128 + nt * 16 + col] = acc[nt][r] + bv;
        }
    }
}

// ---------------- K6b: LayerNorm + relu, wave per row ------------------
__global__ __launch_bounds__(256) void k6_ln(const float* __restrict__ h,
        const float* __restrict__ lng, const float* __restrict__ lnb,
        float* __restrict__ out) {
    int w = (blockIdx.x * 256 + threadIdx.x) >> 6;
    int l = threadIdx.x & 63;
    const float* row = h + (size_t)w * 128 + l * 2;
    float2 v = *(const float2*)row;
    float s = v.x + v.y;
    s += __shfl_xor(s, 1, 64);
    s += __shfl_xor(s, 2, 64);
    s += __shfl_xor(s, 4, 64);
    s += __shfl_xor(s, 8, 64);
    s += __shfl_xor(s, 16, 64);
    s += __shfl_xor(s, 32, 64);
    float mu = s * (1.0f / 128.0f);
    float d0 = v.x - mu, d1 = v.y - mu;
    float vs = d0 * d0 + d1 * d1;
    vs += __shfl_xor(vs, 1, 64);
    vs += __shfl_xor(vs, 2, 64);
    vs += __shfl_xor(vs, 4, 64);
    vs += __shfl_xor(vs, 8, 64);
    vs += __shfl_xor(vs, 16, 64);
    vs += __shfl_xor(vs, 32, 64);
    float rs = rsqrtf(vs * (1.0f / 128.0f) + 1e-5f);
    float2 o;
    o.x = fmaxf(d0 * rs * lng[l * 2]     + lnb[l * 2],     0.f);
    o.y = fmaxf(d1 * rs * lng[l * 2 + 1] + lnb[l * 2 + 1], 0.f);
    *(float2*)(out + (size_t)w * 128 + l * 2) = o;
}

// ---------------- K7: h2 via split-bf16 MFMA (fp32 in/out) -------------
__global__ __launch_bounds__(256) void k7_h2_mfma(const float* __restrict__ in,
        const u16* __restrict__ whi, const u16* __restrict__ wlo,
        const float* __restrict__ bias, float* __restrict__ out) {
    int t = threadIdx.x;
    int l = t & 63;
    int col = l & 15;
    int kg = l >> 4;
    int m0 = blockIdx.x * 64 + (t >> 6) * 16;
    const float* arow = in + (size_t)(m0 + col) * 128 + kg * 8;
    const u16* bh = whi + col * 128 + kg * 8;
    const u16* bl = wlo + col * 128 + kg * 8;

    f32x4 acc[8];
    #pragma unroll
    for (int nt = 0; nt < 8; ++nt) {
        acc[nt][0] = 0.f; acc[nt][1] = 0.f; acc[nt][2] = 0.f; acc[nt][3] = 0.f;
    }
    #pragma unroll
    for (int s = 0; s < 4; ++s) {
        float x[8];
        #pragma unroll
        for (int j = 0; j < 8; ++j) x[j] = arow[s * 32 + j];
        bf16x8 ahi, alo;
        split8(x, ahi, alo);
        #pragma unroll
        for (int nt = 0; nt < 8; ++nt) {
            bf16x8 bhiF = *(const bf16x8*)(bh + nt * 2048 + s * 32);
            bf16x8 bloF = *(const bf16x8*)(bl + nt * 2048 + s * 32);
            acc[nt] = __builtin_amdgcn_mfma_f32_16x16x32_bf16(ahi, bhiF, acc[nt], 0, 0, 0);
            acc[nt] = __builtin_amdgcn_mfma_f32_16x16x32_bf16(alo, bhiF, acc[nt], 0, 0, 0);
            acc[nt] = __builtin_amdgcn_mfma_f32_16x16x32_bf16(ahi, bloF, acc[nt], 0, 0, 0);
        }
    }
    #pragma unroll
    for (int nt = 0; nt < 8; ++nt) {
        float bv = bias[nt * 16 + col];
        #pragma unroll
        for (int r = 0; r < 4; ++r) {
            int m = m0 + kg * 4 + r;
            out[m * 128 + nt * 16 + col] = fmaxf(acc[nt][r] + bv, 0.f);
        }
    }
}

// ---------------- K8: h3 [32768x128]@[128->7], thread = row, fp32 ------
__global__ __launch_bounds__(256) void k8_h3(const float* __restrict__ in,
        const float* __restrict__ w, const float* __restrict__ bias,
        float* __restrict__ out) {
    int r = blockIdx.x * 256 + threadIdx.x;
    float acc[7];
    #pragma unroll
    for (int j = 0; j < 7; ++j) acc[j] = bias[j];
    const float* row = in + (size_t)r * 128;
    #pragma unroll 4
    for (int c = 0; c < 32; ++c) {
        float4 v = *(const float4*)(row + c * 4);
        #pragma unroll
        for (int j = 0; j < 7; ++j) {
            acc[j] += v.x * w[j * 128 + c * 4 + 0];
            acc[j] += v.y * w[j * 128 + c * 4 + 1];
            acc[j] += v.z * w[j * 128 + c * 4 + 2];
            acc[j] += v.w * w[j * 128 + c * 4 + 3];
        }
    }
    #pragma unroll
    for (int j = 0; j < 7; ++j) out[r * 7 + j] = acc[j];
}

extern "C" void kernel_launch(void* const* d_in, const int* in_sizes, int n_in,
                              void* d_out, int out_size, void* d_ws, size_t ws_size,
                              hipStream_t stream) {
    const int*   frame = (const int*)d_in[0];
    const int*   ccol  = (const int*)d_in[1];
    const int*   cobj  = (const int*)d_in[2];
    const float* w1    = (const float*)d_in[3];
    const float* b1    = (const float*)d_in[4];
    const float* w2    = (const float*)d_in[5];
    const float* b2    = (const float*)d_in[6];
    const float* w3    = (const float*)d_in[7];
    const float* b3    = (const float*)d_in[8];
    const float* pw    = (const float*)d_in[9];
    const float* pb    = (const float*)d_in[10];
    const float* h1w   = (const float*)d_in[11];
    const float* h1b   = (const float*)d_in[12];
    const float* lng   = (const float*)d_in[13];
    const float* lnb   = (const float*)d_in[14];
    const float* h2w   = (const float*)d_in[15];
    const float* h2b   = (const float*)d_in[16];
    const float* h3w   = (const float*)d_in[17];
    const float* h3b   = (const float*)d_in[18];
    float* out = (float*)d_out;

    char* ws = (char*)d_ws;
    u16*   pooled1b = (u16*)(ws + 0);                    // 32 MB
    float* comb     = (float*)(ws + 0);                  // 21 MB (after k2)
    u16*   pooled2  = (u16*)(ws + 33554432);             // 16 MB
    float* h1out    = (float*)(ws + 33554432);           // 16 MB (after k3)
    u16*   feat     = (u16*)(ws + 50331648);             // 76.5 MB
    float* h2out    = (float*)(ws + 50331648);           // 16 MB (after k4)
    float* h1pre    = (float*)(ws + 95420416);           // 16 MB (after k4)
    u16*   pwT      = (u16*)(ws + 132120576);            // 77824 B
    u16*   w2r      = (u16*)(ws + 132120576 + 131072);   // 4096 B
    u16*   w3r      = (u16*)(ws + 132120576 + 139264);   // 16384 B
    u16*   h2hi     = (u16*)(ws + 132120576 + 163840);   // 32768 B
    u16*   h2lo     = (u16*)(ws + 132120576 + 196608);   // 32768 B
    u16*   h1hi     = (u16*)(ws + 132120576 + 229376);   // 40960 B
    u16*   h1lo     = (u16*)(ws + 132120576 + 270336);   // 40960 B
    u16*   w1hi     = (u16*)(ws + 132120576 + 311296);   // 1024 B
    u16*   w1lo     = (u16*)(ws + 132120576 + 312320);   // 1024 B

    k0_prep<<<340, 256, 0, stream>>>(pw, w2, w3, h2w, h1w, w1,
                                     pwT, w2r, w3r, h2hi, h2lo, h1hi, h1lo,
                                     w1hi, w1lo);
    k1_conv1_mfma<<<4096, 256, 0, stream>>>(frame, w1hi, w1lo, b1, pooled1b);
    k2_conv2_mfma<<<1024, 256, 0, stream>>>(pooled1b, w2r, b2, pooled2);
    k3_conv3_mfma<<<1024, 256, 0, stream>>>(pooled2, w3r, b3, feat);
    k3_tail<<<256, 256, 0, stream>>>(ccol, cobj, feat);
    k4_proj_mfma<<<1024, 256, 0, stream>>>(feat, pwT, pb, comb);
    k5_extras<<<128, 256, 0, stream>>>(frame, comb);
    k6_h1_gemm<<<512, 256, 0, stream>>>(comb, h1hi, h1lo, h1b, h1pre);
    k6_ln<<<8192, 256, 0, stream>>>(h1pre, lng, lnb, h1out);
    k7_h2_mfma<<<512, 256, 0, stream>>>(h1out, h2hi, h2lo, h2b, h2out);
    k8_h3<<<128, 256, 0, stream>>>(h2out, h3w, h3b, out);
}

// Round 15
// 279.673 us; speedup vs baseline: 1.1047x; 1.0477x over previous
//
#include <hip/hip_runtime.h>
#include <hip/hip_bf16.h>

#define BATCH 32768
#define NELEM 65536   // 2 * BATCH

typedef unsigned short u16;
typedef unsigned int u32;
typedef __attribute__((ext_vector_type(8))) short bf16x8;
typedef __attribute__((ext_vector_type(4))) float f32x4;

__device__ __forceinline__ float bf2f(u16 u) {
    union { u32 u; float f; } c; c.u = ((u32)u) << 16; return c.f;
}
__device__ __forceinline__ u16 f2bf(float f) {
    union { float f; u32 u; } c; c.f = f;
    u32 x = c.u;
    u32 r = (x + 0x7fffu + ((x >> 16) & 1u)) >> 16;  // RNE
    return (u16)r;
}

// ---------------- K0: weight prep ---------------------------------------
__global__ __launch_bounds__(256) void k0_prep(const float* __restrict__ pw,
        const float* __restrict__ w2, const float* __restrict__ w3,
        const float* __restrict__ h2w, const float* __restrict__ h1w,
        const float* __restrict__ w1,
        u16* __restrict__ pwT, u16* __restrict__ w2r, u16* __restrict__ w3r,
        u16* __restrict__ h2hi, u16* __restrict__ h2lo,
        u16* __restrict__ h1hi, u16* __restrict__ h1lo,
        u16* __restrict__ w1hi, u16* __restrict__ w1lo) {
    int idx = blockIdx.x * 256 + threadIdx.x;
    if (idx < 38912) {
        int j = idx / 608, kk = idx - j * 608;
        float v = 0.f;
        if (kk < 576) {
            int p = kk >> 6, oc = kk & 63;
            v = pw[j * 578 + oc * 9 + p];
        } else if (kk < 578) {
            v = pw[j * 578 + kk];
        }
        pwT[idx] = f2bf(v);
    } else if (idx < 40960) {
        int i = idx - 38912;
        int oc = i >> 6, rem = i & 63, tap = rem >> 4, ic = rem & 15;
        w2r[i] = f2bf(w2[oc * 64 + ic * 4 + tap]);
    } else if (idx < 49152) {
        int i = idx - 40960;
        int oc = i >> 7, rem = i & 127, tap = rem >> 5, ic = rem & 31;
        w3r[i] = f2bf(w3[oc * 128 + ic * 4 + tap]);
    } else if (idx < 65536) {
        int i = idx - 49152;
        float v = h2w[i];
        u16 hi = f2bf(v);
        h2hi[i] = hi;
        h2lo[i] = f2bf(v - bf2f(hi));
    } else if (idx < 86016) {
        int i = idx - 65536;
        int j = i / 160, k = i - j * 160;
        float v = (k < 132) ? h1w[j * 132 + k] : 0.f;
        u16 hi = f2bf(v);
        h1hi[i] = hi;
        h1lo[i] = f2bf(v - bf2f(hi));
    } else if (idx < 86528) {
        int i = idx - 86016;               // [oc16][k32]
        int oc = i >> 5, k = i & 31;
        int ky = k >> 4, kx = (k >> 3) & 1, c = k & 7;
        float v = (c < 3) ? w1[oc * 12 + c * 4 + ky * 2 + kx] : 0.f;
        u16 hi = f2bf(v);
        w1hi[i] = hi;
        w1lo[i] = f2bf(v - bf2f(hi));
    }
}

// ---------------- K1: conv1+relu+maxpool via MFMA ----------------------
__global__ __launch_bounds__(256) void k1_conv1_mfma(const int* __restrict__ frame,
        const u16* __restrict__ w1hi, const u16* __restrict__ w1lo,
        const float* __restrict__ b1, u16* __restrict__ pooled1b) {
    __shared__ u16 fr[16 * 656];   // [elem][(y)*72 + (x)*8 + c], padded 9x9
    int t = threadIdx.x;
    int e0 = blockIdx.x * 16;
    #pragma unroll
    for (int i = 0; i < 6; ++i) {
        int o = i * 256 + t;
        if (o < 1312) *(uint4*)(fr + o * 8) = make_uint4(0u, 0u, 0u, 0u);
    }
    __syncthreads();
    #pragma unroll
    for (int i = 0; i < 10; ++i) {
        int idx = i * 256 + t;
        if (idx < 2352) {
            int le = idx / 147, r = idx - le * 147;
            int cell = r / 3, c = r - cell * 3;
            int y = cell / 7, x = cell - y * 7;
            fr[le * 656 + (y + 1) * 72 + (x + 1) * 8 + c] = f2bf((float)frame[e0 * 147 + idx]);
        }
    }
    __syncthreads();
    int l = t & 63;
    int wv = t >> 6;
    int col = l & 15;
    int kg = l >> 4;
    bf16x8 bhi = *(const bf16x8*)(w1hi + col * 32 + kg * 8);
    bf16x8 blo = *(const bf16x8*)(w1lo + col * 32 + kg * 8);
    float bias = b1[col];
    int ky = kg >> 1, kx = kg & 1;
    bool writer = (kg < 2);
    #pragma unroll
    for (int q = 0; q < 4; ++q) {
        int le = wv * 4 + q;
        const u16* eb = fr + le * 656;
        u16* op = pooled1b + (size_t)(e0 + le) * 256;
        #pragma unroll
        for (int mt = 0; mt < 4; ++mt) {
            int posA = mt * 16 + col;
            int oy = posA >> 3, ox = posA & 7;
            bf16x8 a = *(const bf16x8*)(eb + (oy + ky) * 72 + (ox + kx) * 8);
            f32x4 acc = {0.f, 0.f, 0.f, 0.f};
            acc = __builtin_amdgcn_mfma_f32_16x16x32_bf16(a, bhi, acc, 0, 0, 0);
            acc = __builtin_amdgcn_mfma_f32_16x16x32_bf16(a, blo, acc, 0, 0, 0);
            float x0 = fmaxf(acc[0] + bias, 0.f);
            float x1 = fmaxf(acc[1] + bias, 0.f);
            float x2 = fmaxf(acc[2] + bias, 0.f);
            float x3 = fmaxf(acc[3] + bias, 0.f);
            float y0 = fmaxf(x0, x1);
            float y1 = fmaxf(x2, x3);
            float m0 = fmaxf(y0, __shfl_xor(y0, 32, 64));
            float m1 = fmaxf(y1, __shfl_xor(y1, 32, 64));
            if (writer) {
                op[(mt * 4 + kg * 2 + 0) * 16 + col] = f2bf(m0);
                op[(mt * 4 + kg * 2 + 1) * 16 + col] = f2bf(m1);
            }
        }
    }
}

// ---------------- K2: conv2+relu+maxpool fused via MFMA, LDS-free ------
#define K2_WAVES 4096
__global__ __launch_bounds__(256) void k2_conv2_mfma(const u16* __restrict__ pooled1b,
        const u16* __restrict__ w2r, const float* __restrict__ b2,
        u16* __restrict__ pooled2) {
    int t = threadIdx.x;
    int l = t & 63;
    int col = l & 15;
    int kg = l >> 4;
    int wv = (blockIdx.x * 256 + t) >> 6;

    bf16x8 bfrag[2][2];
    #pragma unroll
    for (int s = 0; s < 2; ++s)
        #pragma unroll
        for (int nt = 0; nt < 2; ++nt)
            bfrag[s][nt] = *(const bf16x8*)(w2r + (nt * 16 + col) * 64 + s * 32 + kg * 8);
    float bias[2] = { b2[col], b2[16 + col] };

    int oy = col >> 2, ox = col & 3;
    int aoff[2]; bool aok[2];
    #pragma unroll
    for (int s = 0; s < 2; ++s) {
        int tap = 2 * s + (kg >> 1);
        int ky = tap >> 1, kx = tap & 1;
        int iy = oy - 1 + ky, ix = ox - 1 + kx;
        aok[s] = (iy >= 0 && ix >= 0);
        aoff[s] = (iy * 4 + ix) * 16 + (kg & 1) * 8;
    }

    for (int e = wv; e < NELEM; e += K2_WAVES) {
        const u16* pbase = pooled1b + e * 256;
        bf16x8 a0 = {0,0,0,0,0,0,0,0}, a1 = {0,0,0,0,0,0,0,0};
        if (aok[0]) a0 = *(const bf16x8*)(pbase + aoff[0]);
        if (aok[1]) a1 = *(const bf16x8*)(pbase + aoff[1]);
        f32x4 acc0 = {0.f,0.f,0.f,0.f}, acc1 = {0.f,0.f,0.f,0.f};
        acc0 = __builtin_amdgcn_mfma_f32_16x16x32_bf16(a0, bfrag[0][0], acc0, 0, 0, 0);
        acc1 = __builtin_amdgcn_mfma_f32_16x16x32_bf16(a0, bfrag[0][1], acc1, 0, 0, 0);
        acc0 = __builtin_amdgcn_mfma_f32_16x16x32_bf16(a1, bfrag[1][0], acc0, 0, 0, 0);
        acc1 = __builtin_amdgcn_mfma_f32_16x16x32_bf16(a1, bfrag[1][1], acc1, 0, 0, 0);
        #pragma unroll
        for (int nt = 0; nt < 2; ++nt) {
            f32x4 acc = nt ? acc1 : acc0;
            float b = bias[nt];
            float m0 = fmaxf(fmaxf(acc[0] + b, 0.f), fmaxf(acc[1] + b, 0.f));
            float m1 = fmaxf(fmaxf(acc[2] + b, 0.f), fmaxf(acc[3] + b, 0.f));
            float p0 = fmaxf(m0, __shfl_xor(m0, 16, 64));
            float p1 = fmaxf(m1, __shfl_xor(m1, 16, 64));
            if ((kg & 1) == 0) {
                int q = (kg >> 1) * 2;
                u16* op = pooled2 + e * 128 + nt * 16 + col;
                op[q * 32]       = f2bf(p0);
                op[(q + 1) * 32] = f2bf(p1);
            }
        }
    }
}

// ---------------- K34: fused conv3+relu -> LDS feat -> proj -> comb -----
// Block = 64 elems, 4 waves. Phase 1 = validated k3 tile loop (36 tiles,
// 9/wave), epilogue into LDS featL[64][584] (stride 584 u16 = 292 words
// == 4 mod 32 -> <=2-way banking). Tail cols 576..583 by t<64. Phase 2 =
// validated k4 proj loop with A-frags from LDS. Kills the 76.5 MB feat
// round-trip through HBM.
__global__ __launch_bounds__(256) void k34_conv3_proj(const u16* __restrict__ pooled2,
        const u16* __restrict__ w3r, const float* __restrict__ b3,
        const int* __restrict__ ccol, const int* __restrict__ cobj,
        const u16* __restrict__ pwT, const float* __restrict__ pb,
        float* __restrict__ comb) {
    __shared__ u16 featL[64 * 584];   // 74752 B
    int t = threadIdx.x;
    int l = t & 63;
    int col = l & 15;
    int kg = l >> 4;
    int wv = t >> 6;
    int e0 = blockIdx.x * 64;

    // ---- phase 1: conv3 ----
    {
        bf16x8 bfrag[4][4];
        #pragma unroll
        for (int s = 0; s < 4; ++s)
            #pragma unroll
            for (int nt = 0; nt < 4; ++nt)
                bfrag[s][nt] = *(const bf16x8*)(w3r + (nt * 16 + col) * 128 + s * 32 + kg * 8);
        float bias[4];
        #pragma unroll
        for (int nt = 0; nt < 4; ++nt) bias[nt] = b3[nt * 16 + col];

        for (int i = 0; i < 9; ++i) {
            int m0 = (wv * 9 + i) * 16;
            int m = m0 + col;
            u32 elem = (u32)(((unsigned long long)(u32)m * 954437177ull) >> 33); // m/9
            int p = m - (int)elem * 9;
            int oy = (p * 86) >> 8;
            int ox = p - 3 * oy;
            const u16* pbase = pooled2 + (size_t)(e0 + elem) * 128 + kg * 8;
            f32x4 acc[4];
            #pragma unroll
            for (int nt = 0; nt < 4; ++nt) {
                acc[nt][0] = 0.f; acc[nt][1] = 0.f; acc[nt][2] = 0.f; acc[nt][3] = 0.f;
            }
            #pragma unroll
            for (int s = 0; s < 4; ++s) {
                int ky = s >> 1, kx = s & 1;
                int iy = oy - 1 + ky, ix = ox - 1 + kx;
                bf16x8 a = {0,0,0,0,0,0,0,0};
                if (iy >= 0 && iy <= 1 && ix >= 0 && ix <= 1)
                    a = *(const bf16x8*)(pbase + (iy * 2 + ix) * 32);
                #pragma unroll
                for (int nt = 0; nt < 4; ++nt)
                    acc[nt] = __builtin_amdgcn_mfma_f32_16x16x32_bf16(a, bfrag[s][nt], acc[nt], 0, 0, 0);
            }
            #pragma unroll
            for (int r = 0; r < 4; ++r) {
                int mr = m0 + kg * 4 + r;
                u32 er = (u32)(((unsigned long long)(u32)mr * 954437177ull) >> 33);
                int pr = mr - (int)er * 9;
                u16* fb = featL + er * 584 + pr * 64;
                #pragma unroll
                for (int nt = 0; nt < 4; ++nt)
                    fb[nt * 16 + col] = f2bf(fmaxf(acc[nt][r] + bias[nt], 0.f));
            }
        }
    }
    // ---- tail cols 576..583 ----
    if (t < 64) {
        union { u16 s[8]; uint4 q; } b;
        b.s[0] = f2bf((float)ccol[e0 + t]);
        b.s[1] = f2bf((float)cobj[e0 + t]);
        #pragma unroll
        for (int i = 2; i < 8; ++i) b.s[i] = 0;
        *(uint4*)(featL + t * 584 + 576) = b.q;
    }
    __syncthreads();

    // ---- phase 2: proj (validated k4 body, A from LDS) ----
    int m0g = e0 + wv * 16;
    const u16* arow = featL + (wv * 16 + col) * 584 + kg * 8;
    const u16* brow = pwT + col * 608 + kg * 8;
    f32x4 acc[4];
    #pragma unroll
    for (int i = 0; i < 4; ++i) {
        acc[i][0] = 0.f; acc[i][1] = 0.f; acc[i][2] = 0.f; acc[i][3] = 0.f;
    }
    #pragma unroll 4
    for (int k0 = 0; k0 < 608; k0 += 32) {
        bf16x8 a;
        if (k0 + kg * 8 < 584) {
            a = *(const bf16x8*)(arow + k0);
        } else {
            #pragma unroll
            for (int j = 0; j < 8; ++j) a[j] = 0;
        }
        bf16x8 b0 = *(const bf16x8*)(brow + k0);
        bf16x8 b1 = *(const bf16x8*)(brow + 16 * 608 + k0);
        bf16x8 b2 = *(const bf16x8*)(brow + 32 * 608 + k0);
        bf16x8 b3 = *(const bf16x8*)(brow + 48 * 608 + k0);
        acc[0] = __builtin_amdgcn_mfma_f32_16x16x32_bf16(a, b0, acc[0], 0, 0, 0);
        acc[1] = __builtin_amdgcn_mfma_f32_16x16x32_bf16(a, b1, acc[1], 0, 0, 0);
        acc[2] = __builtin_amdgcn_mfma_f32_16x16x32_bf16(a, b2, acc[2], 0, 0, 0);
        acc[3] = __builtin_amdgcn_mfma_f32_16x16x32_bf16(a, b3, acc[3], 0, 0, 0);
    }
    float* outbase = (m0g < BATCH) ? (comb + (size_t)m0g * 160)
                                   : (comb + (size_t)(m0g - BATCH) * 160 + 64);
    #pragma unroll
    for (int nt = 0; nt < 4; ++nt) {
        float pbv = pb[nt * 16 + col];
        #pragma unroll
        for (int r = 0; r < 4; ++r) {
            outbase[(kg * 4 + r) * 160 + nt * 16 + col] = fmaxf(acc[nt][r] + pbv, 0.f);
        }
    }
}

// ---------------- K5: dir_pos deltas -> comb[b][128..159] --------------
__global__ __launch_bounds__(256) void k5_extras(const int* __restrict__ frame,
        float* __restrict__ comb) {
    int b = blockIdx.x * 256 + threadIdx.x;
    int d[2]; float posy[2], posx[2];
    for (int f = 0; f < 2; ++f) {
        const int* fb = frame + (size_t)(f * BATCH + b) * 147;
        int idx = 49;
        for (int cell = 0; cell < 49; ++cell) {
            int v = fb[cell * 3];
            if (idx == 49 && v == 10) idx = cell;
        }
        if (idx < 49) {
            d[f] = fb[idx * 3 + 2] & 3;
            posy[f] = (float)(idx / 7) / 6.0f;
            posx[f] = (float)(idx % 7) / 6.0f;
        } else {
            d[f] = 0; posy[f] = 0.5f; posx[f] = 0.5f;
        }
    }
    int delta = (d[1] - d[0] + 4) & 3;
    const float ANG = (float)(2.0 * 3.14159 / 4.0);
    float angle = (float)delta * ANG;
    float4 o;
    o.x = sinf(angle);
    o.y = cosf(angle);
    o.z = posy[1] - posy[0];
    o.w = posx[1] - posx[0];
    float* cb = comb + (size_t)b * 160 + 128;
    *(float4*)cb = o;
    float4 z = make_float4(0.f, 0.f, 0.f, 0.f);
    #pragma unroll
    for (int i = 1; i < 8; ++i) *(float4*)(cb + i * 4) = z;
}

__device__ __forceinline__ void split8(const float* __restrict__ x,
                                       bf16x8& hi, bf16x8& lo) {
    #pragma unroll
    for (int j = 0; j < 8; ++j) {
        u16 h = f2bf(x[j]);
        hi[j] = (short)h;
        lo[j] = (short)f2bf(x[j] - bf2f(h));
    }
}

// ---------------- K6a: h1 GEMM via split-bf16 MFMA (no LN) -------------
__global__ __launch_bounds__(256) void k6_h1_gemm(const float* __restrict__ in,
        const u16* __restrict__ whi, const u16* __restrict__ wlo,
        const float* __restrict__ bias, float* __restrict__ out) {
    int t = threadIdx.x;
    int l = t & 63;
    int col = l & 15;
    int kg = l >> 4;
    int m0 = blockIdx.x * 64 + (t >> 6) * 16;
    const float* arow = in + (size_t)(m0 + col) * 160 + kg * 8;
    const u16* bh = whi + col * 160 + kg * 8;
    const u16* bl = wlo + col * 160 + kg * 8;

    f32x4 acc[8];
    #pragma unroll
    for (int nt = 0; nt < 8; ++nt) {
        acc[nt][0] = 0.f; acc[nt][1] = 0.f; acc[nt][2] = 0.f; acc[nt][3] = 0.f;
    }
    #pragma unroll
    for (int s = 0; s < 5; ++s) {
        float x[8];
        #pragma unroll
        for (int j = 0; j < 8; ++j) x[j] = arow[s * 32 + j];
        bf16x8 ahi, alo;
        split8(x, ahi, alo);
        #pragma unroll
        for (int nt = 0; nt < 8; ++nt) {
            bf16x8 bhiF = *(const bf16x8*)(bh + nt * 2560 + s * 32);
            bf16x8 bloF = *(const bf16x8*)(bl + nt * 2560 + s * 32);
            acc[nt] = __builtin_amdgcn_mfma_f32_16x16x32_bf16(ahi, bhiF, acc[nt], 0, 0, 0);
            acc[nt] = __builtin_amdgcn_mfma_f32_16x16x32_bf16(alo, bhiF, acc[nt], 0, 0, 0);
            acc[nt] = __builtin_amdgcn_mfma_f32_16x16x32_bf16(ahi, bloF, acc[nt], 0, 0, 0);
        }
    }
    #pragma unroll
    for (int nt = 0; nt < 8; ++nt) {
        float bv = bias[nt * 16 + col];
        #pragma unroll
        for (int r = 0; r < 4; ++r) {
            int m = m0 + kg * 4 + r;
            out[m * 128 + nt * 16 + col] = acc[nt][r] + bv;
        }
    }
}

// ---------------- K6b: LayerNorm + relu, wave per row ------------------
__global__ __launch_bounds__(256) void k6_ln(const float* __restrict__ h,
        const float* __restrict__ lng, const float* __restrict__ lnb,
        float* __restrict__ out) {
    int w = (blockIdx.x * 256 + threadIdx.x) >> 6;
    int l = threadIdx.x & 63;
    const float* row = h + (size_t)w * 128 + l * 2;
    float2 v = *(const float2*)row;
    float s = v.x + v.y;
    s += __shfl_xor(s, 1, 64);
    s += __shfl_xor(s, 2, 64);
    s += __shfl_xor(s, 4, 64);
    s += __shfl_xor(s, 8, 64);
    s += __shfl_xor(s, 16, 64);
    s += __shfl_xor(s, 32, 64);
    float mu = s * (1.0f / 128.0f);
    float d0 = v.x - mu, d1 = v.y - mu;
    float vs = d0 * d0 + d1 * d1;
    vs += __shfl_xor(vs, 1, 64);
    vs += __shfl_xor(vs, 2, 64);
    vs += __shfl_xor(vs, 4, 64);
    vs += __shfl_xor(vs, 8, 64);
    vs += __shfl_xor(vs, 16, 64);
    vs += __shfl_xor(vs, 32, 64);
    float rs = rsqrtf(vs * (1.0f / 128.0f) + 1e-5f);
    float2 o;
    o.x = fmaxf(d0 * rs * lng[l * 2]     + lnb[l * 2],     0.f);
    o.y = fmaxf(d1 * rs * lng[l * 2 + 1] + lnb[l * 2 + 1], 0.f);
    *(float2*)(out + (size_t)w * 128 + l * 2) = o;
}

// ---------------- K7: h2 via split-bf16 MFMA (fp32 in/out) -------------
__global__ __launch_bounds__(256) void k7_h2_mfma(const float* __restrict__ in,
        const u16* __restrict__ whi, const u16* __restrict__ wlo,
        const float* __restrict__ bias, float* __restrict__ out) {
    int t = threadIdx.x;
    int l = t & 63;
    int col = l & 15;
    int kg = l >> 4;
    int m0 = blockIdx.x * 64 + (t >> 6) * 16;
    const float* arow = in + (size_t)(m0 + col) * 128 + kg * 8;
    const u16* bh = whi + col * 128 + kg * 8;
    const u16* bl = wlo + col * 128 + kg * 8;

    f32x4 acc[8];
    #pragma unroll
    for (int nt = 0; nt < 8; ++nt) {
        acc[nt][0] = 0.f; acc[nt][1] = 0.f; acc[nt][2] = 0.f; acc[nt][3] = 0.f;
    }
    #pragma unroll
    for (int s = 0; s < 4; ++s) {
        float x[8];
        #pragma unroll
        for (int j = 0; j < 8; ++j) x[j] = arow[s * 32 + j];
        bf16x8 ahi, alo;
        split8(x, ahi, alo);
        #pragma unroll
        for (int nt = 0; nt < 8; ++nt) {
            bf16x8 bhiF = *(const bf16x8*)(bh + nt * 2048 + s * 32);
            bf16x8 bloF = *(const bf16x8*)(bl + nt * 2048 + s * 32);
            acc[nt] = __builtin_amdgcn_mfma_f32_16x16x32_bf16(ahi, bhiF, acc[nt], 0, 0, 0);
            acc[nt] = __builtin_amdgcn_mfma_f32_16x16x32_bf16(alo, bhiF, acc[nt], 0, 0, 0);
            acc[nt] = __builtin_amdgcn_mfma_f32_16x16x32_bf16(ahi, bloF, acc[nt], 0, 0, 0);
        }
    }
    #pragma unroll
    for (int nt = 0; nt < 8; ++nt) {
        float bv = bias[nt * 16 + col];
        #pragma unroll
        for (int r = 0; r < 4; ++r) {
            int m = m0 + kg * 4 + r;
            out[m * 128 + nt * 16 + col] = fmaxf(acc[nt][r] + bv, 0.f);
        }
    }
}

// ---------------- K8: h3 [32768x128]@[128->7], thread = row, fp32 ------
__global__ __launch_bounds__(256) void k8_h3(const float* __restrict__ in,
        const float* __restrict__ w, const float* __restrict__ bias,
        float* __restrict__ out) {
    int r = blockIdx.x * 256 + threadIdx.x;
    float acc[7];
    #pragma unroll
    for (int j = 0; j < 7; ++j) acc[j] = bias[j];
    const float* row = in + (size_t)r * 128;
    #pragma unroll 4
    for (int c = 0; c < 32; ++c) {
        float4 v = *(const float4*)(row + c * 4);
        #pragma unroll
        for (int j = 0; j < 7; ++j) {
            acc[j] += v.x * w[j * 128 + c * 4 + 0];
            acc[j] += v.y * w[j * 128 + c * 4 + 1];
            acc[j] += v.z * w[j * 128 + c * 4 + 2];
            acc[j] += v.w * w[j * 128 + c * 4 + 3];
        }
    }
    #pragma unroll
    for (int j = 0; j < 7; ++j) out[r * 7 + j] = acc[j];
}

extern "C" void kernel_launch(void* const* d_in, const int* in_sizes, int n_in,
                              void* d_out, int out_size, void* d_ws, size_t ws_size,
                              hipStream_t stream) {
    const int*   frame = (const int*)d_in[0];
    const int*   ccol  = (const int*)d_in[1];
    const int*   cobj  = (const int*)d_in[2];
    const float* w1    = (const float*)d_in[3];
    const float* b1    = (const float*)d_in[4];
    const float* w2    = (const float*)d_in[5];
    const float* b2    = (const float*)d_in[6];
    const float* w3    = (const float*)d_in[7];
    const float* b3    = (const float*)d_in[8];
    const float* pw    = (const float*)d_in[9];
    const float* pb    = (const float*)d_in[10];
    const float* h1w   = (const float*)d_in[11];
    const float* h1b   = (const float*)d_in[12];
    const float* lng   = (const float*)d_in[13];
    const float* lnb   = (const float*)d_in[14];
    const float* h2w   = (const float*)d_in[15];
    const float* h2b   = (const float*)d_in[16];
    const float* h3w   = (const float*)d_in[17];
    const float* h3b   = (const float*)d_in[18];
    float* out = (float*)d_out;

    char* ws = (char*)d_ws;
    // Region A [0,32MB): pooled1b (k1->k2); then comb fp32 21MB (k34/k5->k6a)
    // Region B [32MB,48MB): pooled2 (k2->k34); then h1out fp32 (k6b->k7)
    // Region C [48MB+): h2out (48..64, k7->k8), h1pre (91..107, k6a->k6b)
    // Region D [126MB+): converted weights (k0 -> consumers)
    u16*   pooled1b = (u16*)(ws + 0);                    // 32 MB
    float* comb     = (float*)(ws + 0);                  // 21 MB (after k2)
    u16*   pooled2  = (u16*)(ws + 33554432);             // 16 MB
    float* h1out    = (float*)(ws + 33554432);           // 16 MB (after k34)
    float* h2out    = (float*)(ws + 50331648);           // 16 MB
    float* h1pre    = (float*)(ws + 95420416);           // 16 MB
    u16*   pwT      = (u16*)(ws + 132120576);            // 77824 B
    u16*   w2r      = (u16*)(ws + 132120576 + 131072);   // 4096 B
    u16*   w3r      = (u16*)(ws + 132120576 + 139264);   // 16384 B
    u16*   h2hi     = (u16*)(ws + 132120576 + 163840);   // 32768 B
    u16*   h2lo     = (u16*)(ws + 132120576 + 196608);   // 32768 B
    u16*   h1hi     = (u16*)(ws + 132120576 + 229376);   // 40960 B
    u16*   h1lo     = (u16*)(ws + 132120576 + 270336);   // 40960 B
    u16*   w1hi     = (u16*)(ws + 132120576 + 311296);   // 1024 B
    u16*   w1lo     = (u16*)(ws + 132120576 + 312320);   // 1024 B

    k0_prep<<<340, 256, 0, stream>>>(pw, w2, w3, h2w, h1w, w1,
                                     pwT, w2r, w3r, h2hi, h2lo, h1hi, h1lo,
                                     w1hi, w1lo);
    k1_conv1_mfma<<<4096, 256, 0, stream>>>(frame, w1hi, w1lo, b1, pooled1b);
    k2_conv2_mfma<<<1024, 256, 0, stream>>>(pooled1b, w2r, b2, pooled2);
    k34_conv3_proj<<<1024, 256, 0, stream>>>(pooled2, w3r, b3, ccol, cobj,
                                             pwT, pb, comb);
    k5_extras<<<128, 256, 0, stream>>>(frame, comb);
    k6_h1_gemm<<<512, 256, 0, stream>>>(comb, h1hi, h1lo, h1b, h1pre);
    k6_ln<<<8192, 256, 0, stream>>>(h1pre, lng, lnb, h1out);
    k7_h2_mfma<<<512, 256, 0, stream>>>(h1out, h2hi, h2lo, h2b, h2out);
    k8_h3<<<128, 256, 0, stream>>>(h2out, h3w, h3b, out);
}

// Round 16
// 274.123 us; speedup vs baseline: 1.1271x; 1.0202x over previous
//
#include <hip/hip_runtime.h>
#include <hip/hip_bf16.h>

#define BATCH 32768
#define NELEM 65536   // 2 * BATCH

typedef unsigned short u16;
typedef unsigned int u32;
typedef __attribute__((ext_vector_type(8))) short bf16x8;
typedef __attribute__((ext_vector_type(4))) float f32x4;

__device__ __forceinline__ float bf2f(u16 u) {
    union { u32 u; float f; } c; c.u = ((u32)u) << 16; return c.f;
}
__device__ __forceinline__ u16 f2bf(float f) {
    union { float f; u32 u; } c; c.f = f;
    u32 x = c.u;
    u32 r = (x + 0x7fffu + ((x >> 16) & 1u)) >> 16;  // RNE
    return (u16)r;
}

// ---------------- K0: weight prep ---------------------------------------
__global__ __launch_bounds__(256) void k0_prep(const float* __restrict__ pw,
        const float* __restrict__ w2, const float* __restrict__ w3,
        const float* __restrict__ h2w, const float* __restrict__ h1w,
        const float* __restrict__ w1,
        u16* __restrict__ pwT, u16* __restrict__ w2r, u16* __restrict__ w3r,
        u16* __restrict__ h2hi, u16* __restrict__ h2lo,
        u16* __restrict__ h1hi, u16* __restrict__ h1lo,
        u16* __restrict__ w1hi, u16* __restrict__ w1lo) {
    int idx = blockIdx.x * 256 + threadIdx.x;
    if (idx < 38912) {
        int j = idx / 608, kk = idx - j * 608;
        float v = 0.f;
        if (kk < 576) {
            int p = kk >> 6, oc = kk & 63;
            v = pw[j * 578 + oc * 9 + p];
        } else if (kk < 578) {
            v = pw[j * 578 + kk];
        }
        pwT[idx] = f2bf(v);
    } else if (idx < 40960) {
        int i = idx - 38912;
        int oc = i >> 6, rem = i & 63, tap = rem >> 4, ic = rem & 15;
        w2r[i] = f2bf(w2[oc * 64 + ic * 4 + tap]);
    } else if (idx < 49152) {
        int i = idx - 40960;
        int oc = i >> 7, rem = i & 127, tap = rem >> 5, ic = rem & 31;
        w3r[i] = f2bf(w3[oc * 128 + ic * 4 + tap]);
    } else if (idx < 65536) {
        int i = idx - 49152;
        float v = h2w[i];
        u16 hi = f2bf(v);
        h2hi[i] = hi;
        h2lo[i] = f2bf(v - bf2f(hi));
    } else if (idx < 86016) {
        int i = idx - 65536;
        int j = i / 160, k = i - j * 160;
        float v = (k < 132) ? h1w[j * 132 + k] : 0.f;
        u16 hi = f2bf(v);
        h1hi[i] = hi;
        h1lo[i] = f2bf(v - bf2f(hi));
    } else if (idx < 86528) {
        int i = idx - 86016;               // [oc16][k32]
        int oc = i >> 5, k = i & 31;
        int ky = k >> 4, kx = (k >> 3) & 1, c = k & 7;
        float v = (c < 3) ? w1[oc * 12 + c * 4 + ky * 2 + kx] : 0.f;
        u16 hi = f2bf(v);
        w1hi[i] = hi;
        w1lo[i] = f2bf(v - bf2f(hi));
    }
}

// ---------------- K1: conv1+relu+maxpool via MFMA ----------------------
__global__ __launch_bounds__(256) void k1_conv1_mfma(const int* __restrict__ frame,
        const u16* __restrict__ w1hi, const u16* __restrict__ w1lo,
        const float* __restrict__ b1, u16* __restrict__ pooled1b) {
    __shared__ u16 fr[16 * 656];   // [elem][(y)*72 + (x)*8 + c], padded 9x9
    int t = threadIdx.x;
    int e0 = blockIdx.x * 16;
    #pragma unroll
    for (int i = 0; i < 6; ++i) {
        int o = i * 256 + t;
        if (o < 1312) *(uint4*)(fr + o * 8) = make_uint4(0u, 0u, 0u, 0u);
    }
    __syncthreads();
    #pragma unroll
    for (int i = 0; i < 10; ++i) {
        int idx = i * 256 + t;
        if (idx < 2352) {
            int le = idx / 147, r = idx - le * 147;
            int cell = r / 3, c = r - cell * 3;
            int y = cell / 7, x = cell - y * 7;
            fr[le * 656 + (y + 1) * 72 + (x + 1) * 8 + c] = f2bf((float)frame[e0 * 147 + idx]);
        }
    }
    __syncthreads();
    int l = t & 63;
    int wv = t >> 6;
    int col = l & 15;
    int kg = l >> 4;
    bf16x8 bhi = *(const bf16x8*)(w1hi + col * 32 + kg * 8);
    bf16x8 blo = *(const bf16x8*)(w1lo + col * 32 + kg * 8);
    float bias = b1[col];
    int ky = kg >> 1, kx = kg & 1;
    bool writer = (kg < 2);
    #pragma unroll
    for (int q = 0; q < 4; ++q) {
        int le = wv * 4 + q;
        const u16* eb = fr + le * 656;
        u16* op = pooled1b + (size_t)(e0 + le) * 256;
        #pragma unroll
        for (int mt = 0; mt < 4; ++mt) {
            int posA = mt * 16 + col;
            int oy = posA >> 3, ox = posA & 7;
            bf16x8 a = *(const bf16x8*)(eb + (oy + ky) * 72 + (ox + kx) * 8);
            f32x4 acc = {0.f, 0.f, 0.f, 0.f};
            acc = __builtin_amdgcn_mfma_f32_16x16x32_bf16(a, bhi, acc, 0, 0, 0);
            acc = __builtin_amdgcn_mfma_f32_16x16x32_bf16(a, blo, acc, 0, 0, 0);
            float x0 = fmaxf(acc[0] + bias, 0.f);
            float x1 = fmaxf(acc[1] + bias, 0.f);
            float x2 = fmaxf(acc[2] + bias, 0.f);
            float x3 = fmaxf(acc[3] + bias, 0.f);
            float y0 = fmaxf(x0, x1);
            float y1 = fmaxf(x2, x3);
            float m0 = fmaxf(y0, __shfl_xor(y0, 32, 64));
            float m1 = fmaxf(y1, __shfl_xor(y1, 32, 64));
            if (writer) {
                op[(mt * 4 + kg * 2 + 0) * 16 + col] = f2bf(m0);
                op[(mt * 4 + kg * 2 + 1) * 16 + col] = f2bf(m1);
            }
        }
    }
}

// ---------------- K2: conv2+relu+maxpool fused via MFMA, LDS-free ------
#define K2_WAVES 4096
__global__ __launch_bounds__(256) void k2_conv2_mfma(const u16* __restrict__ pooled1b,
        const u16* __restrict__ w2r, const float* __restrict__ b2,
        u16* __restrict__ pooled2) {
    int t = threadIdx.x;
    int l = t & 63;
    int col = l & 15;
    int kg = l >> 4;
    int wv = (blockIdx.x * 256 + t) >> 6;

    bf16x8 bfrag[2][2];
    #pragma unroll
    for (int s = 0; s < 2; ++s)
        #pragma unroll
        for (int nt = 0; nt < 2; ++nt)
            bfrag[s][nt] = *(const bf16x8*)(w2r + (nt * 16 + col) * 64 + s * 32 + kg * 8);
    float bias[2] = { b2[col], b2[16 + col] };

    int oy = col >> 2, ox = col & 3;
    int aoff[2]; bool aok[2];
    #pragma unroll
    for (int s = 0; s < 2; ++s) {
        int tap = 2 * s + (kg >> 1);
        int ky = tap >> 1, kx = tap & 1;
        int iy = oy - 1 + ky, ix = ox - 1 + kx;
        aok[s] = (iy >= 0 && ix >= 0);
        aoff[s] = (iy * 4 + ix) * 16 + (kg & 1) * 8;
    }

    for (int e = wv; e < NELEM; e += K2_WAVES) {
        const u16* pbase = pooled1b + e * 256;
        bf16x8 a0 = {0,0,0,0,0,0,0,0}, a1 = {0,0,0,0,0,0,0,0};
        if (aok[0]) a0 = *(const bf16x8*)(pbase + aoff[0]);
        if (aok[1]) a1 = *(const bf16x8*)(pbase + aoff[1]);
        f32x4 acc0 = {0.f,0.f,0.f,0.f}, acc1 = {0.f,0.f,0.f,0.f};
        acc0 = __builtin_amdgcn_mfma_f32_16x16x32_bf16(a0, bfrag[0][0], acc0, 0, 0, 0);
        acc1 = __builtin_amdgcn_mfma_f32_16x16x32_bf16(a0, bfrag[0][1], acc1, 0, 0, 0);
        acc0 = __builtin_amdgcn_mfma_f32_16x16x32_bf16(a1, bfrag[1][0], acc0, 0, 0, 0);
        acc1 = __builtin_amdgcn_mfma_f32_16x16x32_bf16(a1, bfrag[1][1], acc1, 0, 0, 0);
        #pragma unroll
        for (int nt = 0; nt < 2; ++nt) {
            f32x4 acc = nt ? acc1 : acc0;
            float b = bias[nt];
            float m0 = fmaxf(fmaxf(acc[0] + b, 0.f), fmaxf(acc[1] + b, 0.f));
            float m1 = fmaxf(fmaxf(acc[2] + b, 0.f), fmaxf(acc[3] + b, 0.f));
            float p0 = fmaxf(m0, __shfl_xor(m0, 16, 64));
            float p1 = fmaxf(m1, __shfl_xor(m1, 16, 64));
            if ((kg & 1) == 0) {
                int q = (kg >> 1) * 2;
                u16* op = pooled2 + e * 128 + nt * 16 + col;
                op[q * 32]       = f2bf(p0);
                op[(q + 1) * 32] = f2bf(p1);
            }
        }
    }
}

// ---------------- K34: fused conv3 -> LDS feat -> proj -> comb ---------
// Block = 32 elems (featL 37376 B -> 4 blocks/CU, 16 waves/CU; R15's
// 64-elem version capped at 2 blocks/CU = latency-bound at 19% occ).
// Phase 1: 18 tiles strided over 4 waves. Phase 2: wave = (row-half,
// n-half): 16 rows x 2 n-tiles. Same math as validated k3/k4.
__global__ __launch_bounds__(256) void k34_conv3_proj(const u16* __restrict__ pooled2,
        const u16* __restrict__ w3r, const float* __restrict__ b3,
        const int* __restrict__ ccol, const int* __restrict__ cobj,
        const u16* __restrict__ pwT, const float* __restrict__ pb,
        float* __restrict__ comb) {
    __shared__ u16 featL[32 * 584];   // 37376 B
    int t = threadIdx.x;
    int l = t & 63;
    int col = l & 15;
    int kg = l >> 4;
    int wv = t >> 6;
    int e0 = blockIdx.x * 32;

    // ---- phase 1: conv3 (18 tiles, strided over waves) ----
    {
        bf16x8 bfrag[4][4];
        #pragma unroll
        for (int s = 0; s < 4; ++s)
            #pragma unroll
            for (int nt = 0; nt < 4; ++nt)
                bfrag[s][nt] = *(const bf16x8*)(w3r + (nt * 16 + col) * 128 + s * 32 + kg * 8);
        float bias[4];
        #pragma unroll
        for (int nt = 0; nt < 4; ++nt) bias[nt] = b3[nt * 16 + col];

        for (int i = wv; i < 18; i += 4) {
            int m0 = i * 16;
            int m = m0 + col;
            u32 elem = (u32)(((unsigned long long)(u32)m * 954437177ull) >> 33); // m/9
            int p = m - (int)elem * 9;
            int oy = (p * 86) >> 8;
            int ox = p - 3 * oy;
            const u16* pbase = pooled2 + (size_t)(e0 + elem) * 128 + kg * 8;
            f32x4 acc[4];
            #pragma unroll
            for (int nt = 0; nt < 4; ++nt) {
                acc[nt][0] = 0.f; acc[nt][1] = 0.f; acc[nt][2] = 0.f; acc[nt][3] = 0.f;
            }
            #pragma unroll
            for (int s = 0; s < 4; ++s) {
                int ky = s >> 1, kx = s & 1;
                int iy = oy - 1 + ky, ix = ox - 1 + kx;
                bf16x8 a = {0,0,0,0,0,0,0,0};
                if (iy >= 0 && iy <= 1 && ix >= 0 && ix <= 1)
                    a = *(const bf16x8*)(pbase + (iy * 2 + ix) * 32);
                #pragma unroll
                for (int nt = 0; nt < 4; ++nt)
                    acc[nt] = __builtin_amdgcn_mfma_f32_16x16x32_bf16(a, bfrag[s][nt], acc[nt], 0, 0, 0);
            }
            #pragma unroll
            for (int r = 0; r < 4; ++r) {
                int mr = m0 + kg * 4 + r;
                u32 er = (u32)(((unsigned long long)(u32)mr * 954437177ull) >> 33);
                int pr = mr - (int)er * 9;
                u16* fb = featL + er * 584 + pr * 64;
                #pragma unroll
                for (int nt = 0; nt < 4; ++nt)
                    fb[nt * 16 + col] = f2bf(fmaxf(acc[nt][r] + bias[nt], 0.f));
            }
        }
    }
    // ---- tail cols 576..583 ----
    if (t < 32) {
        union { u16 s[8]; uint4 q; } b;
        b.s[0] = f2bf((float)ccol[e0 + t]);
        b.s[1] = f2bf((float)cobj[e0 + t]);
        #pragma unroll
        for (int i = 2; i < 8; ++i) b.s[i] = 0;
        *(uint4*)(featL + t * 584 + 576) = b.q;
    }
    __syncthreads();

    // ---- phase 2: proj; wave = (row-half rh, n-half nh) ----
    int rh = wv & 1, nh = wv >> 1;
    int m0g = e0 + rh * 16;
    const u16* arow = featL + (rh * 16 + col) * 584 + kg * 8;
    const u16* brow = pwT + (nh * 32 + col) * 608 + kg * 8;
    f32x4 acc0 = {0.f,0.f,0.f,0.f}, acc1 = {0.f,0.f,0.f,0.f};
    #pragma unroll 4
    for (int k0 = 0; k0 < 608; k0 += 32) {
        bf16x8 a;
        if (k0 + kg * 8 < 584) {
            a = *(const bf16x8*)(arow + k0);
        } else {
            #pragma unroll
            for (int j = 0; j < 8; ++j) a[j] = 0;
        }
        bf16x8 b0 = *(const bf16x8*)(brow + k0);
        bf16x8 b1 = *(const bf16x8*)(brow + 16 * 608 + k0);
        acc0 = __builtin_amdgcn_mfma_f32_16x16x32_bf16(a, b0, acc0, 0, 0, 0);
        acc1 = __builtin_amdgcn_mfma_f32_16x16x32_bf16(a, b1, acc1, 0, 0, 0);
    }
    float* outbase = (m0g < BATCH) ? (comb + (size_t)m0g * 160)
                                   : (comb + (size_t)(m0g - BATCH) * 160 + 64);
    #pragma unroll
    for (int nt = 0; nt < 2; ++nt) {
        int n = nh * 32 + nt * 16 + col;
        float pbv = pb[n];
        f32x4 acc = nt ? acc1 : acc0;
        #pragma unroll
        for (int r = 0; r < 4; ++r) {
            outbase[(kg * 4 + r) * 160 + n] = fmaxf(acc[r] + pbv, 0.f);
        }
    }
}

// ---------------- K5: dir_pos deltas -> comb[b][128..159] --------------
__global__ __launch_bounds__(256) void k5_extras(const int* __restrict__ frame,
        float* __restrict__ comb) {
    int b = blockIdx.x * 256 + threadIdx.x;
    int d[2]; float posy[2], posx[2];
    for (int f = 0; f < 2; ++f) {
        const int* fb = frame + (size_t)(f * BATCH + b) * 147;
        int idx = 49;
        for (int cell = 0; cell < 49; ++cell) {
            int v = fb[cell * 3];
            if (idx == 49 && v == 10) idx = cell;
        }
        if (idx < 49) {
            d[f] = fb[idx * 3 + 2] & 3;
            posy[f] = (float)(idx / 7) / 6.0f;
            posx[f] = (float)(idx % 7) / 6.0f;
        } else {
            d[f] = 0; posy[f] = 0.5f; posx[f] = 0.5f;
        }
    }
    int delta = (d[1] - d[0] + 4) & 3;
    const float ANG = (float)(2.0 * 3.14159 / 4.0);
    float angle = (float)delta * ANG;
    float4 o;
    o.x = sinf(angle);
    o.y = cosf(angle);
    o.z = posy[1] - posy[0];
    o.w = posx[1] - posx[0];
    float* cb = comb + (size_t)b * 160 + 128;
    *(float4*)cb = o;
    float4 z = make_float4(0.f, 0.f, 0.f, 0.f);
    #pragma unroll
    for (int i = 1; i < 8; ++i) *(float4*)(cb + i * 4) = z;
}

__device__ __forceinline__ void split8(const float* __restrict__ x,
                                       bf16x8& hi, bf16x8& lo) {
    #pragma unroll
    for (int j = 0; j < 8; ++j) {
        u16 h = f2bf(x[j]);
        hi[j] = (short)h;
        lo[j] = (short)f2bf(x[j] - bf2f(h));
    }
}

// ---------------- K6a: h1 GEMM via split-bf16 MFMA (no LN) -------------
__global__ __launch_bounds__(256) void k6_h1_gemm(const float* __restrict__ in,
        const u16* __restrict__ whi, const u16* __restrict__ wlo,
        const float* __restrict__ bias, float* __restrict__ out) {
    int t = threadIdx.x;
    int l = t & 63;
    int col = l & 15;
    int kg = l >> 4;
    int m0 = blockIdx.x * 64 + (t >> 6) * 16;
    const float* arow = in + (size_t)(m0 + col) * 160 + kg * 8;
    const u16* bh = whi + col * 160 + kg * 8;
    const u16* bl = wlo + col * 160 + kg * 8;

    f32x4 acc[8];
    #pragma unroll
    for (int nt = 0; nt < 8; ++nt) {
        acc[nt][0] = 0.f; acc[nt][1] = 0.f; acc[nt][2] = 0.f; acc[nt][3] = 0.f;
    }
    #pragma unroll
    for (int s = 0; s < 5; ++s) {
        float x[8];
        #pragma unroll
        for (int j = 0; j < 8; ++j) x[j] = arow[s * 32 + j];
        bf16x8 ahi, alo;
        split8(x, ahi, alo);
        #pragma unroll
        for (int nt = 0; nt < 8; ++nt) {
            bf16x8 bhiF = *(const bf16x8*)(bh + nt * 2560 + s * 32);
            bf16x8 bloF = *(const bf16x8*)(bl + nt * 2560 + s * 32);
            acc[nt] = __builtin_amdgcn_mfma_f32_16x16x32_bf16(ahi, bhiF, acc[nt], 0, 0, 0);
            acc[nt] = __builtin_amdgcn_mfma_f32_16x16x32_bf16(alo, bhiF, acc[nt], 0, 0, 0);
            acc[nt] = __builtin_amdgcn_mfma_f32_16x16x32_bf16(ahi, bloF, acc[nt], 0, 0, 0);
        }
    }
    #pragma unroll
    for (int nt = 0; nt < 8; ++nt) {
        float bv = bias[nt * 16 + col];
        #pragma unroll
        for (int r = 0; r < 4; ++r) {
            int m = m0 + kg * 4 + r;
            out[m * 128 + nt * 16 + col] = acc[nt][r] + bv;
        }
    }
}

// ---------------- K6b: LayerNorm + relu, wave per row ------------------
__global__ __launch_bounds__(256) void k6_ln(const float* __restrict__ h,
        const float* __restrict__ lng, const float* __restrict__ lnb,
        float* __restrict__ out) {
    int w = (blockIdx.x * 256 + threadIdx.x) >> 6;
    int l = threadIdx.x & 63;
    const float* row = h + (size_t)w * 128 + l * 2;
    float2 v = *(const float2*)row;
    float s = v.x + v.y;
    s += __shfl_xor(s, 1, 64);
    s += __shfl_xor(s, 2, 64);
    s += __shfl_xor(s, 4, 64);
    s += __shfl_xor(s, 8, 64);
    s += __shfl_xor(s, 16, 64);
    s += __shfl_xor(s, 32, 64);
    float mu = s * (1.0f / 128.0f);
    float d0 = v.x - mu, d1 = v.y - mu;
    float vs = d0 * d0 + d1 * d1;
    vs += __shfl_xor(vs, 1, 64);
    vs += __shfl_xor(vs, 2, 64);
    vs += __shfl_xor(vs, 4, 64);
    vs += __shfl_xor(vs, 8, 64);
    vs += __shfl_xor(vs, 16, 64);
    vs += __shfl_xor(vs, 32, 64);
    float rs = rsqrtf(vs * (1.0f / 128.0f) + 1e-5f);
    float2 o;
    o.x = fmaxf(d0 * rs * lng[l * 2]     + lnb[l * 2],     0.f);
    o.y = fmaxf(d1 * rs * lng[l * 2 + 1] + lnb[l * 2 + 1], 0.f);
    *(float2*)(out + (size_t)w * 128 + l * 2) = o;
}

// ---------------- K7: h2 via split-bf16 MFMA (fp32 in/out) -------------
__global__ __launch_bounds__(256) void k7_h2_mfma(const float* __restrict__ in,
        const u16* __restrict__ whi, const u16* __restrict__ wlo,
        const float* __restrict__ bias, float* __restrict__ out) {
    int t = threadIdx.x;
    int l = t & 63;
    int col = l & 15;
    int kg = l >> 4;
    int m0 = blockIdx.x * 64 + (t >> 6) * 16;
    const float* arow = in + (size_t)(m0 + col) * 128 + kg * 8;
    const u16* bh = whi + col * 128 + kg * 8;
    const u16* bl = wlo + col * 128 + kg * 8;

    f32x4 acc[8];
    #pragma unroll
    for (int nt = 0; nt < 8; ++nt) {
        acc[nt][0] = 0.f; acc[nt][1] = 0.f; acc[nt][2] = 0.f; acc[nt][3] = 0.f;
    }
    #pragma unroll
    for (int s = 0; s < 4; ++s) {
        float x[8];
        #pragma unroll
        for (int j = 0; j < 8; ++j) x[j] = arow[s * 32 + j];
        bf16x8 ahi, alo;
        split8(x, ahi, alo);
        #pragma unroll
        for (int nt = 0; nt < 8; ++nt) {
            bf16x8 bhiF = *(const bf16x8*)(bh + nt * 2048 + s * 32);
            bf16x8 bloF = *(const bf16x8*)(bl + nt * 2048 + s * 32);
            acc[nt] = __builtin_amdgcn_mfma_f32_16x16x32_bf16(ahi, bhiF, acc[nt], 0, 0, 0);
            acc[nt] = __builtin_amdgcn_mfma_f32_16x16x32_bf16(alo, bhiF, acc[nt], 0, 0, 0);
            acc[nt] = __builtin_amdgcn_mfma_f32_16x16x32_bf16(ahi, bloF, acc[nt], 0, 0, 0);
        }
    }
    #pragma unroll
    for (int nt = 0; nt < 8; ++nt) {
        float bv = bias[nt * 16 + col];
        #pragma unroll
        for (int r = 0; r < 4; ++r) {
            int m = m0 + kg * 4 + r;
            out[m * 128 + nt * 16 + col] = fmaxf(acc[nt][r] + bv, 0.f);
        }
    }
}

// ---------------- K8: h3 [32768x128]@[128->7], thread = row, fp32 ------
__global__ __launch_bounds__(256) void k8_h3(const float* __restrict__ in,
        const float* __restrict__ w, const float* __restrict__ bias,
        float* __restrict__ out) {
    int r = blockIdx.x * 256 + threadIdx.x;
    float acc[7];
    #pragma unroll
    for (int j = 0; j < 7; ++j) acc[j] = bias[j];
    const float* row = in + (size_t)r * 128;
    #pragma unroll 4
    for (int c = 0; c < 32; ++c) {
        float4 v = *(const float4*)(row + c * 4);
        #pragma unroll
        for (int j = 0; j < 7; ++j) {
            acc[j] += v.x * w[j * 128 + c * 4 + 0];
            acc[j] += v.y * w[j * 128 + c * 4 + 1];
            acc[j] += v.z * w[j * 128 + c * 4 + 2];
            acc[j] += v.w * w[j * 128 + c * 4 + 3];
        }
    }
    #pragma unroll
    for (int j = 0; j < 7; ++j) out[r * 7 + j] = acc[j];
}

extern "C" void kernel_launch(void* const* d_in, const int* in_sizes, int n_in,
                              void* d_out, int out_size, void* d_ws, size_t ws_size,
                              hipStream_t stream) {
    const int*   frame = (const int*)d_in[0];
    const int*   ccol  = (const int*)d_in[1];
    const int*   cobj  = (const int*)d_in[2];
    const float* w1    = (const float*)d_in[3];
    const float* b1    = (const float*)d_in[4];
    const float* w2    = (const float*)d_in[5];
    const float* b2    = (const float*)d_in[6];
    const float* w3    = (const float*)d_in[7];
    const float* b3    = (const float*)d_in[8];
    const float* pw    = (const float*)d_in[9];
    const float* pb    = (const float*)d_in[10];
    const float* h1w   = (const float*)d_in[11];
    const float* h1b   = (const float*)d_in[12];
    const float* lng   = (const float*)d_in[13];
    const float* lnb   = (const float*)d_in[14];
    const float* h2w   = (const float*)d_in[15];
    const float* h2b   = (const float*)d_in[16];
    const float* h3w   = (const float*)d_in[17];
    const float* h3b   = (const float*)d_in[18];
    float* out = (float*)d_out;

    char* ws = (char*)d_ws;
    u16*   pooled1b = (u16*)(ws + 0);                    // 32 MB
    float* comb     = (float*)(ws + 0);                  // 21 MB (after k2)
    u16*   pooled2  = (u16*)(ws + 33554432);             // 16 MB
    float* h1out    = (float*)(ws + 33554432);           // 16 MB (after k34)
    float* h2out    = (float*)(ws + 50331648);           // 16 MB
    float* h1pre    = (float*)(ws + 95420416);           // 16 MB
    u16*   pwT      = (u16*)(ws + 132120576);            // 77824 B
    u16*   w2r      = (u16*)(ws + 132120576 + 131072);   // 4096 B
    u16*   w3r      = (u16*)(ws + 132120576 + 139264);   // 16384 B
    u16*   h2hi     = (u16*)(ws + 132120576 + 163840);   // 32768 B
    u16*   h2lo     = (u16*)(ws + 132120576 + 196608);   // 32768 B
    u16*   h1hi     = (u16*)(ws + 132120576 + 229376);   // 40960 B
    u16*   h1lo     = (u16*)(ws + 132120576 + 270336);   // 40960 B
    u16*   w1hi     = (u16*)(ws + 132120576 + 311296);   // 1024 B
    u16*   w1lo     = (u16*)(ws + 132120576 + 312320);   // 1024 B

    k0_prep<<<340, 256, 0, stream>>>(pw, w2, w3, h2w, h1w, w1,
                                     pwT, w2r, w3r, h2hi, h2lo, h1hi, h1lo,
                                     w1hi, w1lo);
    k1_conv1_mfma<<<4096, 256, 0, stream>>>(frame, w1hi, w1lo, b1, pooled1b);
    k2_conv2_mfma<<<1024, 256, 0, stream>>>(pooled1b, w2r, b2, pooled2);
    k34_conv3_proj<<<2048, 256, 0, stream>>>(pooled2, w3r, b3, ccol, cobj,
                                             pwT, pb, comb);
    k5_extras<<<128, 256, 0, stream>>>(frame, comb);
    k6_h1_gemm<<<512, 256, 0, stream>>>(comb, h1hi, h1lo, h1b, h1pre);
    k6_ln<<<8192, 256, 0, stream>>>(h1pre, lng, lnb, h1out);
    k7_h2_mfma<<<512, 256, 0, stream>>>(h1out, h2hi, h2lo, h2b, h2out);
    k8_h3<<<128, 256, 0, stream>>>(h2out, h3w, h3b, out);
}

// Round 17
// 271.898 us; speedup vs baseline: 1.1363x; 1.0082x over previous
//
#include <hip/hip_runtime.h>
#include <hip/hip_bf16.h>

#define BATCH 32768
#define NELEM 65536   // 2 * BATCH

typedef unsigned short u16;
typedef unsigned int u32;
typedef __attribute__((ext_vector_type(8))) short bf16x8;
typedef __attribute__((ext_vector_type(4))) float f32x4;

__device__ __forceinline__ float bf2f(u16 u) {
    union { u32 u; float f; } c; c.u = ((u32)u) << 16; return c.f;
}
__device__ __forceinline__ u16 f2bf(float f) {
    union { float f; u32 u; } c; c.f = f;
    u32 x = c.u;
    u32 r = (x + 0x7fffu + ((x >> 16) & 1u)) >> 16;  // RNE
    return (u16)r;
}

// ---------------- K0: weight prep ---------------------------------------
__global__ __launch_bounds__(256) void k0_prep(const float* __restrict__ pw,
        const float* __restrict__ w2, const float* __restrict__ w3,
        const float* __restrict__ h2w, const float* __restrict__ h1w,
        const float* __restrict__ w1,
        u16* __restrict__ pwT, u16* __restrict__ w2r, u16* __restrict__ w3r,
        u16* __restrict__ h2hi, u16* __restrict__ h2lo,
        u16* __restrict__ h1hi, u16* __restrict__ h1lo,
        u16* __restrict__ w1hi, u16* __restrict__ w1lo) {
    int idx = blockIdx.x * 256 + threadIdx.x;
    if (idx < 38912) {
        int j = idx / 608, kk = idx - j * 608;
        float v = 0.f;
        if (kk < 576) {
            int p = kk >> 6, oc = kk & 63;
            v = pw[j * 578 + oc * 9 + p];
        } else if (kk < 578) {
            v = pw[j * 578 + kk];
        }
        pwT[idx] = f2bf(v);
    } else if (idx < 40960) {
        int i = idx - 38912;
        int oc = i >> 6, rem = i & 63, tap = rem >> 4, ic = rem & 15;
        w2r[i] = f2bf(w2[oc * 64 + ic * 4 + tap]);
    } else if (idx < 49152) {
        int i = idx - 40960;
        int oc = i >> 7, rem = i & 127, tap = rem >> 5, ic = rem & 31;
        w3r[i] = f2bf(w3[oc * 128 + ic * 4 + tap]);
    } else if (idx < 65536) {
        int i = idx - 49152;
        float v = h2w[i];
        u16 hi = f2bf(v);
        h2hi[i] = hi;
        h2lo[i] = f2bf(v - bf2f(hi));
    } else if (idx < 86016) {
        int i = idx - 65536;
        int j = i / 160, k = i - j * 160;
        float v = (k < 132) ? h1w[j * 132 + k] : 0.f;
        u16 hi = f2bf(v);
        h1hi[i] = hi;
        h1lo[i] = f2bf(v - bf2f(hi));
    } else if (idx < 86528) {
        int i = idx - 86016;               // [oc16][k32]
        int oc = i >> 5, k = i & 31;
        int ky = k >> 4, kx = (k >> 3) & 1, c = k & 7;
        float v = (c < 3) ? w1[oc * 12 + c * 4 + ky * 2 + kx] : 0.f;
        u16 hi = f2bf(v);
        w1hi[i] = hi;
        w1lo[i] = f2bf(v - bf2f(hi));
    }
}

// ---------------- K1: conv1+relu+maxpool via MFMA ----------------------
__global__ __launch_bounds__(256) void k1_conv1_mfma(const int* __restrict__ frame,
        const u16* __restrict__ w1hi, const u16* __restrict__ w1lo,
        const float* __restrict__ b1, u16* __restrict__ pooled1b) {
    __shared__ u16 fr[16 * 656];   // [elem][(y)*72 + (x)*8 + c], padded 9x9
    int t = threadIdx.x;
    int e0 = blockIdx.x * 16;
    #pragma unroll
    for (int i = 0; i < 6; ++i) {
        int o = i * 256 + t;
        if (o < 1312) *(uint4*)(fr + o * 8) = make_uint4(0u, 0u, 0u, 0u);
    }
    __syncthreads();
    #pragma unroll
    for (int i = 0; i < 10; ++i) {
        int idx = i * 256 + t;
        if (idx < 2352) {
            int le = idx / 147, r = idx - le * 147;
            int cell = r / 3, c = r - cell * 3;
            int y = cell / 7, x = cell - y * 7;
            fr[le * 656 + (y + 1) * 72 + (x + 1) * 8 + c] = f2bf((float)frame[e0 * 147 + idx]);
        }
    }
    __syncthreads();
    int l = t & 63;
    int wv = t >> 6;
    int col = l & 15;
    int kg = l >> 4;
    bf16x8 bhi = *(const bf16x8*)(w1hi + col * 32 + kg * 8);
    bf16x8 blo = *(const bf16x8*)(w1lo + col * 32 + kg * 8);
    float bias = b1[col];
    int ky = kg >> 1, kx = kg & 1;
    bool writer = (kg < 2);
    #pragma unroll
    for (int q = 0; q < 4; ++q) {
        int le = wv * 4 + q;
        const u16* eb = fr + le * 656;
        u16* op = pooled1b + (size_t)(e0 + le) * 256;
        #pragma unroll
        for (int mt = 0; mt < 4; ++mt) {
            int posA = mt * 16 + col;
            int oy = posA >> 3, ox = posA & 7;
            bf16x8 a = *(const bf16x8*)(eb + (oy + ky) * 72 + (ox + kx) * 8);
            f32x4 acc = {0.f, 0.f, 0.f, 0.f};
            acc = __builtin_amdgcn_mfma_f32_16x16x32_bf16(a, bhi, acc, 0, 0, 0);
            acc = __builtin_amdgcn_mfma_f32_16x16x32_bf16(a, blo, acc, 0, 0, 0);
            float x0 = fmaxf(acc[0] + bias, 0.f);
            float x1 = fmaxf(acc[1] + bias, 0.f);
            float x2 = fmaxf(acc[2] + bias, 0.f);
            float x3 = fmaxf(acc[3] + bias, 0.f);
            float y0 = fmaxf(x0, x1);
            float y1 = fmaxf(x2, x3);
            float m0 = fmaxf(y0, __shfl_xor(y0, 32, 64));
            float m1 = fmaxf(y1, __shfl_xor(y1, 32, 64));
            if (writer) {
                op[(mt * 4 + kg * 2 + 0) * 16 + col] = f2bf(m0);
                op[(mt * 4 + kg * 2 + 1) * 16 + col] = f2bf(m1);
            }
        }
    }
}

// ---------------- K2: conv2+relu+maxpool fused via MFMA, LDS-free ------
#define K2_WAVES 4096
__global__ __launch_bounds__(256) void k2_conv2_mfma(const u16* __restrict__ pooled1b,
        const u16* __restrict__ w2r, const float* __restrict__ b2,
        u16* __restrict__ pooled2) {
    int t = threadIdx.x;
    int l = t & 63;
    int col = l & 15;
    int kg = l >> 4;
    int wv = (blockIdx.x * 256 + t) >> 6;

    bf16x8 bfrag[2][2];
    #pragma unroll
    for (int s = 0; s < 2; ++s)
        #pragma unroll
        for (int nt = 0; nt < 2; ++nt)
            bfrag[s][nt] = *(const bf16x8*)(w2r + (nt * 16 + col) * 64 + s * 32 + kg * 8);
    float bias[2] = { b2[col], b2[16 + col] };

    int oy = col >> 2, ox = col & 3;
    int aoff[2]; bool aok[2];
    #pragma unroll
    for (int s = 0; s < 2; ++s) {
        int tap = 2 * s + (kg >> 1);
        int ky = tap >> 1, kx = tap & 1;
        int iy = oy - 1 + ky, ix = ox - 1 + kx;
        aok[s] = (iy >= 0 && ix >= 0);
        aoff[s] = (iy * 4 + ix) * 16 + (kg & 1) * 8;
    }

    for (int e = wv; e < NELEM; e += K2_WAVES) {
        const u16* pbase = pooled1b + e * 256;
        bf16x8 a0 = {0,0,0,0,0,0,0,0}, a1 = {0,0,0,0,0,0,0,0};
        if (aok[0]) a0 = *(const bf16x8*)(pbase + aoff[0]);
        if (aok[1]) a1 = *(const bf16x8*)(pbase + aoff[1]);
        f32x4 acc0 = {0.f,0.f,0.f,0.f}, acc1 = {0.f,0.f,0.f,0.f};
        acc0 = __builtin_amdgcn_mfma_f32_16x16x32_bf16(a0, bfrag[0][0], acc0, 0, 0, 0);
        acc1 = __builtin_amdgcn_mfma_f32_16x16x32_bf16(a0, bfrag[0][1], acc1, 0, 0, 0);
        acc0 = __builtin_amdgcn_mfma_f32_16x16x32_bf16(a1, bfrag[1][0], acc0, 0, 0, 0);
        acc1 = __builtin_amdgcn_mfma_f32_16x16x32_bf16(a1, bfrag[1][1], acc1, 0, 0, 0);
        #pragma unroll
        for (int nt = 0; nt < 2; ++nt) {
            f32x4 acc = nt ? acc1 : acc0;
            float b = bias[nt];
            float m0 = fmaxf(fmaxf(acc[0] + b, 0.f), fmaxf(acc[1] + b, 0.f));
            float m1 = fmaxf(fmaxf(acc[2] + b, 0.f), fmaxf(acc[3] + b, 0.f));
            float p0 = fmaxf(m0, __shfl_xor(m0, 16, 64));
            float p1 = fmaxf(m1, __shfl_xor(m1, 16, 64));
            if ((kg & 1) == 0) {
                int q = (kg >> 1) * 2;
                u16* op = pooled2 + e * 128 + nt * 16 + col;
                op[q * 32]       = f2bf(p0);
                op[(q + 1) * 32] = f2bf(p1);
            }
        }
    }
}

// ---------------- K34: fused conv3 -> swizzled LDS feat -> proj --------
// featL: 32 rows x 640 u16 (80 blocks of 8 u16; 40960 B -> 4 blocks/CU).
// Logical 8-u16 block B of row r stored at physical block B ^ (r&7):
// phase-2 ds_read_b128 becomes conflict-free; stores ~4-way. Pure storage
// permutation -> values bit-identical. Phase 1 statically unrolled
// (4 tiles/wave + 1 extra for waves 0,1) so loads pipeline.
__global__ __launch_bounds__(256) void k34_conv3_proj(const u16* __restrict__ pooled2,
        const u16* __restrict__ w3r, const float* __restrict__ b3,
        const int* __restrict__ ccol, const int* __restrict__ cobj,
        const u16* __restrict__ pwT, const float* __restrict__ pb,
        float* __restrict__ comb) {
    __shared__ u16 featL[32 * 640];   // 40960 B
    int t = threadIdx.x;
    int l = t & 63;
    int col = l & 15;
    int kg = l >> 4;
    int wv = t >> 6;
    int e0 = blockIdx.x * 32;
    int colhi = col >> 3, collo = col & 7;

    // ---- phase 1: conv3 (18 tiles; 4/wave unrolled + extra for wv<2) ----
    {
        bf16x8 bfrag[4][4];
        #pragma unroll
        for (int s = 0; s < 4; ++s)
            #pragma unroll
            for (int nt = 0; nt < 4; ++nt)
                bfrag[s][nt] = *(const bf16x8*)(w3r + (nt * 16 + col) * 128 + s * 32 + kg * 8);
        float bias[4];
        #pragma unroll
        for (int nt = 0; nt < 4; ++nt) bias[nt] = b3[nt * 16 + col];

        auto do_tile = [&](int i) {
            int m0 = i * 16;
            int m = m0 + col;
            u32 elem = (u32)(((unsigned long long)(u32)m * 954437177ull) >> 33); // m/9
            int p = m - (int)elem * 9;
            int oy = (p * 86) >> 8;
            int ox = p - 3 * oy;
            const u16* pbase = pooled2 + (size_t)(e0 + elem) * 128 + kg * 8;
            f32x4 acc[4];
            #pragma unroll
            for (int nt = 0; nt < 4; ++nt) {
                acc[nt][0] = 0.f; acc[nt][1] = 0.f; acc[nt][2] = 0.f; acc[nt][3] = 0.f;
            }
            #pragma unroll
            for (int s = 0; s < 4; ++s) {
                int ky = s >> 1, kx = s & 1;
                int iy = oy - 1 + ky, ix = ox - 1 + kx;
                bf16x8 a = {0,0,0,0,0,0,0,0};
                if (iy >= 0 && iy <= 1 && ix >= 0 && ix <= 1)
                    a = *(const bf16x8*)(pbase + (iy * 2 + ix) * 32);
                #pragma unroll
                for (int nt = 0; nt < 4; ++nt)
                    acc[nt] = __builtin_amdgcn_mfma_f32_16x16x32_bf16(a, bfrag[s][nt], acc[nt], 0, 0, 0);
            }
            #pragma unroll
            for (int r = 0; r < 4; ++r) {
                int mr = m0 + kg * 4 + r;
                u32 er = (u32)(((unsigned long long)(u32)mr * 954437177ull) >> 33);
                int pr = mr - (int)er * 9;
                int e7 = (int)(er & 7u);
                u16* fb = featL + er * 640 + collo;
                #pragma unroll
                for (int nt = 0; nt < 4; ++nt) {
                    int blk = (pr * 8 + nt * 2 + colhi) ^ e7;
                    fb[blk * 8] = f2bf(fmaxf(acc[nt][r] + bias[nt], 0.f));
                }
            }
        };
        #pragma unroll
        for (int u = 0; u < 4; ++u) do_tile(wv + u * 4);
        if (wv < 2) do_tile(16 + wv);
    }
    // ---- tail: logical slots 576..583 (block 72) of row t ----
    if (t < 32) {
        union { u16 s[8]; uint4 q; } b;
        b.s[0] = f2bf((float)ccol[e0 + t]);
        b.s[1] = f2bf((float)cobj[e0 + t]);
        #pragma unroll
        for (int i = 2; i < 8; ++i) b.s[i] = 0;
        *(uint4*)(featL + t * 640 + (72 ^ (t & 7)) * 8) = b.q;
    }
    __syncthreads();

    // ---- phase 2: proj; wave = (row-half rh, n-half nh) ----
    int rh = wv & 1, nh = wv >> 1;
    int m0g = e0 + rh * 16;
    const u16* arowb = featL + (rh * 16 + col) * 640;
    int rx = col & 7;                       // row swizzle key
    const u16* brow = pwT + (nh * 32 + col) * 608 + kg * 8;
    f32x4 acc0 = {0.f,0.f,0.f,0.f}, acc1 = {0.f,0.f,0.f,0.f};
    #pragma unroll
    for (int k0 = 0; k0 < 608; k0 += 32) {
        bf16x8 a;
        if (k0 + kg * 8 < 584) {
            int L = (k0 >> 3) + kg;
            a = *(const bf16x8*)(arowb + (L ^ rx) * 8);
        } else {
            #pragma unroll
            for (int j = 0; j < 8; ++j) a[j] = 0;
        }
        bf16x8 b0 = *(const bf16x8*)(brow + k0);
        bf16x8 b1 = *(const bf16x8*)(brow + 16 * 608 + k0);
        acc0 = __builtin_amdgcn_mfma_f32_16x16x32_bf16(a, b0, acc0, 0, 0, 0);
        acc1 = __builtin_amdgcn_mfma_f32_16x16x32_bf16(a, b1, acc1, 0, 0, 0);
    }
    float* outbase = (m0g < BATCH) ? (comb + (size_t)m0g * 160)
                                   : (comb + (size_t)(m0g - BATCH) * 160 + 64);
    #pragma unroll
    for (int nt = 0; nt < 2; ++nt) {
        int n = nh * 32 + nt * 16 + col;
        float pbv = pb[n];
        f32x4 acc = nt ? acc1 : acc0;
        #pragma unroll
        for (int r = 0; r < 4; ++r) {
            outbase[(kg * 4 + r) * 160 + n] = fmaxf(acc[r] + pbv, 0.f);
        }
    }
}

// ---------------- K5: dir_pos deltas -> comb[b][128..159] --------------
__global__ __launch_bounds__(256) void k5_extras(const int* __restrict__ frame,
        float* __restrict__ comb) {
    int b = blockIdx.x * 256 + threadIdx.x;
    int d[2]; float posy[2], posx[2];
    for (int f = 0; f < 2; ++f) {
        const int* fb = frame + (size_t)(f * BATCH + b) * 147;
        int idx = 49;
        for (int cell = 0; cell < 49; ++cell) {
            int v = fb[cell * 3];
            if (idx == 49 && v == 10) idx = cell;
        }
        if (idx < 49) {
            d[f] = fb[idx * 3 + 2] & 3;
            posy[f] = (float)(idx / 7) / 6.0f;
            posx[f] = (float)(idx % 7) / 6.0f;
        } else {
            d[f] = 0; posy[f] = 0.5f; posx[f] = 0.5f;
        }
    }
    int delta = (d[1] - d[0] + 4) & 3;
    const float ANG = (float)(2.0 * 3.14159 / 4.0);
    float angle = (float)delta * ANG;
    float4 o;
    o.x = sinf(angle);
    o.y = cosf(angle);
    o.z = posy[1] - posy[0];
    o.w = posx[1] - posx[0];
    float* cb = comb + (size_t)b * 160 + 128;
    *(float4*)cb = o;
    float4 z = make_float4(0.f, 0.f, 0.f, 0.f);
    #pragma unroll
    for (int i = 1; i < 8; ++i) *(float4*)(cb + i * 4) = z;
}

__device__ __forceinline__ void split8(const float* __restrict__ x,
                                       bf16x8& hi, bf16x8& lo) {
    #pragma unroll
    for (int j = 0; j < 8; ++j) {
        u16 h = f2bf(x[j]);
        hi[j] = (short)h;
        lo[j] = (short)f2bf(x[j] - bf2f(h));
    }
}

// ---------------- K6a: h1 GEMM via split-bf16 MFMA (no LN) -------------
__global__ __launch_bounds__(256) void k6_h1_gemm(const float* __restrict__ in,
        const u16* __restrict__ whi, const u16* __restrict__ wlo,
        const float* __restrict__ bias, float* __restrict__ out) {
    int t = threadIdx.x;
    int l = t & 63;
    int col = l & 15;
    int kg = l >> 4;
    int m0 = blockIdx.x * 64 + (t >> 6) * 16;
    const float* arow = in + (size_t)(m0 + col) * 160 + kg * 8;
    const u16* bh = whi + col * 160 + kg * 8;
    const u16* bl = wlo + col * 160 + kg * 8;

    f32x4 acc[8];
    #pragma unroll
    for (int nt = 0; nt < 8; ++nt) {
        acc[nt][0] = 0.f; acc[nt][1] = 0.f; acc[nt][2] = 0.f; acc[nt][3] = 0.f;
    }
    #pragma unroll
    for (int s = 0; s < 5; ++s) {
        float x[8];
        #pragma unroll
        for (int j = 0; j < 8; ++j) x[j] = arow[s * 32 + j];
        bf16x8 ahi, alo;
        split8(x, ahi, alo);
        #pragma unroll
        for (int nt = 0; nt < 8; ++nt) {
            bf16x8 bhiF = *(const bf16x8*)(bh + nt * 2560 + s * 32);
            bf16x8 bloF = *(const bf16x8*)(bl + nt * 2560 + s * 32);
            acc[nt] = __builtin_amdgcn_mfma_f32_16x16x32_bf16(ahi, bhiF, acc[nt], 0, 0, 0);
            acc[nt] = __builtin_amdgcn_mfma_f32_16x16x32_bf16(alo, bhiF, acc[nt], 0, 0, 0);
            acc[nt] = __builtin_amdgcn_mfma_f32_16x16x32_bf16(ahi, bloF, acc[nt], 0, 0, 0);
        }
    }
    #pragma unroll
    for (int nt = 0; nt < 8; ++nt) {
        float bv = bias[nt * 16 + col];
        #pragma unroll
        for (int r = 0; r < 4; ++r) {
            int m = m0 + kg * 4 + r;
            out[m * 128 + nt * 16 + col] = acc[nt][r] + bv;
        }
    }
}

// ---------------- K6b: LayerNorm + relu, wave per row ------------------
__global__ __launch_bounds__(256) void k6_ln(const float* __restrict__ h,
        const float* __restrict__ lng, const float* __restrict__ lnb,
        float* __restrict__ out) {
    int w = (blockIdx.x * 256 + threadIdx.x) >> 6;
    int l = threadIdx.x & 63;
    const float* row = h + (size_t)w * 128 + l * 2;
    float2 v = *(const float2*)row;
    float s = v.x + v.y;
    s += __shfl_xor(s, 1, 64);
    s += __shfl_xor(s, 2, 64);
    s += __shfl_xor(s, 4, 64);
    s += __shfl_xor(s, 8, 64);
    s += __shfl_xor(s, 16, 64);
    s += __shfl_xor(s, 32, 64);
    float mu = s * (1.0f / 128.0f);
    float d0 = v.x - mu, d1 = v.y - mu;
    float vs = d0 * d0 + d1 * d1;
    vs += __shfl_xor(vs, 1, 64);
    vs += __shfl_xor(vs, 2, 64);
    vs += __shfl_xor(vs, 4, 64);
    vs += __shfl_xor(vs, 8, 64);
    vs += __shfl_xor(vs, 16, 64);
    vs += __shfl_xor(vs, 32, 64);
    float rs = rsqrtf(vs * (1.0f / 128.0f) + 1e-5f);
    float2 o;
    o.x = fmaxf(d0 * rs * lng[l * 2]     + lnb[l * 2],     0.f);
    o.y = fmaxf(d1 * rs * lng[l * 2 + 1] + lnb[l * 2 + 1], 0.f);
    *(float2*)(out + (size_t)w * 128 + l * 2) = o;
}

// ---------------- K7: h2 via split-bf16 MFMA (fp32 in/out) -------------
__global__ __launch_bounds__(256) void k7_h2_mfma(const float* __restrict__ in,
        const u16* __restrict__ whi, const u16* __restrict__ wlo,
        const float* __restrict__ bias, float* __restrict__ out) {
    int t = threadIdx.x;
    int l = t & 63;
    int col = l & 15;
    int kg = l >> 4;
    int m0 = blockIdx.x * 64 + (t >> 6) * 16;
    const float* arow = in + (size_t)(m0 + col) * 128 + kg * 8;
    const u16* bh = whi + col * 128 + kg * 8;
    const u16* bl = wlo + col * 128 + kg * 8;

    f32x4 acc[8];
    #pragma unroll
    for (int nt = 0; nt < 8; ++nt) {
        acc[nt][0] = 0.f; acc[nt][1] = 0.f; acc[nt][2] = 0.f; acc[nt][3] = 0.f;
    }
    #pragma unroll
    for (int s = 0; s < 4; ++s) {
        float x[8];
        #pragma unroll
        for (int j = 0; j < 8; ++j) x[j] = arow[s * 32 + j];
        bf16x8 ahi, alo;
        split8(x, ahi, alo);
        #pragma unroll
        for (int nt = 0; nt < 8; ++nt) {
            bf16x8 bhiF = *(const bf16x8*)(bh + nt * 2048 + s * 32);
            bf16x8 bloF = *(const bf16x8*)(bl + nt * 2048 + s * 32);
            acc[nt] = __builtin_amdgcn_mfma_f32_16x16x32_bf16(ahi, bhiF, acc[nt], 0, 0, 0);
            acc[nt] = __builtin_amdgcn_mfma_f32_16x16x32_bf16(alo, bhiF, acc[nt], 0, 0, 0);
            acc[nt] = __builtin_amdgcn_mfma_f32_16x16x32_bf16(ahi, bloF, acc[nt], 0, 0, 0);
        }
    }
    #pragma unroll
    for (int nt = 0; nt < 8; ++nt) {
        float bv = bias[nt * 16 + col];
        #pragma unroll
        for (int r = 0; r < 4; ++r) {
            int m = m0 + kg * 4 + r;
            out[m * 128 + nt * 16 + col] = fmaxf(acc[nt][r] + bv, 0.f);
        }
    }
}

// ---------------- K8: h3 [32768x128]@[128->7], thread = row, fp32 ------
__global__ __launch_bounds__(256) void k8_h3(const float* __restrict__ in,
        const float* __restrict__ w, const float* __restrict__ bias,
        float* __restrict__ out) {
    int r = blockIdx.x * 256 + threadIdx.x;
    float acc[7];
    #pragma unroll
    for (int j = 0; j < 7; ++j) acc[j] = bias[j];
    const float* row = in + (size_t)r * 128;
    #pragma unroll 4
    for (int c = 0; c < 32; ++c) {
        float4 v = *(const float4*)(row + c * 4);
        #pragma unroll
        for (int j = 0; j < 7; ++j) {
            acc[j] += v.x * w[j * 128 + c * 4 + 0];
            acc[j] += v.y * w[j * 128 + c * 4 + 1];
            acc[j] += v.z * w[j * 128 + c * 4 + 2];
            acc[j] += v.w * w[j * 128 + c * 4 + 3];
        }
    }
    #pragma unroll
    for (int j = 0; j < 7; ++j) out[r * 7 + j] = acc[j];
}

extern "C" void kernel_launch(void* const* d_in, const int* in_sizes, int n_in,
                              void* d_out, int out_size, void* d_ws, size_t ws_size,
                              hipStream_t stream) {
    const int*   frame = (const int*)d_in[0];
    const int*   ccol  = (const int*)d_in[1];
    const int*   cobj  = (const int*)d_in[2];
    const float* w1    = (const float*)d_in[3];
    const float* b1    = (const float*)d_in[4];
    const float* w2    = (const float*)d_in[5];
    const float* b2    = (const float*)d_in[6];
    const float* w3    = (const float*)d_in[7];
    const float* b3    = (const float*)d_in[8];
    const float* pw    = (const float*)d_in[9];
    const float* pb    = (const float*)d_in[10];
    const float* h1w   = (const float*)d_in[11];
    const float* h1b   = (const float*)d_in[12];
    const float* lng   = (const float*)d_in[13];
    const float* lnb   = (const float*)d_in[14];
    const float* h2w   = (const float*)d_in[15];
    const float* h2b   = (const float*)d_in[16];
    const float* h3w   = (const float*)d_in[17];
    const float* h3b   = (const float*)d_in[18];
    float* out = (float*)d_out;

    char* ws = (char*)d_ws;
    u16*   pooled1b = (u16*)(ws + 0);                    // 32 MB
    float* comb     = (float*)(ws + 0);                  // 21 MB (after k2)
    u16*   pooled2  = (u16*)(ws + 33554432);             // 16 MB
    float* h1out    = (float*)(ws + 33554432);           // 16 MB (after k34)
    float* h2out    = (float*)(ws + 50331648);           // 16 MB
    float* h1pre    = (float*)(ws + 95420416);           // 16 MB
    u16*   pwT      = (u16*)(ws + 132120576);            // 77824 B
    u16*   w2r      = (u16*)(ws + 132120576 + 131072);   // 4096 B
    u16*   w3r      = (u16*)(ws + 132120576 + 139264);   // 16384 B
    u16*   h2hi     = (u16*)(ws + 132120576 + 163840);   // 32768 B
    u16*   h2lo     = (u16*)(ws + 132120576 + 196608);   // 32768 B
    u16*   h1hi     = (u16*)(ws + 132120576 + 229376);   // 40960 B
    u16*   h1lo     = (u16*)(ws + 132120576 + 270336);   // 40960 B
    u16*   w1hi     = (u16*)(ws + 132120576 + 311296);   // 1024 B
    u16*   w1lo     = (u16*)(ws + 132120576 + 312320);   // 1024 B

    k0_prep<<<340, 256, 0, stream>>>(pw, w2, w3, h2w, h1w, w1,
                                     pwT, w2r, w3r, h2hi, h2lo, h1hi, h1lo,
                                     w1hi, w1lo);
    k1_conv1_mfma<<<4096, 256, 0, stream>>>(frame, w1hi, w1lo, b1, pooled1b);
    k2_conv2_mfma<<<1024, 256, 0, stream>>>(pooled1b, w2r, b2, pooled2);
    k34_conv3_proj<<<2048, 256, 0, stream>>>(pooled2, w3r, b3, ccol, cobj,
                                             pwT, pb, comb);
    k5_extras<<<128, 256, 0, stream>>>(frame, comb);
    k6_h1_gemm<<<512, 256, 0, stream>>>(comb, h1hi, h1lo, h1b, h1pre);
    k6_ln<<<8192, 256, 0, stream>>>(h1pre, lng, lnb, h1out);
    k7_h2_mfma<<<512, 256, 0, stream>>>(h1out, h2hi, h2lo, h2b, h2out);
    k8_h3<<<128, 256, 0, stream>>>(h2out, h3w, h3b, out);
}

// Round 18
// 260.304 us; speedup vs baseline: 1.1869x; 1.0445x over previous
//
#include <hip/hip_runtime.h>
#include <hip/hip_bf16.h>

#define BATCH 32768
#define NELEM 65536   // 2 * BATCH

typedef unsigned short u16;
typedef unsigned int u32;
typedef __attribute__((ext_vector_type(8))) short bf16x8;
typedef __attribute__((ext_vector_type(4))) float f32x4;

__device__ __forceinline__ float bf2f(u16 u) {
    union { u32 u; float f; } c; c.u = ((u32)u) << 16; return c.f;
}
__device__ __forceinline__ u16 f2bf(float f) {
    union { float f; u32 u; } c; c.f = f;
    u32 x = c.u;
    u32 r = (x + 0x7fffu + ((x >> 16) & 1u)) >> 16;  // RNE
    return (u16)r;
}

// ---------------- K0: weight prep ---------------------------------------
__global__ __launch_bounds__(256) void k0_prep(const float* __restrict__ pw,
        const float* __restrict__ w2, const float* __restrict__ w3,
        const float* __restrict__ h2w, const float* __restrict__ h1w,
        const float* __restrict__ w1,
        u16* __restrict__ pwT, u16* __restrict__ w2r, u16* __restrict__ w3r,
        u16* __restrict__ h2hi, u16* __restrict__ h2lo,
        u16* __restrict__ h1hi, u16* __restrict__ h1lo,
        u16* __restrict__ w1hi, u16* __restrict__ w1lo) {
    int idx = blockIdx.x * 256 + threadIdx.x;
    if (idx < 38912) {
        int j = idx / 608, kk = idx - j * 608;
        float v = 0.f;
        if (kk < 576) {
            int p = kk >> 6, oc = kk & 63;
            v = pw[j * 578 + oc * 9 + p];
        } else if (kk < 578) {
            v = pw[j * 578 + kk];
        }
        pwT[idx] = f2bf(v);
    } else if (idx < 40960) {
        int i = idx - 38912;
        int oc = i >> 6, rem = i & 63, tap = rem >> 4, ic = rem & 15;
        w2r[i] = f2bf(w2[oc * 64 + ic * 4 + tap]);
    } else if (idx < 49152) {
        int i = idx - 40960;
        int oc = i >> 7, rem = i & 127, tap = rem >> 5, ic = rem & 31;
        w3r[i] = f2bf(w3[oc * 128 + ic * 4 + tap]);
    } else if (idx < 65536) {
        int i = idx - 49152;
        float v = h2w[i];
        u16 hi = f2bf(v);
        h2hi[i] = hi;
        h2lo[i] = f2bf(v - bf2f(hi));
    } else if (idx < 86016) {
        int i = idx - 65536;
        int j = i / 160, k = i - j * 160;
        float v = (k < 132) ? h1w[j * 132 + k] : 0.f;
        u16 hi = f2bf(v);
        h1hi[i] = hi;
        h1lo[i] = f2bf(v - bf2f(hi));
    } else if (idx < 86528) {
        int i = idx - 86016;               // [oc16][k32]
        int oc = i >> 5, k = i & 31;
        int ky = k >> 4, kx = (k >> 3) & 1, c = k & 7;
        float v = (c < 3) ? w1[oc * 12 + c * 4 + ky * 2 + kx] : 0.f;
        u16 hi = f2bf(v);
        w1hi[i] = hi;
        w1lo[i] = f2bf(v - bf2f(hi));
    }
}

// ---------------- K1: conv1+relu+maxpool via MFMA ----------------------
__global__ __launch_bounds__(256) void k1_conv1_mfma(const int* __restrict__ frame,
        const u16* __restrict__ w1hi, const u16* __restrict__ w1lo,
        const float* __restrict__ b1, u16* __restrict__ pooled1b) {
    __shared__ u16 fr[16 * 656];   // [elem][(y)*72 + (x)*8 + c], padded 9x9
    int t = threadIdx.x;
    int e0 = blockIdx.x * 16;
    #pragma unroll
    for (int i = 0; i < 6; ++i) {
        int o = i * 256 + t;
        if (o < 1312) *(uint4*)(fr + o * 8) = make_uint4(0u, 0u, 0u, 0u);
    }
    __syncthreads();
    #pragma unroll
    for (int i = 0; i < 10; ++i) {
        int idx = i * 256 + t;
        if (idx < 2352) {
            int le = idx / 147, r = idx - le * 147;
            int cell = r / 3, c = r - cell * 3;
            int y = cell / 7, x = cell - y * 7;
            fr[le * 656 + (y + 1) * 72 + (x + 1) * 8 + c] = f2bf((float)frame[e0 * 147 + idx]);
        }
    }
    __syncthreads();
    int l = t & 63;
    int wv = t >> 6;
    int col = l & 15;
    int kg = l >> 4;
    bf16x8 bhi = *(const bf16x8*)(w1hi + col * 32 + kg * 8);
    bf16x8 blo = *(const bf16x8*)(w1lo + col * 32 + kg * 8);
    float bias = b1[col];
    int ky = kg >> 1, kx = kg & 1;
    bool writer = (kg < 2);
    #pragma unroll
    for (int q = 0; q < 4; ++q) {
        int le = wv * 4 + q;
        const u16* eb = fr + le * 656;
        u16* op = pooled1b + (size_t)(e0 + le) * 256;
        #pragma unroll
        for (int mt = 0; mt < 4; ++mt) {
            int posA = mt * 16 + col;
            int oy = posA >> 3, ox = posA & 7;
            bf16x8 a = *(const bf16x8*)(eb + (oy + ky) * 72 + (ox + kx) * 8);
            f32x4 acc = {0.f, 0.f, 0.f, 0.f};
            acc = __builtin_amdgcn_mfma_f32_16x16x32_bf16(a, bhi, acc, 0, 0, 0);
            acc = __builtin_amdgcn_mfma_f32_16x16x32_bf16(a, blo, acc, 0, 0, 0);
            float x0 = fmaxf(acc[0] + bias, 0.f);
            float x1 = fmaxf(acc[1] + bias, 0.f);
            float x2 = fmaxf(acc[2] + bias, 0.f);
            float x3 = fmaxf(acc[3] + bias, 0.f);
            float y0 = fmaxf(x0, x1);
            float y1 = fmaxf(x2, x3);
            float m0 = fmaxf(y0, __shfl_xor(y0, 32, 64));
            float m1 = fmaxf(y1, __shfl_xor(y1, 32, 64));
            if (writer) {
                op[(mt * 4 + kg * 2 + 0) * 16 + col] = f2bf(m0);
                op[(mt * 4 + kg * 2 + 1) * 16 + col] = f2bf(m1);
            }
        }
    }
}

// ---------------- K2: conv2+relu+maxpool fused via MFMA, LDS-free ------
#define K2_WAVES 4096
__global__ __launch_bounds__(256) void k2_conv2_mfma(const u16* __restrict__ pooled1b,
        const u16* __restrict__ w2r, const float* __restrict__ b2,
        u16* __restrict__ pooled2) {
    int t = threadIdx.x;
    int l = t & 63;
    int col = l & 15;
    int kg = l >> 4;
    int wv = (blockIdx.x * 256 + t) >> 6;

    bf16x8 bfrag[2][2];
    #pragma unroll
    for (int s = 0; s < 2; ++s)
        #pragma unroll
        for (int nt = 0; nt < 2; ++nt)
            bfrag[s][nt] = *(const bf16x8*)(w2r + (nt * 16 + col) * 64 + s * 32 + kg * 8);
    float bias[2] = { b2[col], b2[16 + col] };

    int oy = col >> 2, ox = col & 3;
    int aoff[2]; bool aok[2];
    #pragma unroll
    for (int s = 0; s < 2; ++s) {
        int tap = 2 * s + (kg >> 1);
        int ky = tap >> 1, kx = tap & 1;
        int iy = oy - 1 + ky, ix = ox - 1 + kx;
        aok[s] = (iy >= 0 && ix >= 0);
        aoff[s] = (iy * 4 + ix) * 16 + (kg & 1) * 8;
    }

    for (int e = wv; e < NELEM; e += K2_WAVES) {
        const u16* pbase = pooled1b + e * 256;
        bf16x8 a0 = {0,0,0,0,0,0,0,0}, a1 = {0,0,0,0,0,0,0,0};
        if (aok[0]) a0 = *(const bf16x8*)(pbase + aoff[0]);
        if (aok[1]) a1 = *(const bf16x8*)(pbase + aoff[1]);
        f32x4 acc0 = {0.f,0.f,0.f,0.f}, acc1 = {0.f,0.f,0.f,0.f};
        acc0 = __builtin_amdgcn_mfma_f32_16x16x32_bf16(a0, bfrag[0][0], acc0, 0, 0, 0);
        acc1 = __builtin_amdgcn_mfma_f32_16x16x32_bf16(a0, bfrag[0][1], acc1, 0, 0, 0);
        acc0 = __builtin_amdgcn_mfma_f32_16x16x32_bf16(a1, bfrag[1][0], acc0, 0, 0, 0);
        acc1 = __builtin_amdgcn_mfma_f32_16x16x32_bf16(a1, bfrag[1][1], acc1, 0, 0, 0);
        #pragma unroll
        for (int nt = 0; nt < 2; ++nt) {
            f32x4 acc = nt ? acc1 : acc0;
            float b = bias[nt];
            float m0 = fmaxf(fmaxf(acc[0] + b, 0.f), fmaxf(acc[1] + b, 0.f));
            float m1 = fmaxf(fmaxf(acc[2] + b, 0.f), fmaxf(acc[3] + b, 0.f));
            float p0 = fmaxf(m0, __shfl_xor(m0, 16, 64));
            float p1 = fmaxf(m1, __shfl_xor(m1, 16, 64));
            if ((kg & 1) == 0) {
                int q = (kg >> 1) * 2;
                u16* op = pooled2 + e * 128 + nt * 16 + col;
                op[q * 32]       = f2bf(p0);
                op[(q + 1) * 32] = f2bf(p1);
            }
        }
    }
}

// ---------------- K34: fused conv3 -> swizzled LDS feat -> proj --------
// NEW: pooled2 slice (8 KB) cooperatively staged into LDS first, so the
// phase-1 tile loop's A-fragment loads are ds_read (120 cyc, pipelined
// via lgkmcnt) instead of global loads (200-900 cyc) — removes exposed
// VMEM latency from the barrier-aligned phase-1 critical path. Values
// bit-identical. LDS 49152 B -> 3 blocks/CU.
__global__ __launch_bounds__(256) void k34_conv3_proj(const u16* __restrict__ pooled2,
        const u16* __restrict__ w3r, const float* __restrict__ b3,
        const int* __restrict__ ccol, const int* __restrict__ cobj,
        const u16* __restrict__ pwT, const float* __restrict__ pb,
        float* __restrict__ comb) {
    __shared__ u16 featL[32 * 640];   // 40960 B
    __shared__ u16 p2L[32 * 128];     // 8192 B
    int t = threadIdx.x;
    int l = t & 63;
    int col = l & 15;
    int kg = l >> 4;
    int wv = t >> 6;
    int e0 = blockIdx.x * 32;
    int colhi = col >> 3, collo = col & 7;

    // ---- stage pooled2 slice (coalesced 8 KB) ----
    {
        const uint4* src = (const uint4*)(pooled2 + (size_t)e0 * 128);
        uint4* dst = (uint4*)p2L;
        #pragma unroll
        for (int i = 0; i < 2; ++i) dst[i * 256 + t] = src[i * 256 + t];
    }
    __syncthreads();

    // ---- phase 1: conv3 (18 tiles; 4/wave unrolled + extra for wv<2) ----
    {
        bf16x8 bfrag[4][4];
        #pragma unroll
        for (int s = 0; s < 4; ++s)
            #pragma unroll
            for (int nt = 0; nt < 4; ++nt)
                bfrag[s][nt] = *(const bf16x8*)(w3r + (nt * 16 + col) * 128 + s * 32 + kg * 8);
        float bias[4];
        #pragma unroll
        for (int nt = 0; nt < 4; ++nt) bias[nt] = b3[nt * 16 + col];

        auto do_tile = [&](int i) {
            int m0 = i * 16;
            int m = m0 + col;
            u32 elem = (u32)(((unsigned long long)(u32)m * 954437177ull) >> 33); // m/9
            int p = m - (int)elem * 9;
            int oy = (p * 86) >> 8;
            int ox = p - 3 * oy;
            const u16* pbase = p2L + elem * 128 + kg * 8;
            f32x4 acc[4];
            #pragma unroll
            for (int nt = 0; nt < 4; ++nt) {
                acc[nt][0] = 0.f; acc[nt][1] = 0.f; acc[nt][2] = 0.f; acc[nt][3] = 0.f;
            }
            #pragma unroll
            for (int s = 0; s < 4; ++s) {
                int ky = s >> 1, kx = s & 1;
                int iy = oy - 1 + ky, ix = ox - 1 + kx;
                bf16x8 a = {0,0,0,0,0,0,0,0};
                if (iy >= 0 && iy <= 1 && ix >= 0 && ix <= 1)
                    a = *(const bf16x8*)(pbase + (iy * 2 + ix) * 32);
                #pragma unroll
                for (int nt = 0; nt < 4; ++nt)
                    acc[nt] = __builtin_amdgcn_mfma_f32_16x16x32_bf16(a, bfrag[s][nt], acc[nt], 0, 0, 0);
            }
            #pragma unroll
            for (int r = 0; r < 4; ++r) {
                int mr = m0 + kg * 4 + r;
                u32 er = (u32)(((unsigned long long)(u32)mr * 954437177ull) >> 33);
                int pr = mr - (int)er * 9;
                int e7 = (int)(er & 7u);
                u16* fb = featL + er * 640 + collo;
                #pragma unroll
                for (int nt = 0; nt < 4; ++nt) {
                    int blk = (pr * 8 + nt * 2 + colhi) ^ e7;
                    fb[blk * 8] = f2bf(fmaxf(acc[nt][r] + bias[nt], 0.f));
                }
            }
        };
        #pragma unroll
        for (int u = 0; u < 4; ++u) do_tile(wv + u * 4);
        if (wv < 2) do_tile(16 + wv);
    }
    // ---- tail: logical slots 576..583 (block 72) of row t ----
    if (t < 32) {
        union { u16 s[8]; uint4 q; } b;
        b.s[0] = f2bf((float)ccol[e0 + t]);
        b.s[1] = f2bf((float)cobj[e0 + t]);
        #pragma unroll
        for (int i = 2; i < 8; ++i) b.s[i] = 0;
        *(uint4*)(featL + t * 640 + (72 ^ (t & 7)) * 8) = b.q;
    }
    __syncthreads();

    // ---- phase 2: proj; wave = (row-half rh, n-half nh) ----
    int rh = wv & 1, nh = wv >> 1;
    int m0g = e0 + rh * 16;
    const u16* arowb = featL + (rh * 16 + col) * 640;
    int rx = col & 7;                       // row swizzle key
    const u16* brow = pwT + (nh * 32 + col) * 608 + kg * 8;
    f32x4 acc0 = {0.f,0.f,0.f,0.f}, acc1 = {0.f,0.f,0.f,0.f};
    #pragma unroll
    for (int k0 = 0; k0 < 608; k0 += 32) {
        bf16x8 a;
        if (k0 + kg * 8 < 584) {
            int L = (k0 >> 3) + kg;
            a = *(const bf16x8*)(arowb + (L ^ rx) * 8);
        } else {
            #pragma unroll
            for (int j = 0; j < 8; ++j) a[j] = 0;
        }
        bf16x8 b0 = *(const bf16x8*)(brow + k0);
        bf16x8 b1 = *(const bf16x8*)(brow + 16 * 608 + k0);
        acc0 = __builtin_amdgcn_mfma_f32_16x16x32_bf16(a, b0, acc0, 0, 0, 0);
        acc1 = __builtin_amdgcn_mfma_f32_16x16x32_bf16(a, b1, acc1, 0, 0, 0);
    }
    float* outbase = (m0g < BATCH) ? (comb + (size_t)m0g * 160)
                                   : (comb + (size_t)(m0g - BATCH) * 160 + 64);
    #pragma unroll
    for (int nt = 0; nt < 2; ++nt) {
        int n = nh * 32 + nt * 16 + col;
        float pbv = pb[n];
        f32x4 acc = nt ? acc1 : acc0;
        #pragma unroll
        for (int r = 0; r < 4; ++r) {
            outbase[(kg * 4 + r) * 160 + n] = fmaxf(acc[r] + pbv, 0.f);
        }
    }
}

// ---------------- K5: dir_pos deltas -> comb[b][128..159] --------------
__global__ __launch_bounds__(256) void k5_extras(const int* __restrict__ frame,
        float* __restrict__ comb) {
    int b = blockIdx.x * 256 + threadIdx.x;
    int d[2]; float posy[2], posx[2];
    for (int f = 0; f < 2; ++f) {
        const int* fb = frame + (size_t)(f * BATCH + b) * 147;
        int idx = 49;
        for (int cell = 0; cell < 49; ++cell) {
            int v = fb[cell * 3];
            if (idx == 49 && v == 10) idx = cell;
        }
        if (idx < 49) {
            d[f] = fb[idx * 3 + 2] & 3;
            posy[f] = (float)(idx / 7) / 6.0f;
            posx[f] = (float)(idx % 7) / 6.0f;
        } else {
            d[f] = 0; posy[f] = 0.5f; posx[f] = 0.5f;
        }
    }
    int delta = (d[1] - d[0] + 4) & 3;
    const float ANG = (float)(2.0 * 3.14159 / 4.0);
    float angle = (float)delta * ANG;
    float4 o;
    o.x = sinf(angle);
    o.y = cosf(angle);
    o.z = posy[1] - posy[0];
    o.w = posx[1] - posx[0];
    float* cb = comb + (size_t)b * 160 + 128;
    *(float4*)cb = o;
    float4 z = make_float4(0.f, 0.f, 0.f, 0.f);
    #pragma unroll
    for (int i = 1; i < 8; ++i) *(float4*)(cb + i * 4) = z;
}

__device__ __forceinline__ void split8(const float* __restrict__ x,
                                       bf16x8& hi, bf16x8& lo) {
    #pragma unroll
    for (int j = 0; j < 8; ++j) {
        u16 h = f2bf(x[j]);
        hi[j] = (short)h;
        lo[j] = (short)f2bf(x[j] - bf2f(h));
    }
}

// ---------------- K6a: h1 GEMM via split-bf16 MFMA (no LN) -------------
__global__ __launch_bounds__(256) void k6_h1_gemm(const float* __restrict__ in,
        const u16* __restrict__ whi, const u16* __restrict__ wlo,
        const float* __restrict__ bias, float* __restrict__ out) {
    int t = threadIdx.x;
    int l = t & 63;
    int col = l & 15;
    int kg = l >> 4;
    int m0 = blockIdx.x * 64 + (t >> 6) * 16;
    const float* arow = in + (size_t)(m0 + col) * 160 + kg * 8;
    const u16* bh = whi + col * 160 + kg * 8;
    const u16* bl = wlo + col * 160 + kg * 8;

    f32x4 acc[8];
    #pragma unroll
    for (int nt = 0; nt < 8; ++nt) {
        acc[nt][0] = 0.f; acc[nt][1] = 0.f; acc[nt][2] = 0.f; acc[nt][3] = 0.f;
    }
    #pragma unroll
    for (int s = 0; s < 5; ++s) {
        float x[8];
        #pragma unroll
        for (int j = 0; j < 8; ++j) x[j] = arow[s * 32 + j];
        bf16x8 ahi, alo;
        split8(x, ahi, alo);
        #pragma unroll
        for (int nt = 0; nt < 8; ++nt) {
            bf16x8 bhiF = *(const bf16x8*)(bh + nt * 2560 + s * 32);
            bf16x8 bloF = *(const bf16x8*)(bl + nt * 2560 + s * 32);
            acc[nt] = __builtin_amdgcn_mfma_f32_16x16x32_bf16(ahi, bhiF, acc[nt], 0, 0, 0);
            acc[nt] = __builtin_amdgcn_mfma_f32_16x16x32_bf16(alo, bhiF, acc[nt], 0, 0, 0);
            acc[nt] = __builtin_amdgcn_mfma_f32_16x16x32_bf16(ahi, bloF, acc[nt], 0, 0, 0);
        }
    }
    #pragma unroll
    for (int nt = 0; nt < 8; ++nt) {
        float bv = bias[nt * 16 + col];
        #pragma unroll
        for (int r = 0; r < 4; ++r) {
            int m = m0 + kg * 4 + r;
            out[m * 128 + nt * 16 + col] = acc[nt][r] + bv;
        }
    }
}

// ---------------- K6b: LayerNorm + relu, wave per row ------------------
__global__ __launch_bounds__(256) void k6_ln(const float* __restrict__ h,
        const float* __restrict__ lng, const float* __restrict__ lnb,
        float* __restrict__ out) {
    int w = (blockIdx.x * 256 + threadIdx.x) >> 6;
    int l = threadIdx.x & 63;
    const float* row = h + (size_t)w * 128 + l * 2;
    float2 v = *(const float2*)row;
    float s = v.x + v.y;
    s += __shfl_xor(s, 1, 64);
    s += __shfl_xor(s, 2, 64);
    s += __shfl_xor(s, 4, 64);
    s += __shfl_xor(s, 8, 64);
    s += __shfl_xor(s, 16, 64);
    s += __shfl_xor(s, 32, 64);
    float mu = s * (1.0f / 128.0f);
    float d0 = v.x - mu, d1 = v.y - mu;
    float vs = d0 * d0 + d1 * d1;
    vs += __shfl_xor(vs, 1, 64);
    vs += __shfl_xor(vs, 2, 64);
    vs += __shfl_xor(vs, 4, 64);
    vs += __shfl_xor(vs, 8, 64);
    vs += __shfl_xor(vs, 16, 64);
    vs += __shfl_xor(vs, 32, 64);
    float rs = rsqrtf(vs * (1.0f / 128.0f) + 1e-5f);
    float2 o;
    o.x = fmaxf(d0 * rs * lng[l * 2]     + lnb[l * 2],     0.f);
    o.y = fmaxf(d1 * rs * lng[l * 2 + 1] + lnb[l * 2 + 1], 0.f);
    *(float2*)(out + (size_t)w * 128 + l * 2) = o;
}

// ---------------- K7: h2 via split-bf16 MFMA (fp32 in/out) -------------
__global__ __launch_bounds__(256) void k7_h2_mfma(const float* __restrict__ in,
        const u16* __restrict__ whi, const u16* __restrict__ wlo,
        const float* __restrict__ bias, float* __restrict__ out) {
    int t = threadIdx.x;
    int l = t & 63;
    int col = l & 15;
    int kg = l >> 4;
    int m0 = blockIdx.x * 64 + (t >> 6) * 16;
    const float* arow = in + (size_t)(m0 + col) * 128 + kg * 8;
    const u16* bh = whi + col * 128 + kg * 8;
    const u16* bl = wlo + col * 128 + kg * 8;

    f32x4 acc[8];
    #pragma unroll
    for (int nt = 0; nt < 8; ++nt) {
        acc[nt][0] = 0.f; acc[nt][1] = 0.f; acc[nt][2] = 0.f; acc[nt][3] = 0.f;
    }
    #pragma unroll
    for (int s = 0; s < 4; ++s) {
        float x[8];
        #pragma unroll
        for (int j = 0; j < 8; ++j) x[j] = arow[s * 32 + j];
        bf16x8 ahi, alo;
        split8(x, ahi, alo);
        #pragma unroll
        for (int nt = 0; nt < 8; ++nt) {
            bf16x8 bhiF = *(const bf16x8*)(bh + nt * 2048 + s * 32);
            bf16x8 bloF = *(const bf16x8*)(bl + nt * 2048 + s * 32);
            acc[nt] = __builtin_amdgcn_mfma_f32_16x16x32_bf16(ahi, bhiF, acc[nt], 0, 0, 0);
            acc[nt] = __builtin_amdgcn_mfma_f32_16x16x32_bf16(alo, bhiF, acc[nt], 0, 0, 0);
            acc[nt] = __builtin_amdgcn_mfma_f32_16x16x32_bf16(ahi, bloF, acc[nt], 0, 0, 0);
        }
    }
    #pragma unroll
    for (int nt = 0; nt < 8; ++nt) {
        float bv = bias[nt * 16 + col];
        #pragma unroll
        for (int r = 0; r < 4; ++r) {
            int m = m0 + kg * 4 + r;
            out[m * 128 + nt * 16 + col] = fmaxf(acc[nt][r] + bv, 0.f);
        }
    }
}

// ---------------- K8: h3 [32768x128]@[128->7], thread = row, fp32 ------
__global__ __launch_bounds__(256) void k8_h3(const float* __restrict__ in,
        const float* __restrict__ w, const float* __restrict__ bias,
        float* __restrict__ out) {
    int r = blockIdx.x * 256 + threadIdx.x;
    float acc[7];
    #pragma unroll
    for (int j = 0; j < 7; ++j) acc[j] = bias[j];
    const float* row = in + (size_t)r * 128;
    #pragma unroll 4
    for (int c = 0; c < 32; ++c) {
        float4 v = *(const float4*)(row + c * 4);
        #pragma unroll
        for (int j = 0; j < 7; ++j) {
            acc[j] += v.x * w[j * 128 + c * 4 + 0];
            acc[j] += v.y * w[j * 128 + c * 4 + 1];
            acc[j] += v.z * w[j * 128 + c * 4 + 2];
            acc[j] += v.w * w[j * 128 + c * 4 + 3];
        }
    }
    #pragma unroll
    for (int j = 0; j < 7; ++j) out[r * 7 + j] = acc[j];
}

extern "C" void kernel_launch(void* const* d_in, const int* in_sizes, int n_in,
                              void* d_out, int out_size, void* d_ws, size_t ws_size,
                              hipStream_t stream) {
    const int*   frame = (const int*)d_in[0];
    const int*   ccol  = (const int*)d_in[1];
    const int*   cobj  = (const int*)d_in[2];
    const float* w1    = (const float*)d_in[3];
    const float* b1    = (const float*)d_in[4];
    const float* w2    = (const float*)d_in[5];
    const float* b2    = (const float*)d_in[6];
    const float* w3    = (const float*)d_in[7];
    const float* b3    = (const float*)d_in[8];
    const float* pw    = (const float*)d_in[9];
    const float* pb    = (const float*)d_in[10];
    const float* h1w   = (const float*)d_in[11];
    const float* h1b   = (const float*)d_in[12];
    const float* lng   = (const float*)d_in[13];
    const float* lnb   = (const float*)d_in[14];
    const float* h2w   = (const float*)d_in[15];
    const float* h2b   = (const float*)d_in[16];
    const float* h3w   = (const float*)d_in[17];
    const float* h3b   = (const float*)d_in[18];
    float* out = (float*)d_out;

    char* ws = (char*)d_ws;
    u16*   pooled1b = (u16*)(ws + 0);                    // 32 MB
    float* comb     = (float*)(ws + 0);                  // 21 MB (after k2)
    u16*   pooled2  = (u16*)(ws + 33554432);             // 16 MB
    float* h1out    = (float*)(ws + 33554432);           // 16 MB (after k34)
    float* h2out    = (float*)(ws + 50331648);           // 16 MB
    float* h1pre    = (float*)(ws + 95420416);           // 16 MB
    u16*   pwT      = (u16*)(ws + 132120576);            // 77824 B
    u16*   w2r      = (u16*)(ws + 132120576 + 131072);   // 4096 B
    u16*   w3r      = (u16*)(ws + 132120576 + 139264);   // 16384 B
    u16*   h2hi     = (u16*)(ws + 132120576 + 163840);   // 32768 B
    u16*   h2lo     = (u16*)(ws + 132120576 + 196608);   // 32768 B
    u16*   h1hi     = (u16*)(ws + 132120576 + 229376);   // 40960 B
    u16*   h1lo     = (u16*)(ws + 132120576 + 270336);   // 40960 B
    u16*   w1hi     = (u16*)(ws + 132120576 + 311296);   // 1024 B
    u16*   w1lo     = (u16*)(ws + 132120576 + 312320);   // 1024 B

    k0_prep<<<340, 256, 0, stream>>>(pw, w2, w3, h2w, h1w, w1,
                                     pwT, w2r, w3r, h2hi, h2lo, h1hi, h1lo,
                                     w1hi, w1lo);
    k1_conv1_mfma<<<4096, 256, 0, stream>>>(frame, w1hi, w1lo, b1, pooled1b);
    k2_conv2_mfma<<<1024, 256, 0, stream>>>(pooled1b, w2r, b2, pooled2);
    k34_conv3_proj<<<2048, 256, 0, stream>>>(pooled2, w3r, b3, ccol, cobj,
                                             pwT, pb, comb);
    k5_extras<<<128, 256, 0, stream>>>(frame, comb);
    k6_h1_gemm<<<512, 256, 0, stream>>>(comb, h1hi, h1lo, h1b, h1pre);
    k6_ln<<<8192, 256, 0, stream>>>(h1pre, lng, lnb, h1out);
    k7_h2_mfma<<<512, 256, 0, stream>>>(h1out, h2hi, h2lo, h2b, h2out);
    k8_h3<<<128, 256, 0, stream>>>(h2out, h3w, h3b, out);
}

// Round 19
// 255.893 us; speedup vs baseline: 1.2074x; 1.0172x over previous
//
#include <hip/hip_runtime.h>
#include <hip/hip_bf16.h>

#define BATCH 32768
#define NELEM 65536   // 2 * BATCH

typedef unsigned short u16;
typedef unsigned int u32;
typedef __attribute__((ext_vector_type(8))) short bf16x8;
typedef __attribute__((ext_vector_type(4))) float f32x4;

__device__ __forceinline__ float bf2f(u16 u) {
    union { u32 u; float f; } c; c.u = ((u32)u) << 16; return c.f;
}
__device__ __forceinline__ u16 f2bf(float f) {
    union { float f; u32 u; } c; c.f = f;
    u32 x = c.u;
    u32 r = (x + 0x7fffu + ((x >> 16) & 1u)) >> 16;  // RNE
    return (u16)r;
}

// ---------------- K0: weight prep ---------------------------------------
__global__ __launch_bounds__(256) void k0_prep(const float* __restrict__ pw,
        const float* __restrict__ w2, const float* __restrict__ w3,
        const float* __restrict__ h2w, const float* __restrict__ h1w,
        const float* __restrict__ w1,
        u16* __restrict__ pwT, u16* __restrict__ w2r, u16* __restrict__ w3r,
        u16* __restrict__ h2hi, u16* __restrict__ h2lo,
        u16* __restrict__ h1hi, u16* __restrict__ h1lo,
        u16* __restrict__ w1hi, u16* __restrict__ w1lo) {
    int idx = blockIdx.x * 256 + threadIdx.x;
    if (idx < 38912) {
        int j = idx / 608, kk = idx - j * 608;
        float v = 0.f;
        if (kk < 576) {
            int p = kk >> 6, oc = kk & 63;
            v = pw[j * 578 + oc * 9 + p];
        } else if (kk < 578) {
            v = pw[j * 578 + kk];
        }
        pwT[idx] = f2bf(v);
    } else if (idx < 40960) {
        int i = idx - 38912;
        int oc = i >> 6, rem = i & 63, tap = rem >> 4, ic = rem & 15;
        w2r[i] = f2bf(w2[oc * 64 + ic * 4 + tap]);
    } else if (idx < 49152) {
        int i = idx - 40960;
        int oc = i >> 7, rem = i & 127, tap = rem >> 5, ic = rem & 31;
        w3r[i] = f2bf(w3[oc * 128 + ic * 4 + tap]);
    } else if (idx < 65536) {
        int i = idx - 49152;
        float v = h2w[i];
        u16 hi = f2bf(v);
        h2hi[i] = hi;
        h2lo[i] = f2bf(v - bf2f(hi));
    } else if (idx < 86016) {
        int i = idx - 65536;
        int j = i / 160, k = i - j * 160;
        float v = (k < 132) ? h1w[j * 132 + k] : 0.f;
        u16 hi = f2bf(v);
        h1hi[i] = hi;
        h1lo[i] = f2bf(v - bf2f(hi));
    } else if (idx < 86528) {
        int i = idx - 86016;               // [oc16][k32]
        int oc = i >> 5, k = i & 31;
        int ky = k >> 4, kx = (k >> 3) & 1, c = k & 7;
        float v = (c < 3) ? w1[oc * 12 + c * 4 + ky * 2 + kx] : 0.f;
        u16 hi = f2bf(v);
        w1hi[i] = hi;
        w1lo[i] = f2bf(v - bf2f(hi));
    }
}

// ---------------- KC: fused conv1+pool -> conv2+pool -> conv3 -> proj ---
// Block = 32 elems, all intermediates in LDS (overlaid; peak 48 KB ->
// 3 blocks/CU). Phases are the byte-identical validated k1/k2/k34 bodies
// with global pointers swapped for LDS. Eliminates pooled1b (32 MB) and
// pooled2 (16 MB) HBM round-trips + two kernel launches.
// LDS map (u16 units): p2L[0,4096) | p1L[4096,12288) | frL[12288,22784)
// featL[4096,24576) overlays p1L+frL (both dead by conv3).
__global__ __launch_bounds__(256) void kconv_all(const int* __restrict__ frame,
        const u16* __restrict__ w1hi, const u16* __restrict__ w1lo,
        const float* __restrict__ b1,
        const u16* __restrict__ w2r, const float* __restrict__ b2,
        const u16* __restrict__ w3r, const float* __restrict__ b3,
        const int* __restrict__ ccol, const int* __restrict__ cobj,
        const u16* __restrict__ pwT, const float* __restrict__ pb,
        float* __restrict__ comb) {
    __shared__ u16 lds[24576];     // 49152 B
    u16* p2L   = lds;              // 4096 u16
    u16* p1L   = lds + 4096;       // 8192 u16
    u16* frL   = lds + 12288;      // 10496 u16 (16 elems x 656)
    u16* featL = lds + 4096;       // 20480 u16 (overlay)
    int t = threadIdx.x;
    int l = t & 63;
    int wv = t >> 6;
    int col = l & 15;
    int kg = l >> 4;
    int e0 = blockIdx.x * 32;

    // zero frL pad ring (whole region once; interior overwritten per half)
    #pragma unroll
    for (int i = 0; i < 6; ++i) {
        int o = i * 256 + t;
        if (o < 1312) *(uint4*)(frL + o * 8) = make_uint4(0u, 0u, 0u, 0u);
    }

    // ---- phase A: conv1+relu+pool (two halves of 16 elems) ----
    {
        bf16x8 c1hi = *(const bf16x8*)(w1hi + col * 32 + kg * 8);
        bf16x8 c1lo = *(const bf16x8*)(w1lo + col * 32 + kg * 8);
        float c1b = b1[col];
        int ky1 = kg >> 1, kx1 = kg & 1;
        bool wr1 = (kg < 2);
        for (int h = 0; h < 2; ++h) {
            __syncthreads();   // frL reusable (zeros done / prev conv1 read done)
            const int* fbase = frame + (size_t)(e0 + h * 16) * 147;
            #pragma unroll
            for (int i = 0; i < 10; ++i) {
                int idx = i * 256 + t;
                if (idx < 2352) {
                    int le = idx / 147, r = idx - le * 147;
                    int cell = r / 3, c = r - cell * 3;
                    int y = cell / 7, x = cell - y * 7;
                    frL[le * 656 + (y + 1) * 72 + (x + 1) * 8 + c] = f2bf((float)fbase[idx]);
                }
            }
            __syncthreads();
            #pragma unroll
            for (int q = 0; q < 4; ++q) {
                int le = wv * 4 + q;
                const u16* eb = frL + le * 656;
                u16* op = p1L + (h * 16 + le) * 256;
                #pragma unroll
                for (int mt = 0; mt < 4; ++mt) {
                    int posA = mt * 16 + col;
                    int oy = posA >> 3, ox = posA & 7;
                    bf16x8 a = *(const bf16x8*)(eb + (oy + ky1) * 72 + (ox + kx1) * 8);
                    f32x4 acc = {0.f, 0.f, 0.f, 0.f};
                    acc = __builtin_amdgcn_mfma_f32_16x16x32_bf16(a, c1hi, acc, 0, 0, 0);
                    acc = __builtin_amdgcn_mfma_f32_16x16x32_bf16(a, c1lo, acc, 0, 0, 0);
                    float x0 = fmaxf(acc[0] + c1b, 0.f);
                    float x1 = fmaxf(acc[1] + c1b, 0.f);
                    float x2 = fmaxf(acc[2] + c1b, 0.f);
                    float x3 = fmaxf(acc[3] + c1b, 0.f);
                    float y0 = fmaxf(x0, x1);
                    float y1 = fmaxf(x2, x3);
                    float m0 = fmaxf(y0, __shfl_xor(y0, 32, 64));
                    float m1 = fmaxf(y1, __shfl_xor(y1, 32, 64));
                    if (wr1) {
                        op[(mt * 4 + kg * 2 + 0) * 16 + col] = f2bf(m0);
                        op[(mt * 4 + kg * 2 + 1) * 16 + col] = f2bf(m1);
                    }
                }
            }
        }
    }
    __syncthreads();

    // ---- phase B: conv2+relu+pool (8 elems/wave) ----
    {
        bf16x8 bfrag[2][2];
        #pragma unroll
        for (int s = 0; s < 2; ++s)
            #pragma unroll
            for (int nt = 0; nt < 2; ++nt)
                bfrag[s][nt] = *(const bf16x8*)(w2r + (nt * 16 + col) * 64 + s * 32 + kg * 8);
        float bias2[2] = { b2[col], b2[16 + col] };
        int oy = col >> 2, ox = col & 3;
        int aoff[2]; bool aok[2];
        #pragma unroll
        for (int s = 0; s < 2; ++s) {
            int tap = 2 * s + (kg >> 1);
            int ky = tap >> 1, kx = tap & 1;
            int iy = oy - 1 + ky, ix = ox - 1 + kx;
            aok[s] = (iy >= 0 && ix >= 0);
            aoff[s] = (iy * 4 + ix) * 16 + (kg & 1) * 8;
        }
        #pragma unroll
        for (int q = 0; q < 8; ++q) {
            int e = wv * 8 + q;
            const u16* pbase = p1L + e * 256;
            bf16x8 a0 = {0,0,0,0,0,0,0,0}, a1 = {0,0,0,0,0,0,0,0};
            if (aok[0]) a0 = *(const bf16x8*)(pbase + aoff[0]);
            if (aok[1]) a1 = *(const bf16x8*)(pbase + aoff[1]);
            f32x4 acc0 = {0.f,0.f,0.f,0.f}, acc1 = {0.f,0.f,0.f,0.f};
            acc0 = __builtin_amdgcn_mfma_f32_16x16x32_bf16(a0, bfrag[0][0], acc0, 0, 0, 0);
            acc1 = __builtin_amdgcn_mfma_f32_16x16x32_bf16(a0, bfrag[0][1], acc1, 0, 0, 0);
            acc0 = __builtin_amdgcn_mfma_f32_16x16x32_bf16(a1, bfrag[1][0], acc0, 0, 0, 0);
            acc1 = __builtin_amdgcn_mfma_f32_16x16x32_bf16(a1, bfrag[1][1], acc1, 0, 0, 0);
            #pragma unroll
            for (int nt = 0; nt < 2; ++nt) {
                f32x4 acc = nt ? acc1 : acc0;
                float b = bias2[nt];
                float m0 = fmaxf(fmaxf(acc[0] + b, 0.f), fmaxf(acc[1] + b, 0.f));
                float m1 = fmaxf(fmaxf(acc[2] + b, 0.f), fmaxf(acc[3] + b, 0.f));
                float p0 = fmaxf(m0, __shfl_xor(m0, 16, 64));
                float p1 = fmaxf(m1, __shfl_xor(m1, 16, 64));
                if ((kg & 1) == 0) {
                    int qq = (kg >> 1) * 2;
                    u16* op = p2L + e * 128 + nt * 16 + col;
                    op[qq * 32]       = f2bf(p0);
                    op[(qq + 1) * 32] = f2bf(p1);
                }
            }
        }
    }
    __syncthreads();   // p1L dead; featL (overlay) writable

    int colhi = col >> 3, collo = col & 7;
    // ---- phase C: conv3 (18 tiles; 4/wave + extra for wv<2) ----
    {
        bf16x8 bfrag[4][4];
        #pragma unroll
        for (int s = 0; s < 4; ++s)
            #pragma unroll
            for (int nt = 0; nt < 4; ++nt)
                bfrag[s][nt] = *(const bf16x8*)(w3r + (nt * 16 + col) * 128 + s * 32 + kg * 8);
        float bias[4];
        #pragma unroll
        for (int nt = 0; nt < 4; ++nt) bias[nt] = b3[nt * 16 + col];

        auto do_tile = [&](int i) {
            int m0 = i * 16;
            int m = m0 + col;
            u32 elem = (u32)(((unsigned long long)(u32)m * 954437177ull) >> 33); // m/9
            int p = m - (int)elem * 9;
            int oy = (p * 86) >> 8;
            int ox = p - 3 * oy;
            const u16* pbase = p2L + elem * 128 + kg * 8;
            f32x4 acc[4];
            #pragma unroll
            for (int nt = 0; nt < 4; ++nt) {
                acc[nt][0] = 0.f; acc[nt][1] = 0.f; acc[nt][2] = 0.f; acc[nt][3] = 0.f;
            }
            #pragma unroll
            for (int s = 0; s < 4; ++s) {
                int ky = s >> 1, kx = s & 1;
                int iy = oy - 1 + ky, ix = ox - 1 + kx;
                bf16x8 a = {0,0,0,0,0,0,0,0};
                if (iy >= 0 && iy <= 1 && ix >= 0 && ix <= 1)
                    a = *(const bf16x8*)(pbase + (iy * 2 + ix) * 32);
                #pragma unroll
                for (int nt = 0; nt < 4; ++nt)
                    acc[nt] = __builtin_amdgcn_mfma_f32_16x16x32_bf16(a, bfrag[s][nt], acc[nt], 0, 0, 0);
            }
            #pragma unroll
            for (int r = 0; r < 4; ++r) {
                int mr = m0 + kg * 4 + r;
                u32 er = (u32)(((unsigned long long)(u32)mr * 954437177ull) >> 33);
                int pr = mr - (int)er * 9;
                int e7 = (int)(er & 7u);
                u16* fb = featL + er * 640 + collo;
                #pragma unroll
                for (int nt = 0; nt < 4; ++nt) {
                    int blk = (pr * 8 + nt * 2 + colhi) ^ e7;
                    fb[blk * 8] = f2bf(fmaxf(acc[nt][r] + bias[nt], 0.f));
                }
            }
        };
        #pragma unroll
        for (int u = 0; u < 4; ++u) do_tile(wv + u * 4);
        if (wv < 2) do_tile(16 + wv);
    }
    // ---- tail: logical slots 576..583 (block 72) of row t ----
    if (t < 32) {
        union { u16 s[8]; uint4 q; } b;
        b.s[0] = f2bf((float)ccol[e0 + t]);
        b.s[1] = f2bf((float)cobj[e0 + t]);
        #pragma unroll
        for (int i = 2; i < 8; ++i) b.s[i] = 0;
        *(uint4*)(featL + t * 640 + (72 ^ (t & 7)) * 8) = b.q;
    }
    __syncthreads();

    // ---- phase D: proj; wave = (row-half rh, n-half nh) ----
    int rh = wv & 1, nh = wv >> 1;
    int m0g = e0 + rh * 16;
    const u16* arowb = featL + (rh * 16 + col) * 640;
    int rx = col & 7;
    const u16* brow = pwT + (nh * 32 + col) * 608 + kg * 8;
    f32x4 acc0 = {0.f,0.f,0.f,0.f}, acc1 = {0.f,0.f,0.f,0.f};
    #pragma unroll
    for (int k0 = 0; k0 < 608; k0 += 32) {
        bf16x8 a;
        if (k0 + kg * 8 < 584) {
            int L = (k0 >> 3) + kg;
            a = *(const bf16x8*)(arowb + (L ^ rx) * 8);
        } else {
            #pragma unroll
            for (int j = 0; j < 8; ++j) a[j] = 0;
        }
        bf16x8 b0 = *(const bf16x8*)(brow + k0);
        bf16x8 b1 = *(const bf16x8*)(brow + 16 * 608 + k0);
        acc0 = __builtin_amdgcn_mfma_f32_16x16x32_bf16(a, b0, acc0, 0, 0, 0);
        acc1 = __builtin_amdgcn_mfma_f32_16x16x32_bf16(a, b1, acc1, 0, 0, 0);
    }
    float* outbase = (m0g < BATCH) ? (comb + (size_t)m0g * 160)
                                   : (comb + (size_t)(m0g - BATCH) * 160 + 64);
    #pragma unroll
    for (int nt = 0; nt < 2; ++nt) {
        int n = nh * 32 + nt * 16 + col;
        float pbv = pb[n];
        f32x4 acc = nt ? acc1 : acc0;
        #pragma unroll
        for (int r = 0; r < 4; ++r) {
            outbase[(kg * 4 + r) * 160 + n] = fmaxf(acc[r] + pbv, 0.f);
        }
    }
}

// ---------------- K5: dir_pos deltas -> comb[b][128..159] --------------
__global__ __launch_bounds__(256) void k5_extras(const int* __restrict__ frame,
        float* __restrict__ comb) {
    int b = blockIdx.x * 256 + threadIdx.x;
    int d[2]; float posy[2], posx[2];
    for (int f = 0; f < 2; ++f) {
        const int* fb = frame + (size_t)(f * BATCH + b) * 147;
        int idx = 49;
        for (int cell = 0; cell < 49; ++cell) {
            int v = fb[cell * 3];
            if (idx == 49 && v == 10) idx = cell;
        }
        if (idx < 49) {
            d[f] = fb[idx * 3 + 2] & 3;
            posy[f] = (float)(idx / 7) / 6.0f;
            posx[f] = (float)(idx % 7) / 6.0f;
        } else {
            d[f] = 0; posy[f] = 0.5f; posx[f] = 0.5f;
        }
    }
    int delta = (d[1] - d[0] + 4) & 3;
    const float ANG = (float)(2.0 * 3.14159 / 4.0);
    float angle = (float)delta * ANG;
    float4 o;
    o.x = sinf(angle);
    o.y = cosf(angle);
    o.z = posy[1] - posy[0];
    o.w = posx[1] - posx[0];
    float* cb = comb + (size_t)b * 160 + 128;
    *(float4*)cb = o;
    float4 z = make_float4(0.f, 0.f, 0.f, 0.f);
    #pragma unroll
    for (int i = 1; i < 8; ++i) *(float4*)(cb + i * 4) = z;
}

__device__ __forceinline__ void split8(const float* __restrict__ x,
                                       bf16x8& hi, bf16x8& lo) {
    #pragma unroll
    for (int j = 0; j < 8; ++j) {
        u16 h = f2bf(x[j]);
        hi[j] = (short)h;
        lo[j] = (short)f2bf(x[j] - bf2f(h));
    }
}

// ---------------- K6a: h1 GEMM via split-bf16 MFMA (no LN) -------------
__global__ __launch_bounds__(256) void k6_h1_gemm(const float* __restrict__ in,
        const u16* __restrict__ whi, const u16* __restrict__ wlo,
        const float* __restrict__ bias, float* __restrict__ out) {
    int t = threadIdx.x;
    int l = t & 63;
    int col = l & 15;
    int kg = l >> 4;
    int m0 = blockIdx.x * 64 + (t >> 6) * 16;
    const float* arow = in + (size_t)(m0 + col) * 160 + kg * 8;
    const u16* bh = whi + col * 160 + kg * 8;
    const u16* bl = wlo + col * 160 + kg * 8;

    f32x4 acc[8];
    #pragma unroll
    for (int nt = 0; nt < 8; ++nt) {
        acc[nt][0] = 0.f; acc[nt][1] = 0.f; acc[nt][2] = 0.f; acc[nt][3] = 0.f;
    }
    #pragma unroll
    for (int s = 0; s < 5; ++s) {
        float x[8];
        #pragma unroll
        for (int j = 0; j < 8; ++j) x[j] = arow[s * 32 + j];
        bf16x8 ahi, alo;
        split8(x, ahi, alo);
        #pragma unroll
        for (int nt = 0; nt < 8; ++nt) {
            bf16x8 bhiF = *(const bf16x8*)(bh + nt * 2560 + s * 32);
            bf16x8 bloF = *(const bf16x8*)(bl + nt * 2560 + s * 32);
            acc[nt] = __builtin_amdgcn_mfma_f32_16x16x32_bf16(ahi, bhiF, acc[nt], 0, 0, 0);
            acc[nt] = __builtin_amdgcn_mfma_f32_16x16x32_bf16(alo, bhiF, acc[nt], 0, 0, 0);
            acc[nt] = __builtin_amdgcn_mfma_f32_16x16x32_bf16(ahi, bloF, acc[nt], 0, 0, 0);
        }
    }
    #pragma unroll
    for (int nt = 0; nt < 8; ++nt) {
        float bv = bias[nt * 16 + col];
        #pragma unroll
        for (int r = 0; r < 4; ++r) {
            int m = m0 + kg * 4 + r;
            out[m * 128 + nt * 16 + col] = acc[nt][r] + bv;
        }
    }
}

// ---------------- K6b: LayerNorm + relu, wave per row ------------------
__global__ __launch_bounds__(256) void k6_ln(const float* __restrict__ h,
        const float* __restrict__ lng, const float* __restrict__ lnb,
        float* __restrict__ out) {
    int w = (blockIdx.x * 256 + threadIdx.x) >> 6;
    int l = threadIdx.x & 63;
    const float* row = h + (size_t)w * 128 + l * 2;
    float2 v = *(const float2*)row;
    float s = v.x + v.y;
    s += __shfl_xor(s, 1, 64);
    s += __shfl_xor(s, 2, 64);
    s += __shfl_xor(s, 4, 64);
    s += __shfl_xor(s, 8, 64);
    s += __shfl_xor(s, 16, 64);
    s += __shfl_xor(s, 32, 64);
    float mu = s * (1.0f / 128.0f);
    float d0 = v.x - mu, d1 = v.y - mu;
    float vs = d0 * d0 + d1 * d1;
    vs += __shfl_xor(vs, 1, 64);
    vs += __shfl_xor(vs, 2, 64);
    vs += __shfl_xor(vs, 4, 64);
    vs += __shfl_xor(vs, 8, 64);
    vs += __shfl_xor(vs, 16, 64);
    vs += __shfl_xor(vs, 32, 64);
    float rs = rsqrtf(vs * (1.0f / 128.0f) + 1e-5f);
    float2 o;
    o.x = fmaxf(d0 * rs * lng[l * 2]     + lnb[l * 2],     0.f);
    o.y = fmaxf(d1 * rs * lng[l * 2 + 1] + lnb[l * 2 + 1], 0.f);
    *(float2*)(out + (size_t)w * 128 + l * 2) = o;
}

// ---------------- K7: h2 via split-bf16 MFMA (fp32 in/out) -------------
__global__ __launch_bounds__(256) void k7_h2_mfma(const float* __restrict__ in,
        const u16* __restrict__ whi, const u16* __restrict__ wlo,
        const float* __restrict__ bias, float* __restrict__ out) {
    int t = threadIdx.x;
    int l = t & 63;
    int col = l & 15;
    int kg = l >> 4;
    int m0 = blockIdx.x * 64 + (t >> 6) * 16;
    const float* arow = in + (size_t)(m0 + col) * 128 + kg * 8;
    const u16* bh = whi + col * 128 + kg * 8;
    const u16* bl = wlo + col * 128 + kg * 8;

    f32x4 acc[8];
    #pragma unroll
    for (int nt = 0; nt < 8; ++nt) {
        acc[nt][0] = 0.f; acc[nt][1] = 0.f; acc[nt][2] = 0.f; acc[nt][3] = 0.f;
    }
    #pragma unroll
    for (int s = 0; s < 4; ++s) {
        float x[8];
        #pragma unroll
        for (int j = 0; j < 8; ++j) x[j] = arow[s * 32 + j];
        bf16x8 ahi, alo;
        split8(x, ahi, alo);
        #pragma unroll
        for (int nt = 0; nt < 8; ++nt) {
            bf16x8 bhiF = *(const bf16x8*)(bh + nt * 2048 + s * 32);
            bf16x8 bloF = *(const bf16x8*)(bl + nt * 2048 + s * 32);
            acc[nt] = __builtin_amdgcn_mfma_f32_16x16x32_bf16(ahi, bhiF, acc[nt], 0, 0, 0);
            acc[nt] = __builtin_amdgcn_mfma_f32_16x16x32_bf16(alo, bhiF, acc[nt], 0, 0, 0);
            acc[nt] = __builtin_amdgcn_mfma_f32_16x16x32_bf16(ahi, bloF, acc[nt], 0, 0, 0);
        }
    }
    #pragma unroll
    for (int nt = 0; nt < 8; ++nt) {
        float bv = bias[nt * 16 + col];
        #pragma unroll
        for (int r = 0; r < 4; ++r) {
            int m = m0 + kg * 4 + r;
            out[m * 128 + nt * 16 + col] = fmaxf(acc[nt][r] + bv, 0.f);
        }
    }
}

// ---------------- K8: h3 [32768x128]@[128->7], thread = row, fp32 ------
__global__ __launch_bounds__(256) void k8_h3(const float* __restrict__ in,
        const float* __restrict__ w, const float* __restrict__ bias,
        float* __restrict__ out) {
    int r = blockIdx.x * 256 + threadIdx.x;
    float acc[7];
    #pragma unroll
    for (int j = 0; j < 7; ++j) acc[j] = bias[j];
    const float* row = in + (size_t)r * 128;
    #pragma unroll 4
    for (int c = 0; c < 32; ++c) {
        float4 v = *(const float4*)(row + c * 4);
        #pragma unroll
        for (int j = 0; j < 7; ++j) {
            acc[j] += v.x * w[j * 128 + c * 4 + 0];
            acc[j] += v.y * w[j * 128 + c * 4 + 1];
            acc[j] += v.z * w[j * 128 + c * 4 + 2];
            acc[j] += v.w * w[j * 128 + c * 4 + 3];
        }
    }
    #pragma unroll
    for (int j = 0; j < 7; ++j) out[r * 7 + j] = acc[j];
}

extern "C" void kernel_launch(void* const* d_in, const int* in_sizes, int n_in,
                              void* d_out, int out_size, void* d_ws, size_t ws_size,
                              hipStream_t stream) {
    const int*   frame = (const int*)d_in[0];
    const int*   ccol  = (const int*)d_in[1];
    const int*   cobj  = (const int*)d_in[2];
    const float* w1    = (const float*)d_in[3];
    const float* b1    = (const float*)d_in[4];
    const float* w2    = (const float*)d_in[5];
    const float* b2    = (const float*)d_in[6];
    const float* w3    = (const float*)d_in[7];
    const float* b3    = (const float*)d_in[8];
    const float* pw    = (const float*)d_in[9];
    const float* pb    = (const float*)d_in[10];
    const float* h1w   = (const float*)d_in[11];
    const float* h1b   = (const float*)d_in[12];
    const float* lng   = (const float*)d_in[13];
    const float* lnb   = (const float*)d_in[14];
    const float* h2w   = (const float*)d_in[15];
    const float* h2b   = (const float*)d_in[16];
    const float* h3w   = (const float*)d_in[17];
    const float* h3b   = (const float*)d_in[18];
    float* out = (float*)d_out;

    char* ws = (char*)d_ws;
    float* comb     = (float*)(ws + 0);                  // 21 MB
    float* h1out    = (float*)(ws + 33554432);           // 16 MB
    float* h2out    = (float*)(ws + 50331648);           // 16 MB
    float* h1pre    = (float*)(ws + 95420416);           // 16 MB
    u16*   pwT      = (u16*)(ws + 132120576);            // 77824 B
    u16*   w2r      = (u16*)(ws + 132120576 + 131072);   // 4096 B
    u16*   w3r      = (u16*)(ws + 132120576 + 139264);   // 16384 B
    u16*   h2hi     = (u16*)(ws + 132120576 + 163840);   // 32768 B
    u16*   h2lo     = (u16*)(ws + 132120576 + 196608);   // 32768 B
    u16*   h1hi     = (u16*)(ws + 132120576 + 229376);   // 40960 B
    u16*   h1lo     = (u16*)(ws + 132120576 + 270336);   // 40960 B
    u16*   w1hi     = (u16*)(ws + 132120576 + 311296);   // 1024 B
    u16*   w1lo     = (u16*)(ws + 132120576 + 312320);   // 1024 B

    k0_prep<<<340, 256, 0, stream>>>(pw, w2, w3, h2w, h1w, w1,
                                     pwT, w2r, w3r, h2hi, h2lo, h1hi, h1lo,
                                     w1hi, w1lo);
    kconv_all<<<2048, 256, 0, stream>>>(frame, w1hi, w1lo, b1, w2r, b2,
                                        w3r, b3, ccol, cobj, pwT, pb, comb);
    k5_extras<<<128, 256, 0, stream>>>(frame, comb);
    k6_h1_gemm<<<512, 256, 0, stream>>>(comb, h1hi, h1lo, h1b, h1pre);
    k6_ln<<<8192, 256, 0, stream>>>(h1pre, lng, lnb, h1out);
    k7_h2_mfma<<<512, 256, 0, stream>>>(h1out, h2hi, h2lo, h2b, h2out);
    k8_h3<<<128, 256, 0, stream>>>(h2out, h3w, h3b, out);
}

// Round 20
// 248.825 us; speedup vs baseline: 1.2417x; 1.0284x over previous
//
#include <hip/hip_runtime.h>
#include <hip/hip_bf16.h>

#define BATCH 32768
#define NELEM 65536   // 2 * BATCH

typedef unsigned short u16;
typedef unsigned int u32;
typedef __attribute__((ext_vector_type(8))) short bf16x8;
typedef __attribute__((ext_vector_type(4))) float f32x4;

__device__ __forceinline__ float bf2f(u16 u) {
    union { u32 u; float f; } c; c.u = ((u32)u) << 16; return c.f;
}
__device__ __forceinline__ u16 f2bf(float f) {
    union { float f; u32 u; } c; c.f = f;
    u32 x = c.u;
    u32 r = (x + 0x7fffu + ((x >> 16) & 1u)) >> 16;  // RNE
    return (u16)r;
}

// ---------------- K0: weight prep ---------------------------------------
__global__ __launch_bounds__(256) void k0_prep(const float* __restrict__ pw,
        const float* __restrict__ w2, const float* __restrict__ w3,
        const float* __restrict__ h2w, const float* __restrict__ h1w,
        const float* __restrict__ w1,
        u16* __restrict__ pwT, u16* __restrict__ w2r, u16* __restrict__ w3r,
        u16* __restrict__ h2hi, u16* __restrict__ h2lo,
        u16* __restrict__ h1hi, u16* __restrict__ h1lo,
        u16* __restrict__ w1hi, u16* __restrict__ w1lo) {
    int idx = blockIdx.x * 256 + threadIdx.x;
    if (idx < 38912) {
        int j = idx / 608, kk = idx - j * 608;
        float v = 0.f;
        if (kk < 576) {
            int p = kk >> 6, oc = kk & 63;
            v = pw[j * 578 + oc * 9 + p];
        } else if (kk < 578) {
            v = pw[j * 578 + kk];
        }
        pwT[idx] = f2bf(v);
    } else if (idx < 40960) {
        int i = idx - 38912;
        int oc = i >> 6, rem = i & 63, tap = rem >> 4, ic = rem & 15;
        w2r[i] = f2bf(w2[oc * 64 + ic * 4 + tap]);
    } else if (idx < 49152) {
        int i = idx - 40960;
        int oc = i >> 7, rem = i & 127, tap = rem >> 5, ic = rem & 31;
        w3r[i] = f2bf(w3[oc * 128 + ic * 4 + tap]);
    } else if (idx < 65536) {
        int i = idx - 49152;
        float v = h2w[i];
        u16 hi = f2bf(v);
        h2hi[i] = hi;
        h2lo[i] = f2bf(v - bf2f(hi));
    } else if (idx < 86016) {
        int i = idx - 65536;
        int j = i / 160, k = i - j * 160;
        float v = (k < 132) ? h1w[j * 132 + k] : 0.f;
        u16 hi = f2bf(v);
        h1hi[i] = hi;
        h1lo[i] = f2bf(v - bf2f(hi));
    } else if (idx < 86528) {
        int i = idx - 86016;               // [oc16][k32]
        int oc = i >> 5, k = i & 31;
        int ky = k >> 4, kx = (k >> 3) & 1, c = k & 7;
        float v = (c < 3) ? w1[oc * 12 + c * 4 + ky * 2 + kx] : 0.f;
        u16 hi = f2bf(v);
        w1hi[i] = hi;
        w1lo[i] = f2bf(v - bf2f(hi));
    }
}

// ---------------- KC: fused conv1+pool -> conv2+pool -> conv3 -> proj ---
__global__ __launch_bounds__(256) void kconv_all(const int* __restrict__ frame,
        const u16* __restrict__ w1hi, const u16* __restrict__ w1lo,
        const float* __restrict__ b1,
        const u16* __restrict__ w2r, const float* __restrict__ b2,
        const u16* __restrict__ w3r, const float* __restrict__ b3,
        const int* __restrict__ ccol, const int* __restrict__ cobj,
        const u16* __restrict__ pwT, const float* __restrict__ pb,
        float* __restrict__ comb) {
    __shared__ u16 lds[24576];     // 49152 B
    u16* p2L   = lds;              // 4096 u16
    u16* p1L   = lds + 4096;       // 8192 u16
    u16* frL   = lds + 12288;      // 10496 u16 (16 elems x 656)
    u16* featL = lds + 4096;       // 20480 u16 (overlay)
    int t = threadIdx.x;
    int l = t & 63;
    int wv = t >> 6;
    int col = l & 15;
    int kg = l >> 4;
    int e0 = blockIdx.x * 32;

    #pragma unroll
    for (int i = 0; i < 6; ++i) {
        int o = i * 256 + t;
        if (o < 1312) *(uint4*)(frL + o * 8) = make_uint4(0u, 0u, 0u, 0u);
    }

    // ---- phase A: conv1+relu+pool (two halves of 16 elems) ----
    {
        bf16x8 c1hi = *(const bf16x8*)(w1hi + col * 32 + kg * 8);
        bf16x8 c1lo = *(const bf16x8*)(w1lo + col * 32 + kg * 8);
        float c1b = b1[col];
        int ky1 = kg >> 1, kx1 = kg & 1;
        bool wr1 = (kg < 2);
        for (int h = 0; h < 2; ++h) {
            __syncthreads();
            const int* fbase = frame + (size_t)(e0 + h * 16) * 147;
            #pragma unroll
            for (int i = 0; i < 10; ++i) {
                int idx = i * 256 + t;
                if (idx < 2352) {
                    int le = idx / 147, r = idx - le * 147;
                    int cell = r / 3, c = r - cell * 3;
                    int y = cell / 7, x = cell - y * 7;
                    frL[le * 656 + (y + 1) * 72 + (x + 1) * 8 + c] = f2bf((float)fbase[idx]);
                }
            }
            __syncthreads();
            #pragma unroll
            for (int q = 0; q < 4; ++q) {
                int le = wv * 4 + q;
                const u16* eb = frL + le * 656;
                u16* op = p1L + (h * 16 + le) * 256;
                #pragma unroll
                for (int mt = 0; mt < 4; ++mt) {
                    int posA = mt * 16 + col;
                    int oy = posA >> 3, ox = posA & 7;
                    bf16x8 a = *(const bf16x8*)(eb + (oy + ky1) * 72 + (ox + kx1) * 8);
                    f32x4 acc = {0.f, 0.f, 0.f, 0.f};
                    acc = __builtin_amdgcn_mfma_f32_16x16x32_bf16(a, c1hi, acc, 0, 0, 0);
                    acc = __builtin_amdgcn_mfma_f32_16x16x32_bf16(a, c1lo, acc, 0, 0, 0);
                    float x0 = fmaxf(acc[0] + c1b, 0.f);
                    float x1 = fmaxf(acc[1] + c1b, 0.f);
                    float x2 = fmaxf(acc[2] + c1b, 0.f);
                    float x3 = fmaxf(acc[3] + c1b, 0.f);
                    float y0 = fmaxf(x0, x1);
                    float y1 = fmaxf(x2, x3);
                    float m0 = fmaxf(y0, __shfl_xor(y0, 32, 64));
                    float m1 = fmaxf(y1, __shfl_xor(y1, 32, 64));
                    if (wr1) {
                        op[(mt * 4 + kg * 2 + 0) * 16 + col] = f2bf(m0);
                        op[(mt * 4 + kg * 2 + 1) * 16 + col] = f2bf(m1);
                    }
                }
            }
        }
    }
    __syncthreads();

    // ---- phase B: conv2+relu+pool (8 elems/wave) ----
    {
        bf16x8 bfrag[2][2];
        #pragma unroll
        for (int s = 0; s < 2; ++s)
            #pragma unroll
            for (int nt = 0; nt < 2; ++nt)
                bfrag[s][nt] = *(const bf16x8*)(w2r + (nt * 16 + col) * 64 + s * 32 + kg * 8);
        float bias2[2] = { b2[col], b2[16 + col] };
        int oy = col >> 2, ox = col & 3;
        int aoff[2]; bool aok[2];
        #pragma unroll
        for (int s = 0; s < 2; ++s) {
            int tap = 2 * s + (kg >> 1);
            int ky = tap >> 1, kx = tap & 1;
            int iy = oy - 1 + ky, ix = ox - 1 + kx;
            aok[s] = (iy >= 0 && ix >= 0);
            aoff[s] = (iy * 4 + ix) * 16 + (kg & 1) * 8;
        }
        #pragma unroll
        for (int q = 0; q < 8; ++q) {
            int e = wv * 8 + q;
            const u16* pbase = p1L + e * 256;
            bf16x8 a0 = {0,0,0,0,0,0,0,0}, a1 = {0,0,0,0,0,0,0,0};
            if (aok[0]) a0 = *(const bf16x8*)(pbase + aoff[0]);
            if (aok[1]) a1 = *(const bf16x8*)(pbase + aoff[1]);
            f32x4 acc0 = {0.f,0.f,0.f,0.f}, acc1 = {0.f,0.f,0.f,0.f};
            acc0 = __builtin_amdgcn_mfma_f32_16x16x32_bf16(a0, bfrag[0][0], acc0, 0, 0, 0);
            acc1 = __builtin_amdgcn_mfma_f32_16x16x32_bf16(a0, bfrag[0][1], acc1, 0, 0, 0);
            acc0 = __builtin_amdgcn_mfma_f32_16x16x32_bf16(a1, bfrag[1][0], acc0, 0, 0, 0);
            acc1 = __builtin_amdgcn_mfma_f32_16x16x32_bf16(a1, bfrag[1][1], acc1, 0, 0, 0);
            #pragma unroll
            for (int nt = 0; nt < 2; ++nt) {
                f32x4 acc = nt ? acc1 : acc0;
                float b = bias2[nt];
                float m0 = fmaxf(fmaxf(acc[0] + b, 0.f), fmaxf(acc[1] + b, 0.f));
                float m1 = fmaxf(fmaxf(acc[2] + b, 0.f), fmaxf(acc[3] + b, 0.f));
                float p0 = fmaxf(m0, __shfl_xor(m0, 16, 64));
                float p1 = fmaxf(m1, __shfl_xor(m1, 16, 64));
                if ((kg & 1) == 0) {
                    int qq = (kg >> 1) * 2;
                    u16* op = p2L + e * 128 + nt * 16 + col;
                    op[qq * 32]       = f2bf(p0);
                    op[(qq + 1) * 32] = f2bf(p1);
                }
            }
        }
    }
    __syncthreads();   // p1L dead; featL (overlay) writable

    int colhi = col >> 3, collo = col & 7;
    // ---- phase C: conv3 (18 tiles; 4/wave + extra for wv<2) ----
    {
        bf16x8 bfrag[4][4];
        #pragma unroll
        for (int s = 0; s < 4; ++s)
            #pragma unroll
            for (int nt = 0; nt < 4; ++nt)
                bfrag[s][nt] = *(const bf16x8*)(w3r + (nt * 16 + col) * 128 + s * 32 + kg * 8);
        float bias[4];
        #pragma unroll
        for (int nt = 0; nt < 4; ++nt) bias[nt] = b3[nt * 16 + col];

        auto do_tile = [&](int i) {
            int m0 = i * 16;
            int m = m0 + col;
            u32 elem = (u32)(((unsigned long long)(u32)m * 954437177ull) >> 33); // m/9
            int p = m - (int)elem * 9;
            int oy = (p * 86) >> 8;
            int ox = p - 3 * oy;
            const u16* pbase = p2L + elem * 128 + kg * 8;
            f32x4 acc[4];
            #pragma unroll
            for (int nt = 0; nt < 4; ++nt) {
                acc[nt][0] = 0.f; acc[nt][1] = 0.f; acc[nt][2] = 0.f; acc[nt][3] = 0.f;
            }
            #pragma unroll
            for (int s = 0; s < 4; ++s) {
                int ky = s >> 1, kx = s & 1;
                int iy = oy - 1 + ky, ix = ox - 1 + kx;
                bf16x8 a = {0,0,0,0,0,0,0,0};
                if (iy >= 0 && iy <= 1 && ix >= 0 && ix <= 1)
                    a = *(const bf16x8*)(pbase + (iy * 2 + ix) * 32);
                #pragma unroll
                for (int nt = 0; nt < 4; ++nt)
                    acc[nt] = __builtin_amdgcn_mfma_f32_16x16x32_bf16(a, bfrag[s][nt], acc[nt], 0, 0, 0);
            }
            #pragma unroll
            for (int r = 0; r < 4; ++r) {
                int mr = m0 + kg * 4 + r;
                u32 er = (u32)(((unsigned long long)(u32)mr * 954437177ull) >> 33);
                int pr = mr - (int)er * 9;
                int e7 = (int)(er & 7u);
                u16* fb = featL + er * 640 + collo;
                #pragma unroll
                for (int nt = 0; nt < 4; ++nt) {
                    int blk = (pr * 8 + nt * 2 + colhi) ^ e7;
                    fb[blk * 8] = f2bf(fmaxf(acc[nt][r] + bias[nt], 0.f));
                }
            }
        };
        #pragma unroll
        for (int u = 0; u < 4; ++u) do_tile(wv + u * 4);
        if (wv < 2) do_tile(16 + wv);
    }
    if (t < 32) {
        union { u16 s[8]; uint4 q; } b;
        b.s[0] = f2bf((float)ccol[e0 + t]);
        b.s[1] = f2bf((float)cobj[e0 + t]);
        #pragma unroll
        for (int i = 2; i < 8; ++i) b.s[i] = 0;
        *(uint4*)(featL + t * 640 + (72 ^ (t & 7)) * 8) = b.q;
    }
    __syncthreads();

    // ---- phase D: proj; wave = (row-half rh, n-half nh) ----
    int rh = wv & 1, nh = wv >> 1;
    int m0g = e0 + rh * 16;
    const u16* arowb = featL + (rh * 16 + col) * 640;
    int rx = col & 7;
    const u16* brow = pwT + (nh * 32 + col) * 608 + kg * 8;
    f32x4 acc0 = {0.f,0.f,0.f,0.f}, acc1 = {0.f,0.f,0.f,0.f};
    #pragma unroll
    for (int k0 = 0; k0 < 608; k0 += 32) {
        bf16x8 a;
        if (k0 + kg * 8 < 584) {
            int L = (k0 >> 3) + kg;
            a = *(const bf16x8*)(arowb + (L ^ rx) * 8);
        } else {
            #pragma unroll
            for (int j = 0; j < 8; ++j) a[j] = 0;
        }
        bf16x8 b0 = *(const bf16x8*)(brow + k0);
        bf16x8 b1 = *(const bf16x8*)(brow + 16 * 608 + k0);
        acc0 = __builtin_amdgcn_mfma_f32_16x16x32_bf16(a, b0, acc0, 0, 0, 0);
        acc1 = __builtin_amdgcn_mfma_f32_16x16x32_bf16(a, b1, acc1, 0, 0, 0);
    }
    float* outbase = (m0g < BATCH) ? (comb + (size_t)m0g * 160)
                                   : (comb + (size_t)(m0g - BATCH) * 160 + 64);
    #pragma unroll
    for (int nt = 0; nt < 2; ++nt) {
        int n = nh * 32 + nt * 16 + col;
        float pbv = pb[n];
        f32x4 acc = nt ? acc1 : acc0;
        #pragma unroll
        for (int r = 0; r < 4; ++r) {
            outbase[(kg * 4 + r) * 160 + n] = fmaxf(acc[r] + pbv, 0.f);
        }
    }
}

// ---------------- K5: dir_pos deltas -> comb[b][128..159] --------------
__global__ __launch_bounds__(256) void k5_extras(const int* __restrict__ frame,
        float* __restrict__ comb) {
    int b = blockIdx.x * 256 + threadIdx.x;
    int d[2]; float posy[2], posx[2];
    for (int f = 0; f < 2; ++f) {
        const int* fb = frame + (size_t)(f * BATCH + b) * 147;
        int idx = 49;
        for (int cell = 0; cell < 49; ++cell) {
            int v = fb[cell * 3];
            if (idx == 49 && v == 10) idx = cell;
        }
        if (idx < 49) {
            d[f] = fb[idx * 3 + 2] & 3;
            posy[f] = (float)(idx / 7) / 6.0f;
            posx[f] = (float)(idx % 7) / 6.0f;
        } else {
            d[f] = 0; posy[f] = 0.5f; posx[f] = 0.5f;
        }
    }
    int delta = (d[1] - d[0] + 4) & 3;
    const float ANG = (float)(2.0 * 3.14159 / 4.0);
    float angle = (float)delta * ANG;
    float4 o;
    o.x = sinf(angle);
    o.y = cosf(angle);
    o.z = posy[1] - posy[0];
    o.w = posx[1] - posx[0];
    float* cb = comb + (size_t)b * 160 + 128;
    *(float4*)cb = o;
    float4 z = make_float4(0.f, 0.f, 0.f, 0.f);
    #pragma unroll
    for (int i = 1; i < 8; ++i) *(float4*)(cb + i * 4) = z;
}

__device__ __forceinline__ void split8(const float* __restrict__ x,
                                       bf16x8& hi, bf16x8& lo) {
    #pragma unroll
    for (int j = 0; j < 8; ++j) {
        u16 h = f2bf(x[j]);
        hi[j] = (short)h;
        lo[j] = (short)f2bf(x[j] - bf2f(h));
    }
}

// ---------------- KM: fused h1 GEMM -> LN -> h2 GEMM -> h3 -------------
// Block = 64 rows; the 64x128 activation tile lives in LDS hL[64][132]
// (33792 B -> 4 blocks/CU). Phases are the validated k6a / k6_ln / k7 /
// k8 bodies with global pointers swapped for LDS (fp32 round-trips are
// exact; FMA orders unchanged -> bit-identical). Kills h1pre/h1out/h2out
// HBM round-trips (96 MB) + 3 launches.
__global__ __launch_bounds__(256) void kmlp(const float* __restrict__ comb,
        const u16* __restrict__ h1hi, const u16* __restrict__ h1lo,
        const float* __restrict__ h1b,
        const float* __restrict__ lng, const float* __restrict__ lnb,
        const u16* __restrict__ h2hi, const u16* __restrict__ h2lo,
        const float* __restrict__ h2b,
        const float* __restrict__ h3w, const float* __restrict__ h3b,
        float* __restrict__ out) {
    __shared__ float hL[64 * 132];
    int t = threadIdx.x;
    int l = t & 63;
    int col = l & 15;
    int kg = l >> 4;
    int wv = t >> 6;
    int mb = blockIdx.x * 64;

    // ---- phase 1: h1 GEMM (k6a body), epilogue -> hL ----
    {
        const float* arow = comb + (size_t)(mb + wv * 16 + col) * 160 + kg * 8;
        const u16* bh = h1hi + col * 160 + kg * 8;
        const u16* bl = h1lo + col * 160 + kg * 8;
        f32x4 acc[8];
        #pragma unroll
        for (int nt = 0; nt < 8; ++nt) {
            acc[nt][0] = 0.f; acc[nt][1] = 0.f; acc[nt][2] = 0.f; acc[nt][3] = 0.f;
        }
        #pragma unroll
        for (int s = 0; s < 5; ++s) {
            float x[8];
            #pragma unroll
            for (int j = 0; j < 8; ++j) x[j] = arow[s * 32 + j];
            bf16x8 ahi, alo;
            split8(x, ahi, alo);
            #pragma unroll
            for (int nt = 0; nt < 8; ++nt) {
                bf16x8 bhiF = *(const bf16x8*)(bh + nt * 2560 + s * 32);
                bf16x8 bloF = *(const bf16x8*)(bl + nt * 2560 + s * 32);
                acc[nt] = __builtin_amdgcn_mfma_f32_16x16x32_bf16(ahi, bhiF, acc[nt], 0, 0, 0);
                acc[nt] = __builtin_amdgcn_mfma_f32_16x16x32_bf16(alo, bhiF, acc[nt], 0, 0, 0);
                acc[nt] = __builtin_amdgcn_mfma_f32_16x16x32_bf16(ahi, bloF, acc[nt], 0, 0, 0);
            }
        }
        #pragma unroll
        for (int nt = 0; nt < 8; ++nt) {
            float bv = h1b[nt * 16 + col];
            #pragma unroll
            for (int r = 0; r < 4; ++r)
                hL[(wv * 16 + kg * 4 + r) * 132 + nt * 16 + col] = acc[nt][r] + bv;
        }
    }
    __syncthreads();

    // ---- phase 2: LN + relu in place (k6_ln body, wave's 16 rows) ----
    for (int rr = 0; rr < 16; ++rr) {
        float* rp = hL + (wv * 16 + rr) * 132 + l * 2;
        float2 v = *(const float2*)rp;
        float s = v.x + v.y;
        s += __shfl_xor(s, 1, 64);
        s += __shfl_xor(s, 2, 64);
        s += __shfl_xor(s, 4, 64);
        s += __shfl_xor(s, 8, 64);
        s += __shfl_xor(s, 16, 64);
        s += __shfl_xor(s, 32, 64);
        float mu = s * (1.0f / 128.0f);
        float d0 = v.x - mu, d1 = v.y - mu;
        float vs = d0 * d0 + d1 * d1;
        vs += __shfl_xor(vs, 1, 64);
        vs += __shfl_xor(vs, 2, 64);
        vs += __shfl_xor(vs, 4, 64);
        vs += __shfl_xor(vs, 8, 64);
        vs += __shfl_xor(vs, 16, 64);
        vs += __shfl_xor(vs, 32, 64);
        float rs = rsqrtf(vs * (1.0f / 128.0f) + 1e-5f);
        float2 o;
        o.x = fmaxf(d0 * rs * lng[l * 2]     + lnb[l * 2],     0.f);
        o.y = fmaxf(d1 * rs * lng[l * 2 + 1] + lnb[l * 2 + 1], 0.f);
        *(float2*)rp = o;
    }
    __syncthreads();

    // ---- phase 3: h2 GEMM (k7 body), A from hL, in-place epilogue ----
    {
        const float* arow = hL + (wv * 16 + col) * 132 + kg * 8;
        const u16* bh = h2hi + col * 128 + kg * 8;
        const u16* bl = h2lo + col * 128 + kg * 8;
        f32x4 acc[8];
        #pragma unroll
        for (int nt = 0; nt < 8; ++nt) {
            acc[nt][0] = 0.f; acc[nt][1] = 0.f; acc[nt][2] = 0.f; acc[nt][3] = 0.f;
        }
        #pragma unroll
        for (int s = 0; s < 4; ++s) {
            float x[8];
            #pragma unroll
            for (int j = 0; j < 8; ++j) x[j] = arow[s * 32 + j];
            bf16x8 ahi, alo;
            split8(x, ahi, alo);
            #pragma unroll
            for (int nt = 0; nt < 8; ++nt) {
                bf16x8 bhiF = *(const bf16x8*)(bh + nt * 2048 + s * 32);
                bf16x8 bloF = *(const bf16x8*)(bl + nt * 2048 + s * 32);
                acc[nt] = __builtin_amdgcn_mfma_f32_16x16x32_bf16(ahi, bhiF, acc[nt], 0, 0, 0);
                acc[nt] = __builtin_amdgcn_mfma_f32_16x16x32_bf16(alo, bhiF, acc[nt], 0, 0, 0);
                acc[nt] = __builtin_amdgcn_mfma_f32_16x16x32_bf16(ahi, bloF, acc[nt], 0, 0, 0);
            }
        }
        #pragma unroll
        for (int nt = 0; nt < 8; ++nt) {
            float bv = h2b[nt * 16 + col];
            #pragma unroll
            for (int r = 0; r < 4; ++r)
                hL[(wv * 16 + kg * 4 + r) * 132 + nt * 16 + col] = fmaxf(acc[nt][r] + bv, 0.f);
        }
    }
    __syncthreads();

    // ---- phase 4: h3 (k8 body); thread = (row, j-pair) ----
    {
        int row = t >> 2, jq = t & 3, j0 = jq * 2;
        const float* rp = hL + row * 132;
        float a0 = h3b[j0];
        float a1 = (jq < 3) ? h3b[j0 + 1] : 0.f;
        #pragma unroll 4
        for (int c = 0; c < 32; ++c) {
            float4 v = *(const float4*)(rp + c * 4);
            const float* wr0 = h3w + j0 * 128 + c * 4;
            a0 += v.x * wr0[0];
            a0 += v.y * wr0[1];
            a0 += v.z * wr0[2];
            a0 += v.w * wr0[3];
            if (jq < 3) {
                const float* wr1 = h3w + (j0 + 1) * 128 + c * 4;
                a1 += v.x * wr1[0];
                a1 += v.y * wr1[1];
                a1 += v.z * wr1[2];
                a1 += v.w * wr1[3];
            }
        }
        float* ob = out + (size_t)(mb + row) * 7;
        ob[j0] = a0;
        if (jq < 3) ob[j0 + 1] = a1;
    }
}

extern "C" void kernel_launch(void* const* d_in, const int* in_sizes, int n_in,
                              void* d_out, int out_size, void* d_ws, size_t ws_size,
                              hipStream_t stream) {
    const int*   frame = (const int*)d_in[0];
    const int*   ccol  = (const int*)d_in[1];
    const int*   cobj  = (const int*)d_in[2];
    const float* w1    = (const float*)d_in[3];
    const float* b1    = (const float*)d_in[4];
    const float* w2    = (const float*)d_in[5];
    const float* b2    = (const float*)d_in[6];
    const float* w3    = (const float*)d_in[7];
    const float* b3    = (const float*)d_in[8];
    const float* pw    = (const float*)d_in[9];
    const float* pb    = (const float*)d_in[10];
    const float* h1w   = (const float*)d_in[11];
    const float* h1b   = (const float*)d_in[12];
    const float* lng   = (const float*)d_in[13];
    const float* lnb   = (const float*)d_in[14];
    const float* h2w   = (const float*)d_in[15];
    const float* h2b   = (const float*)d_in[16];
    const float* h3w   = (const float*)d_in[17];
    const float* h3b   = (const float*)d_in[18];
    float* out = (float*)d_out;

    char* ws = (char*)d_ws;
    float* comb     = (float*)(ws + 0);                  // 21 MB
    u16*   pwT      = (u16*)(ws + 132120576);            // 77824 B
    u16*   w2r      = (u16*)(ws + 132120576 + 131072);   // 4096 B
    u16*   w3r      = (u16*)(ws + 132120576 + 139264);   // 16384 B
    u16*   h2hi     = (u16*)(ws + 132120576 + 163840);   // 32768 B
    u16*   h2lo     = (u16*)(ws + 132120576 + 196608);   // 32768 B
    u16*   h1hi     = (u16*)(ws + 132120576 + 229376);   // 40960 B
    u16*   h1lo     = (u16*)(ws + 132120576 + 270336);   // 40960 B
    u16*   w1hi     = (u16*)(ws + 132120576 + 311296);   // 1024 B
    u16*   w1lo     = (u16*)(ws + 132120576 + 312320);   // 1024 B

    k0_prep<<<340, 256, 0, stream>>>(pw, w2, w3, h2w, h1w, w1,
                                     pwT, w2r, w3r, h2hi, h2lo, h1hi, h1lo,
                                     w1hi, w1lo);
    kconv_all<<<2048, 256, 0, stream>>>(frame, w1hi, w1lo, b1, w2r, b2,
                                        w3r, b3, ccol, cobj, pwT, pb, comb);
    k5_extras<<<128, 256, 0, stream>>>(frame, comb);
    kmlp<<<512, 256, 0, stream>>>(comb, h1hi, h1lo, h1b, lng, lnb,
                                  h2hi, h2lo, h2b, h3w, h3b, out);
}

// Round 21
// 230.963 us; speedup vs baseline: 1.3377x; 1.0773x over previous
//
#include <hip/hip_runtime.h>
#include <hip/hip_bf16.h>

#define BATCH 32768
#define NELEM 65536   // 2 * BATCH

typedef unsigned short u16;
typedef unsigned int u32;
typedef __attribute__((ext_vector_type(8))) short bf16x8;
typedef __attribute__((ext_vector_type(4))) float f32x4;

__device__ __forceinline__ float bf2f(u16 u) {
    union { u32 u; float f; } c; c.u = ((u32)u) << 16; return c.f;
}
__device__ __forceinline__ u16 f2bf(float f) {
    union { float f; u32 u; } c; c.f = f;
    u32 x = c.u;
    u32 r = (x + 0x7fffu + ((x >> 16) & 1u)) >> 16;  // RNE
    return (u16)r;
}

// ---------------- K0: weight prep ---------------------------------------
__global__ __launch_bounds__(256) void k0_prep(const float* __restrict__ pw,
        const float* __restrict__ w2, const float* __restrict__ w3,
        const float* __restrict__ h2w, const float* __restrict__ h1w,
        const float* __restrict__ w1,
        u16* __restrict__ pwT, u16* __restrict__ w2r, u16* __restrict__ w3r,
        u16* __restrict__ h2hi, u16* __restrict__ h2lo,
        u16* __restrict__ h1hi, u16* __restrict__ h1lo,
        u16* __restrict__ w1hi, u16* __restrict__ w1lo) {
    int idx = blockIdx.x * 256 + threadIdx.x;
    if (idx < 38912) {
        int j = idx / 608, kk = idx - j * 608;
        float v = 0.f;
        if (kk < 576) {
            int p = kk >> 6, oc = kk & 63;
            v = pw[j * 578 + oc * 9 + p];
        } else if (kk < 578) {
            v = pw[j * 578 + kk];
        }
        pwT[idx] = f2bf(v);
    } else if (idx < 40960) {
        int i = idx - 38912;
        int oc = i >> 6, rem = i & 63, tap = rem >> 4, ic = rem & 15;
        w2r[i] = f2bf(w2[oc * 64 + ic * 4 + tap]);
    } else if (idx < 49152) {
        int i = idx - 40960;
        int oc = i >> 7, rem = i & 127, tap = rem >> 5, ic = rem & 31;
        w3r[i] = f2bf(w3[oc * 128 + ic * 4 + tap]);
    } else if (idx < 65536) {
        int i = idx - 49152;
        float v = h2w[i];
        u16 hi = f2bf(v);
        h2hi[i] = hi;
        h2lo[i] = f2bf(v - bf2f(hi));
    } else if (idx < 86016) {
        int i = idx - 65536;
        int j = i / 160, k = i - j * 160;
        float v = (k < 132) ? h1w[j * 132 + k] : 0.f;
        u16 hi = f2bf(v);
        h1hi[i] = hi;
        h1lo[i] = f2bf(v - bf2f(hi));
    } else if (idx < 86528) {
        int i = idx - 86016;               // [oc16][k32]
        int oc = i >> 5, k = i & 31;
        int ky = k >> 4, kx = (k >> 3) & 1, c = k & 7;
        float v = (c < 3) ? w1[oc * 12 + c * 4 + ky * 2 + kx] : 0.f;
        u16 hi = f2bf(v);
        w1hi[i] = hi;
        w1lo[i] = f2bf(v - bf2f(hi));
    }
}

// ---------------- KC: fused conv1+pool -> conv2+pool -> conv3 -> proj ---
// Also computes per-frame dir/pos (d, posy, posx) from the LDS-staged
// frame (bf16-exact for ints 0..10; ==10 and &3 identical to the old
// k5 int path) -> fdir[NELEM] float4. k5_extras eliminated.
// comb is now [b][128] (extras synthesized in kmlp from fdir).
__global__ __launch_bounds__(256) void kconv_all(const int* __restrict__ frame,
        const u16* __restrict__ w1hi, const u16* __restrict__ w1lo,
        const float* __restrict__ b1,
        const u16* __restrict__ w2r, const float* __restrict__ b2,
        const u16* __restrict__ w3r, const float* __restrict__ b3,
        const int* __restrict__ ccol, const int* __restrict__ cobj,
        const u16* __restrict__ pwT, const float* __restrict__ pb,
        float* __restrict__ comb, float4* __restrict__ fdir) {
    __shared__ u16 lds[24576];     // 49152 B
    u16* p2L   = lds;              // 4096 u16
    u16* p1L   = lds + 4096;       // 8192 u16
    u16* frL   = lds + 12288;      // 10496 u16 (16 elems x 656)
    u16* featL = lds + 4096;       // 20480 u16 (overlay)
    int t = threadIdx.x;
    int l = t & 63;
    int wv = t >> 6;
    int col = l & 15;
    int kg = l >> 4;
    int e0 = blockIdx.x * 32;

    #pragma unroll
    for (int i = 0; i < 6; ++i) {
        int o = i * 256 + t;
        if (o < 1312) *(uint4*)(frL + o * 8) = make_uint4(0u, 0u, 0u, 0u);
    }

    // ---- phase A: conv1+relu+pool (two halves of 16 elems) + dir scan ----
    {
        bf16x8 c1hi = *(const bf16x8*)(w1hi + col * 32 + kg * 8);
        bf16x8 c1lo = *(const bf16x8*)(w1lo + col * 32 + kg * 8);
        float c1b = b1[col];
        int ky1 = kg >> 1, kx1 = kg & 1;
        bool wr1 = (kg < 2);
        for (int h = 0; h < 2; ++h) {
            __syncthreads();
            const int* fbase = frame + (size_t)(e0 + h * 16) * 147;
            #pragma unroll
            for (int i = 0; i < 10; ++i) {
                int idx = i * 256 + t;
                if (idx < 2352) {
                    int le = idx / 147, r = idx - le * 147;
                    int cell = r / 3, c = r - cell * 3;
                    int y = cell / 7, x = cell - y * 7;
                    frL[le * 656 + (y + 1) * 72 + (x + 1) * 8 + c] = f2bf((float)fbase[idx]);
                }
            }
            __syncthreads();
            #pragma unroll
            for (int q = 0; q < 4; ++q) {
                int le = wv * 4 + q;
                const u16* eb = frL + le * 656;
                u16* op = p1L + (h * 16 + le) * 256;
                #pragma unroll
                for (int mt = 0; mt < 4; ++mt) {
                    int posA = mt * 16 + col;
                    int oy = posA >> 3, ox = posA & 7;
                    bf16x8 a = *(const bf16x8*)(eb + (oy + ky1) * 72 + (ox + kx1) * 8);
                    f32x4 acc = {0.f, 0.f, 0.f, 0.f};
                    acc = __builtin_amdgcn_mfma_f32_16x16x32_bf16(a, c1hi, acc, 0, 0, 0);
                    acc = __builtin_amdgcn_mfma_f32_16x16x32_bf16(a, c1lo, acc, 0, 0, 0);
                    float x0 = fmaxf(acc[0] + c1b, 0.f);
                    float x1 = fmaxf(acc[1] + c1b, 0.f);
                    float x2 = fmaxf(acc[2] + c1b, 0.f);
                    float x3 = fmaxf(acc[3] + c1b, 0.f);
                    float y0 = fmaxf(x0, x1);
                    float y1 = fmaxf(x2, x3);
                    float m0 = fmaxf(y0, __shfl_xor(y0, 32, 64));
                    float m1 = fmaxf(y1, __shfl_xor(y1, 32, 64));
                    if (wr1) {
                        op[(mt * 4 + kg * 2 + 0) * 16 + col] = f2bf(m0);
                        op[(mt * 4 + kg * 2 + 1) * 16 + col] = f2bf(m1);
                    }
                }
            }
            // ---- dir/pos scan: 16-lane group (kg-group? no: group=kg) per elem ----
            {
                int le = wv * 4 + kg;              // 4 groups of 16 lanes (key = col)
                const u16* eb = frL + le * 656;
                int best = 49;
                #pragma unroll
                for (int q2 = 0; q2 < 4; ++q2) {
                    int cell = col + q2 * 16;
                    if (cell < 49) {
                        int y = cell / 7, x = cell - y * 7;
                        u16 v = eb[(y + 1) * 72 + (x + 1) * 8];
                        if (v == (u16)0x4120 && cell < best) best = cell;  // bf16(10.0)
                    }
                }
                best = min(best, __shfl_xor(best, 1, 64));
                best = min(best, __shfl_xor(best, 2, 64));
                best = min(best, __shfl_xor(best, 4, 64));
                best = min(best, __shfl_xor(best, 8, 64));
                if (col == 0) {
                    float dd = 0.f, py = 0.5f, px = 0.5f;
                    if (best < 49) {
                        int y = best / 7, x = best - y * 7;
                        u16 c2 = eb[(y + 1) * 72 + (x + 1) * 8 + 2];
                        dd = (float)(((int)bf2f(c2)) & 3);
                        py = (float)y / 6.0f;
                        px = (float)x / 6.0f;
                    }
                    fdir[e0 + h * 16 + le] = make_float4(dd, py, px, 0.f);
                }
            }
        }
    }
    __syncthreads();

    // ---- phase B: conv2+relu+pool (8 elems/wave) ----
    {
        bf16x8 bfrag[2][2];
        #pragma unroll
        for (int s = 0; s < 2; ++s)
            #pragma unroll
            for (int nt = 0; nt < 2; ++nt)
                bfrag[s][nt] = *(const bf16x8*)(w2r + (nt * 16 + col) * 64 + s * 32 + kg * 8);
        float bias2[2] = { b2[col], b2[16 + col] };
        int oy = col >> 2, ox = col & 3;
        int aoff[2]; bool aok[2];
        #pragma unroll
        for (int s = 0; s < 2; ++s) {
            int tap = 2 * s + (kg >> 1);
            int ky = tap >> 1, kx = tap & 1;
            int iy = oy - 1 + ky, ix = ox - 1 + kx;
            aok[s] = (iy >= 0 && ix >= 0);
            aoff[s] = (iy * 4 + ix) * 16 + (kg & 1) * 8;
        }
        #pragma unroll
        for (int q = 0; q < 8; ++q) {
            int e = wv * 8 + q;
            const u16* pbase = p1L + e * 256;
            bf16x8 a0 = {0,0,0,0,0,0,0,0}, a1 = {0,0,0,0,0,0,0,0};
            if (aok[0]) a0 = *(const bf16x8*)(pbase + aoff[0]);
            if (aok[1]) a1 = *(const bf16x8*)(pbase + aoff[1]);
            f32x4 acc0 = {0.f,0.f,0.f,0.f}, acc1 = {0.f,0.f,0.f,0.f};
            acc0 = __builtin_amdgcn_mfma_f32_16x16x32_bf16(a0, bfrag[0][0], acc0, 0, 0, 0);
            acc1 = __builtin_amdgcn_mfma_f32_16x16x32_bf16(a0, bfrag[0][1], acc1, 0, 0, 0);
            acc0 = __builtin_amdgcn_mfma_f32_16x16x32_bf16(a1, bfrag[1][0], acc0, 0, 0, 0);
            acc1 = __builtin_amdgcn_mfma_f32_16x16x32_bf16(a1, bfrag[1][1], acc1, 0, 0, 0);
            #pragma unroll
            for (int nt = 0; nt < 2; ++nt) {
                f32x4 acc = nt ? acc1 : acc0;
                float b = bias2[nt];
                float m0 = fmaxf(fmaxf(acc[0] + b, 0.f), fmaxf(acc[1] + b, 0.f));
                float m1 = fmaxf(fmaxf(acc[2] + b, 0.f), fmaxf(acc[3] + b, 0.f));
                float p0 = fmaxf(m0, __shfl_xor(m0, 16, 64));
                float p1 = fmaxf(m1, __shfl_xor(m1, 16, 64));
                if ((kg & 1) == 0) {
                    int qq = (kg >> 1) * 2;
                    u16* op = p2L + e * 128 + nt * 16 + col;
                    op[qq * 32]       = f2bf(p0);
                    op[(qq + 1) * 32] = f2bf(p1);
                }
            }
        }
    }
    __syncthreads();   // p1L dead; featL (overlay) writable

    int colhi = col >> 3, collo = col & 7;
    // ---- phase C: conv3 (18 tiles; 4/wave + extra for wv<2) ----
    {
        bf16x8 bfrag[4][4];
        #pragma unroll
        for (int s = 0; s < 4; ++s)
            #pragma unroll
            for (int nt = 0; nt < 4; ++nt)
                bfrag[s][nt] = *(const bf16x8*)(w3r + (nt * 16 + col) * 128 + s * 32 + kg * 8);
        float bias[4];
        #pragma unroll
        for (int nt = 0; nt < 4; ++nt) bias[nt] = b3[nt * 16 + col];

        auto do_tile = [&](int i) {
            int m0 = i * 16;
            int m = m0 + col;
            u32 elem = (u32)(((unsigned long long)(u32)m * 954437177ull) >> 33); // m/9
            int p = m - (int)elem * 9;
            int oy = (p * 86) >> 8;
            int ox = p - 3 * oy;
            const u16* pbase = p2L + elem * 128 + kg * 8;
            f32x4 acc[4];
            #pragma unroll
            for (int nt = 0; nt < 4; ++nt) {
                acc[nt][0] = 0.f; acc[nt][1] = 0.f; acc[nt][2] = 0.f; acc[nt][3] = 0.f;
            }
            #pragma unroll
            for (int s = 0; s < 4; ++s) {
                int ky = s >> 1, kx = s & 1;
                int iy = oy - 1 + ky, ix = ox - 1 + kx;
                bf16x8 a = {0,0,0,0,0,0,0,0};
                if (iy >= 0 && iy <= 1 && ix >= 0 && ix <= 1)
                    a = *(const bf16x8*)(pbase + (iy * 2 + ix) * 32);
                #pragma unroll
                for (int nt = 0; nt < 4; ++nt)
                    acc[nt] = __builtin_amdgcn_mfma_f32_16x16x32_bf16(a, bfrag[s][nt], acc[nt], 0, 0, 0);
            }
            #pragma unroll
            for (int r = 0; r < 4; ++r) {
                int mr = m0 + kg * 4 + r;
                u32 er = (u32)(((unsigned long long)(u32)mr * 954437177ull) >> 33);
                int pr = mr - (int)er * 9;
                int e7 = (int)(er & 7u);
                u16* fb = featL + er * 640 + collo;
                #pragma unroll
                for (int nt = 0; nt < 4; ++nt) {
                    int blk = (pr * 8 + nt * 2 + colhi) ^ e7;
                    fb[blk * 8] = f2bf(fmaxf(acc[nt][r] + bias[nt], 0.f));
                }
            }
        };
        #pragma unroll
        for (int u = 0; u < 4; ++u) do_tile(wv + u * 4);
        if (wv < 2) do_tile(16 + wv);
    }
    if (t < 32) {
        union { u16 s[8]; uint4 q; } b;
        b.s[0] = f2bf((float)ccol[e0 + t]);
        b.s[1] = f2bf((float)cobj[e0 + t]);
        #pragma unroll
        for (int i = 2; i < 8; ++i) b.s[i] = 0;
        *(uint4*)(featL + t * 640 + (72 ^ (t & 7)) * 8) = b.q;
    }
    __syncthreads();

    // ---- phase D: proj; wave = (row-half rh, n-half nh) ----
    int rh = wv & 1, nh = wv >> 1;
    int m0g = e0 + rh * 16;
    const u16* arowb = featL + (rh * 16 + col) * 640;
    int rx = col & 7;
    const u16* brow = pwT + (nh * 32 + col) * 608 + kg * 8;
    f32x4 acc0 = {0.f,0.f,0.f,0.f}, acc1 = {0.f,0.f,0.f,0.f};
    #pragma unroll
    for (int k0 = 0; k0 < 608; k0 += 32) {
        bf16x8 a;
        if (k0 + kg * 8 < 584) {
            int L = (k0 >> 3) + kg;
            a = *(const bf16x8*)(arowb + (L ^ rx) * 8);
        } else {
            #pragma unroll
            for (int j = 0; j < 8; ++j) a[j] = 0;
        }
        bf16x8 b0 = *(const bf16x8*)(brow + k0);
        bf16x8 b1 = *(const bf16x8*)(brow + 16 * 608 + k0);
        acc0 = __builtin_amdgcn_mfma_f32_16x16x32_bf16(a, b0, acc0, 0, 0, 0);
        acc1 = __builtin_amdgcn_mfma_f32_16x16x32_bf16(a, b1, acc1, 0, 0, 0);
    }
    float* outbase = (m0g < BATCH) ? (comb + (size_t)m0g * 128)
                                   : (comb + (size_t)(m0g - BATCH) * 128 + 64);
    #pragma unroll
    for (int nt = 0; nt < 2; ++nt) {
        int n = nh * 32 + nt * 16 + col;
        float pbv = pb[n];
        f32x4 acc = nt ? acc1 : acc0;
        #pragma unroll
        for (int r = 0; r < 4; ++r) {
            outbase[(kg * 4 + r) * 128 + n] = fmaxf(acc[r] + pbv, 0.f);
        }
    }
}

__device__ __forceinline__ void split8(const float* __restrict__ x,
                                       bf16x8& hi, bf16x8& lo) {
    #pragma unroll
    for (int j = 0; j < 8; ++j) {
        u16 h = f2bf(x[j]);
        hi[j] = (short)h;
        lo[j] = (short)f2bf(x[j] - bf2f(h));
    }
}

// ---------------- KM: fused h1 GEMM -> LN -> h2 GEMM -> h3 -------------
// comb is [b][128]; extras (cols 128..131) synthesized from fdir pairs
// (identical arithmetic to the old k5: same delta/sinf/cosf/pos-deltas).
__global__ __launch_bounds__(256) void kmlp(const float* __restrict__ comb,
        const float4* __restrict__ fdir,
        const u16* __restrict__ h1hi, const u16* __restrict__ h1lo,
        const float* __restrict__ h1b,
        const float* __restrict__ lng, const float* __restrict__ lnb,
        const u16* __restrict__ h2hi, const u16* __restrict__ h2lo,
        const float* __restrict__ h2b,
        const float* __restrict__ h3w, const float* __restrict__ h3b,
        float* __restrict__ out) {
    __shared__ float hL[64 * 132];
    int t = threadIdx.x;
    int l = t & 63;
    int col = l & 15;
    int kg = l >> 4;
    int wv = t >> 6;
    int mb = blockIdx.x * 64;

    // ---- phase 1: h1 GEMM, epilogue -> hL ----
    {
        int gb = mb + wv * 16 + col;
        const float* arow = comb + (size_t)gb * 128 + kg * 8;
        const u16* bh = h1hi + col * 160 + kg * 8;
        const u16* bl = h1lo + col * 160 + kg * 8;
        f32x4 acc[8];
        #pragma unroll
        for (int nt = 0; nt < 8; ++nt) {
            acc[nt][0] = 0.f; acc[nt][1] = 0.f; acc[nt][2] = 0.f; acc[nt][3] = 0.f;
        }
        #pragma unroll
        for (int s = 0; s < 5; ++s) {
            float x[8];
            if (s < 4) {
                #pragma unroll
                for (int j = 0; j < 8; ++j) x[j] = arow[s * 32 + j];
            } else {
                #pragma unroll
                for (int j = 0; j < 8; ++j) x[j] = 0.f;
                if (kg == 0) {
                    float4 f0 = fdir[gb];
                    float4 f1 = fdir[gb + BATCH];
                    int delta = (((int)f1.x) - ((int)f0.x) + 4) & 3;
                    const float ANG = (float)(2.0 * 3.14159 / 4.0);
                    float angle = (float)delta * ANG;
                    x[0] = sinf(angle);
                    x[1] = cosf(angle);
                    x[2] = f1.y - f0.y;
                    x[3] = f1.z - f0.z;
                }
            }
            bf16x8 ahi, alo;
            split8(x, ahi, alo);
            #pragma unroll
            for (int nt = 0; nt < 8; ++nt) {
                bf16x8 bhiF = *(const bf16x8*)(bh + nt * 2560 + s * 32);
                bf16x8 bloF = *(const bf16x8*)(bl + nt * 2560 + s * 32);
                acc[nt] = __builtin_amdgcn_mfma_f32_16x16x32_bf16(ahi, bhiF, acc[nt], 0, 0, 0);
                acc[nt] = __builtin_amdgcn_mfma_f32_16x16x32_bf16(alo, bhiF, acc[nt], 0, 0, 0);
                acc[nt] = __builtin_amdgcn_mfma_f32_16x16x32_bf16(ahi, bloF, acc[nt], 0, 0, 0);
            }
        }
        #pragma unroll
        for (int nt = 0; nt < 8; ++nt) {
            float bv = h1b[nt * 16 + col];
            #pragma unroll
            for (int r = 0; r < 4; ++r)
                hL[(wv * 16 + kg * 4 + r) * 132 + nt * 16 + col] = acc[nt][r] + bv;
        }
    }
    __syncthreads();

    // ---- phase 2: LN + relu in place (wave's 16 rows) ----
    for (int rr = 0; rr < 16; ++rr) {
        float* rp = hL + (wv * 16 + rr) * 132 + l * 2;
        float2 v = *(const float2*)rp;
        float s = v.x + v.y;
        s += __shfl_xor(s, 1, 64);
        s += __shfl_xor(s, 2, 64);
        s += __shfl_xor(s, 4, 64);
        s += __shfl_xor(s, 8, 64);
        s += __shfl_xor(s, 16, 64);
        s += __shfl_xor(s, 32, 64);
        float mu = s * (1.0f / 128.0f);
        float d0 = v.x - mu, d1 = v.y - mu;
        float vs = d0 * d0 + d1 * d1;
        vs += __shfl_xor(vs, 1, 64);
        vs += __shfl_xor(vs, 2, 64);
        vs += __shfl_xor(vs, 4, 64);
        vs += __shfl_xor(vs, 8, 64);
        vs += __shfl_xor(vs, 16, 64);
        vs += __shfl_xor(vs, 32, 64);
        float rs = rsqrtf(vs * (1.0f / 128.0f) + 1e-5f);
        float2 o;
        o.x = fmaxf(d0 * rs * lng[l * 2]     + lnb[l * 2],     0.f);
        o.y = fmaxf(d1 * rs * lng[l * 2 + 1] + lnb[l * 2 + 1], 0.f);
        *(float2*)rp = o;
    }
    __syncthreads();

    // ---- phase 3: h2 GEMM, A from hL, in-place epilogue ----
    {
        const float* arow = hL + (wv * 16 + col) * 132 + kg * 8;
        const u16* bh = h2hi + col * 128 + kg * 8;
        const u16* bl = h2lo + col * 128 + kg * 8;
        f32x4 acc[8];
        #pragma unroll
        for (int nt = 0; nt < 8; ++nt) {
            acc[nt][0] = 0.f; acc[nt][1] = 0.f; acc[nt][2] = 0.f; acc[nt][3] = 0.f;
        }
        #pragma unroll
        for (int s = 0; s < 4; ++s) {
            float x[8];
            #pragma unroll
            for (int j = 0; j < 8; ++j) x[j] = arow[s * 32 + j];
            bf16x8 ahi, alo;
            split8(x, ahi, alo);
            #pragma unroll
            for (int nt = 0; nt < 8; ++nt) {
                bf16x8 bhiF = *(const bf16x8*)(bh + nt * 2048 + s * 32);
                bf16x8 bloF = *(const bf16x8*)(bl + nt * 2048 + s * 32);
                acc[nt] = __builtin_amdgcn_mfma_f32_16x16x32_bf16(ahi, bhiF, acc[nt], 0, 0, 0);
                acc[nt] = __builtin_amdgcn_mfma_f32_16x16x32_bf16(alo, bhiF, acc[nt], 0, 0, 0);
                acc[nt] = __builtin_amdgcn_mfma_f32_16x16x32_bf16(ahi, bloF, acc[nt], 0, 0, 0);
            }
        }
        __syncthreads();
        #pragma unroll
        for (int nt = 0; nt < 8; ++nt) {
            float bv = h2b[nt * 16 + col];
            #pragma unroll
            for (int r = 0; r < 4; ++r)
                hL[(wv * 16 + kg * 4 + r) * 132 + nt * 16 + col] = fmaxf(acc[nt][r] + bv, 0.f);
        }
    }
    __syncthreads();

    // ---- phase 4: h3; thread = (row, j-pair) ----
    {
        int row = t >> 2, jq = t & 3, j0 = jq * 2;
        const float* rp = hL + row * 132;
        float a0 = h3b[j0];
        float a1 = (jq < 3) ? h3b[j0 + 1] : 0.f;
        #pragma unroll 4
        for (int c = 0; c < 32; ++c) {
            float4 v = *(const float4*)(rp + c * 4);
            const float* wr0 = h3w + j0 * 128 + c * 4;
            a0 += v.x * wr0[0];
            a0 += v.y * wr0[1];
            a0 += v.z * wr0[2];
            a0 += v.w * wr0[3];
            if (jq < 3) {
                const float* wr1 = h3w + (j0 + 1) * 128 + c * 4;
                a1 += v.x * wr1[0];
                a1 += v.y * wr1[1];
                a1 += v.z * wr1[2];
                a1 += v.w * wr1[3];
            }
        }
        float* ob = out + (size_t)(mb + row) * 7;
        ob[j0] = a0;
        if (jq < 3) ob[j0 + 1] = a1;
    }
}

extern "C" void kernel_launch(void* const* d_in, const int* in_sizes, int n_in,
                              void* d_out, int out_size, void* d_ws, size_t ws_size,
                              hipStream_t stream) {
    const int*   frame = (const int*)d_in[0];
    const int*   ccol  = (const int*)d_in[1];
    const int*   cobj  = (const int*)d_in[2];
    const float* w1    = (const float*)d_in[3];
    const float* b1    = (const float*)d_in[4];
    const float* w2    = (const float*)d_in[5];
    const float* b2    = (const float*)d_in[6];
    const float* w3    = (const float*)d_in[7];
    const float* b3    = (const float*)d_in[8];
    const float* pw    = (const float*)d_in[9];
    const float* pb    = (const float*)d_in[10];
    const float* h1w   = (const float*)d_in[11];
    const float* h1b   = (const float*)d_in[12];
    const float* lng   = (const float*)d_in[13];
    const float* lnb   = (const float*)d_in[14];
    const float* h2w   = (const float*)d_in[15];
    const float* h2b   = (const float*)d_in[16];
    const float* h3w   = (const float*)d_in[17];
    const float* h3b   = (const float*)d_in[18];
    float* out = (float*)d_out;

    char* ws = (char*)d_ws;
    float* comb     = (float*)(ws + 0);                  // 16.8 MB
    float4* fdir    = (float4*)(ws + 33554432);          // 1 MB
    u16*   pwT      = (u16*)(ws + 132120576);            // 77824 B
    u16*   w2r      = (u16*)(ws + 132120576 + 131072);   // 4096 B
    u16*   w3r      = (u16*)(ws + 132120576 + 139264);   // 16384 B
    u16*   h2hi     = (u16*)(ws + 132120576 + 163840);   // 32768 B
    u16*   h2lo     = (u16*)(ws + 132120576 + 196608);   // 32768 B
    u16*   h1hi     = (u16*)(ws + 132120576 + 229376);   // 40960 B
    u16*   h1lo     = (u16*)(ws + 132120576 + 270336);   // 40960 B
    u16*   w1hi     = (u16*)(ws + 132120576 + 311296);   // 1024 B
    u16*   w1lo     = (u16*)(ws + 132120576 + 312320);   // 1024 B

    k0_prep<<<340, 256, 0, stream>>>(pw, w2, w3, h2w, h1w, w1,
                                     pwT, w2r, w3r, h2hi, h2lo, h1hi, h1lo,
                                     w1hi, w1lo);
    kconv_all<<<2048, 256, 0, stream>>>(frame, w1hi, w1lo, b1, w2r, b2,
                                        w3r, b3, ccol, cobj, pwT, pb, comb, fdir);
    kmlp<<<512, 256, 0, stream>>>(comb, fdir, h1hi, h1lo, h1b, lng, lnb,
                                  h2hi, h2lo, h2b, h3w, h3b, out);
}

// Round 22
// 219.750 us; speedup vs baseline: 1.4060x; 1.0510x over previous
//
#include <hip/hip_runtime.h>
#include <hip/hip_bf16.h>

#define BATCH 32768
#define NELEM 65536   // 2 * BATCH

typedef unsigned short u16;
typedef unsigned int u32;
typedef __attribute__((ext_vector_type(8))) short bf16x8;
typedef __attribute__((ext_vector_type(4))) float f32x4;

__device__ __forceinline__ float bf2f(u16 u) {
    union { u32 u; float f; } c; c.u = ((u32)u) << 16; return c.f;
}
__device__ __forceinline__ u16 f2bf(float f) {
    union { float f; u32 u; } c; c.f = f;
    u32 x = c.u;
    u32 r = (x + 0x7fffu + ((x >> 16) & 1u)) >> 16;  // RNE
    return (u16)r;
}

// ---------------- K0: weight prep ---------------------------------------
__global__ __launch_bounds__(256) void k0_prep(const float* __restrict__ pw,
        const float* __restrict__ w2, const float* __restrict__ w3,
        const float* __restrict__ h2w, const float* __restrict__ h1w,
        const float* __restrict__ w1,
        u16* __restrict__ pwT, u16* __restrict__ w2r, u16* __restrict__ w3r,
        u16* __restrict__ h2hi, u16* __restrict__ h2lo,
        u16* __restrict__ h1hi, u16* __restrict__ h1lo,
        u16* __restrict__ w1hi, u16* __restrict__ w1lo) {
    int idx = blockIdx.x * 256 + threadIdx.x;
    if (idx < 38912) {
        int j = idx / 608, kk = idx - j * 608;
        float v = 0.f;
        if (kk < 576) {
            int p = kk >> 6, oc = kk & 63;
            v = pw[j * 578 + oc * 9 + p];
        } else if (kk < 578) {
            v = pw[j * 578 + kk];
        }
        pwT[idx] = f2bf(v);
    } else if (idx < 40960) {
        int i = idx - 38912;
        int oc = i >> 6, rem = i & 63, tap = rem >> 4, ic = rem & 15;
        w2r[i] = f2bf(w2[oc * 64 + ic * 4 + tap]);
    } else if (idx < 49152) {
        int i = idx - 40960;
        int oc = i >> 7, rem = i & 127, tap = rem >> 5, ic = rem & 31;
        w3r[i] = f2bf(w3[oc * 128 + ic * 4 + tap]);
    } else if (idx < 65536) {
        int i = idx - 49152;
        float v = h2w[i];
        u16 hi = f2bf(v);
        h2hi[i] = hi;
        h2lo[i] = f2bf(v - bf2f(hi));
    } else if (idx < 86016) {
        int i = idx - 65536;
        int j = i / 160, k = i - j * 160;
        float v = (k < 132) ? h1w[j * 132 + k] : 0.f;
        u16 hi = f2bf(v);
        h1hi[i] = hi;
        h1lo[i] = f2bf(v - bf2f(hi));
    } else if (idx < 86528) {
        int i = idx - 86016;               // [oc16][k32]
        int oc = i >> 5, k = i & 31;
        int ky = k >> 4, kx = (k >> 3) & 1, c = k & 7;
        float v = (c < 3) ? w1[oc * 12 + c * 4 + ky * 2 + kx] : 0.f;
        u16 hi = f2bf(v);
        w1hi[i] = hi;
        w1lo[i] = f2bf(v - bf2f(hi));
    }
}

__device__ __forceinline__ void split8(const float* __restrict__ x,
                                       bf16x8& hi, bf16x8& lo) {
    #pragma unroll
    for (int j = 0; j < 8; ++j) {
        u16 h = f2bf(x[j]);
        hi[j] = (short)h;
        lo[j] = (short)f2bf(x[j] - bf2f(h));
    }
}

// ---------------- KALL: whole network, one block = 16 batch rows --------
// Elems: local 0..15 = curr (b0+i), 16..31 = next (b0+BATCH+i). Conv
// phases A-D are the validated kconv_all bodies; proj writes combL in
// LDS; then MLP phases (validated kmlp bodies) finish the 16 rows.
// LDS overlays: combL over dead p2L; hL over dead featL.
__global__ __launch_bounds__(256) void kall(const int* __restrict__ frame,
        const u16* __restrict__ w1hi, const u16* __restrict__ w1lo,
        const float* __restrict__ b1,
        const u16* __restrict__ w2r, const float* __restrict__ b2,
        const u16* __restrict__ w3r, const float* __restrict__ b3,
        const int* __restrict__ ccol, const int* __restrict__ cobj,
        const u16* __restrict__ pwT, const float* __restrict__ pb,
        const u16* __restrict__ h1hi, const u16* __restrict__ h1lo,
        const float* __restrict__ h1b,
        const float* __restrict__ lng, const float* __restrict__ lnb,
        const u16* __restrict__ h2hi, const u16* __restrict__ h2lo,
        const float* __restrict__ h2b,
        const float* __restrict__ h3w, const float* __restrict__ h3b,
        float* __restrict__ out) {
    __shared__ u16 lds[24576];     // 49152 B
    __shared__ float4 fdirL[32];   // 512 B
    u16* p2L   = lds;              // [0,4096)
    u16* p1L   = lds + 4096;       // [4096,12288)
    u16* frL   = lds + 12288;      // 16*656 ends 22784
    u16* featL = lds + 4096;       // [4096,24576) overlay
    float* combL = (float*)lds;            // 16*128 floats = 4096 u16 (over p2L)
    float* hL    = (float*)(lds + 4096);   // 16*132 floats = 8448 u16 (over featL)
    int t = threadIdx.x;
    int l = t & 63;
    int wv = t >> 6;
    int col = l & 15;
    int kg = l >> 4;
    int b0 = blockIdx.x * 16;

    #pragma unroll
    for (int i = 0; i < 6; ++i) {
        int o = i * 256 + t;
        if (o < 1312) *(uint4*)(frL + o * 8) = make_uint4(0u, 0u, 0u, 0u);
    }

    // ---- phase A: conv1+relu+pool (h=0 curr, h=1 next) + dir scan ----
    {
        bf16x8 c1hi = *(const bf16x8*)(w1hi + col * 32 + kg * 8);
        bf16x8 c1lo = *(const bf16x8*)(w1lo + col * 32 + kg * 8);
        float c1b = b1[col];
        int ky1 = kg >> 1, kx1 = kg & 1;
        bool wr1 = (kg < 2);
        for (int h = 0; h < 2; ++h) {
            __syncthreads();
            const int* fbase = frame + ((size_t)b0 + (size_t)h * BATCH) * 147;
            #pragma unroll
            for (int i = 0; i < 10; ++i) {
                int idx = i * 256 + t;
                if (idx < 2352) {
                    int le = idx / 147, r = idx - le * 147;
                    int cell = r / 3, c = r - cell * 3;
                    int y = cell / 7, x = cell - y * 7;
                    frL[le * 656 + (y + 1) * 72 + (x + 1) * 8 + c] = f2bf((float)fbase[idx]);
                }
            }
            __syncthreads();
            #pragma unroll
            for (int q = 0; q < 4; ++q) {
                int le = wv * 4 + q;
                const u16* eb = frL + le * 656;
                u16* op = p1L + (h * 16 + le) * 256;
                #pragma unroll
                for (int mt = 0; mt < 4; ++mt) {
                    int posA = mt * 16 + col;
                    int oy = posA >> 3, ox = posA & 7;
                    bf16x8 a = *(const bf16x8*)(eb + (oy + ky1) * 72 + (ox + kx1) * 8);
                    f32x4 acc = {0.f, 0.f, 0.f, 0.f};
                    acc = __builtin_amdgcn_mfma_f32_16x16x32_bf16(a, c1hi, acc, 0, 0, 0);
                    acc = __builtin_amdgcn_mfma_f32_16x16x32_bf16(a, c1lo, acc, 0, 0, 0);
                    float x0 = fmaxf(acc[0] + c1b, 0.f);
                    float x1 = fmaxf(acc[1] + c1b, 0.f);
                    float x2 = fmaxf(acc[2] + c1b, 0.f);
                    float x3 = fmaxf(acc[3] + c1b, 0.f);
                    float y0 = fmaxf(x0, x1);
                    float y1 = fmaxf(x2, x3);
                    float m0 = fmaxf(y0, __shfl_xor(y0, 32, 64));
                    float m1 = fmaxf(y1, __shfl_xor(y1, 32, 64));
                    if (wr1) {
                        op[(mt * 4 + kg * 2 + 0) * 16 + col] = f2bf(m0);
                        op[(mt * 4 + kg * 2 + 1) * 16 + col] = f2bf(m1);
                    }
                }
            }
            // ---- dir/pos scan (16-lane group per elem) ----
            {
                int le = wv * 4 + kg;
                const u16* eb = frL + le * 656;
                int best = 49;
                #pragma unroll
                for (int q2 = 0; q2 < 4; ++q2) {
                    int cell = col + q2 * 16;
                    if (cell < 49) {
                        int y = cell / 7, x = cell - y * 7;
                        u16 v = eb[(y + 1) * 72 + (x + 1) * 8];
                        if (v == (u16)0x4120 && cell < best) best = cell;  // bf16(10.0)
                    }
                }
                best = min(best, __shfl_xor(best, 1, 64));
                best = min(best, __shfl_xor(best, 2, 64));
                best = min(best, __shfl_xor(best, 4, 64));
                best = min(best, __shfl_xor(best, 8, 64));
                if (col == 0) {
                    float dd = 0.f, py = 0.5f, px = 0.5f;
                    if (best < 49) {
                        int y = best / 7, x = best - y * 7;
                        u16 c2 = eb[(y + 1) * 72 + (x + 1) * 8 + 2];
                        dd = (float)(((int)bf2f(c2)) & 3);
                        py = (float)y / 6.0f;
                        px = (float)x / 6.0f;
                    }
                    fdirL[h * 16 + le] = make_float4(dd, py, px, 0.f);
                }
            }
        }
    }
    __syncthreads();

    // ---- phase B: conv2+relu+pool (8 elems/wave) ----
    {
        bf16x8 bfrag[2][2];
        #pragma unroll
        for (int s = 0; s < 2; ++s)
            #pragma unroll
            for (int nt = 0; nt < 2; ++nt)
                bfrag[s][nt] = *(const bf16x8*)(w2r + (nt * 16 + col) * 64 + s * 32 + kg * 8);
        float bias2[2] = { b2[col], b2[16 + col] };
        int oy = col >> 2, ox = col & 3;
        int aoff[2]; bool aok[2];
        #pragma unroll
        for (int s = 0; s < 2; ++s) {
            int tap = 2 * s + (kg >> 1);
            int ky = tap >> 1, kx = tap & 1;
            int iy = oy - 1 + ky, ix = ox - 1 + kx;
            aok[s] = (iy >= 0 && ix >= 0);
            aoff[s] = (iy * 4 + ix) * 16 + (kg & 1) * 8;
        }
        #pragma unroll
        for (int q = 0; q < 8; ++q) {
            int e = wv * 8 + q;
            const u16* pbase = p1L + e * 256;
            bf16x8 a0 = {0,0,0,0,0,0,0,0}, a1 = {0,0,0,0,0,0,0,0};
            if (aok[0]) a0 = *(const bf16x8*)(pbase + aoff[0]);
            if (aok[1]) a1 = *(const bf16x8*)(pbase + aoff[1]);
            f32x4 acc0 = {0.f,0.f,0.f,0.f}, acc1 = {0.f,0.f,0.f,0.f};
            acc0 = __builtin_amdgcn_mfma_f32_16x16x32_bf16(a0, bfrag[0][0], acc0, 0, 0, 0);
            acc1 = __builtin_amdgcn_mfma_f32_16x16x32_bf16(a0, bfrag[0][1], acc1, 0, 0, 0);
            acc0 = __builtin_amdgcn_mfma_f32_16x16x32_bf16(a1, bfrag[1][0], acc0, 0, 0, 0);
            acc1 = __builtin_amdgcn_mfma_f32_16x16x32_bf16(a1, bfrag[1][1], acc1, 0, 0, 0);
            #pragma unroll
            for (int nt = 0; nt < 2; ++nt) {
                f32x4 acc = nt ? acc1 : acc0;
                float b = bias2[nt];
                float m0 = fmaxf(fmaxf(acc[0] + b, 0.f), fmaxf(acc[1] + b, 0.f));
                float m1 = fmaxf(fmaxf(acc[2] + b, 0.f), fmaxf(acc[3] + b, 0.f));
                float p0 = fmaxf(m0, __shfl_xor(m0, 16, 64));
                float p1 = fmaxf(m1, __shfl_xor(m1, 16, 64));
                if ((kg & 1) == 0) {
                    int qq = (kg >> 1) * 2;
                    u16* op = p2L + e * 128 + nt * 16 + col;
                    op[qq * 32]       = f2bf(p0);
                    op[(qq + 1) * 32] = f2bf(p1);
                }
            }
        }
    }
    __syncthreads();   // p1L dead; featL writable

    int colhi = col >> 3, collo = col & 7;
    // ---- phase C: conv3 (18 tiles; 4/wave + extra for wv<2) ----
    {
        bf16x8 bfrag[4][4];
        #pragma unroll
        for (int s = 0; s < 4; ++s)
            #pragma unroll
            for (int nt = 0; nt < 4; ++nt)
                bfrag[s][nt] = *(const bf16x8*)(w3r + (nt * 16 + col) * 128 + s * 32 + kg * 8);
        float bias[4];
        #pragma unroll
        for (int nt = 0; nt < 4; ++nt) bias[nt] = b3[nt * 16 + col];

        auto do_tile = [&](int i) {
            int m0 = i * 16;
            int m = m0 + col;
            u32 elem = (u32)(((unsigned long long)(u32)m * 954437177ull) >> 33); // m/9
            int p = m - (int)elem * 9;
            int oy = (p * 86) >> 8;
            int ox = p - 3 * oy;
            const u16* pbase = p2L + elem * 128 + kg * 8;
            f32x4 acc[4];
            #pragma unroll
            for (int nt = 0; nt < 4; ++nt) {
                acc[nt][0] = 0.f; acc[nt][1] = 0.f; acc[nt][2] = 0.f; acc[nt][3] = 0.f;
            }
            #pragma unroll
            for (int s = 0; s < 4; ++s) {
                int ky = s >> 1, kx = s & 1;
                int iy = oy - 1 + ky, ix = ox - 1 + kx;
                bf16x8 a = {0,0,0,0,0,0,0,0};
                if (iy >= 0 && iy <= 1 && ix >= 0 && ix <= 1)
                    a = *(const bf16x8*)(pbase + (iy * 2 + ix) * 32);
                #pragma unroll
                for (int nt = 0; nt < 4; ++nt)
                    acc[nt] = __builtin_amdgcn_mfma_f32_16x16x32_bf16(a, bfrag[s][nt], acc[nt], 0, 0, 0);
            }
            #pragma unroll
            for (int r = 0; r < 4; ++r) {
                int mr = m0 + kg * 4 + r;
                u32 er = (u32)(((unsigned long long)(u32)mr * 954437177ull) >> 33);
                int pr = mr - (int)er * 9;
                int e7 = (int)(er & 7u);
                u16* fb = featL + er * 640 + collo;
                #pragma unroll
                for (int nt = 0; nt < 4; ++nt) {
                    int blk = (pr * 8 + nt * 2 + colhi) ^ e7;
                    fb[blk * 8] = f2bf(fmaxf(acc[nt][r] + bias[nt], 0.f));
                }
            }
        };
        #pragma unroll
        for (int u = 0; u < 4; ++u) do_tile(wv + u * 4);
        if (wv < 2) do_tile(16 + wv);
    }
    if (t < 32) {
        int g = b0 + (t >> 4) * BATCH + (t & 15);
        union { u16 s[8]; uint4 q; } b;
        b.s[0] = f2bf((float)ccol[g]);
        b.s[1] = f2bf((float)cobj[g]);
        #pragma unroll
        for (int i = 2; i < 8; ++i) b.s[i] = 0;
        *(uint4*)(featL + t * 640 + (72 ^ (t & 7)) * 8) = b.q;
    }
    __syncthreads();

    // ---- phase D: proj -> combL; wave = (row-half rh, n-half nh) ----
    {
        int rh = wv & 1, nh = wv >> 1;
        const u16* arowb = featL + (rh * 16 + col) * 640;
        int rx = col & 7;
        const u16* brow = pwT + (nh * 32 + col) * 608 + kg * 8;
        f32x4 acc0 = {0.f,0.f,0.f,0.f}, acc1 = {0.f,0.f,0.f,0.f};
        #pragma unroll
        for (int k0 = 0; k0 < 608; k0 += 32) {
            bf16x8 a;
            if (k0 + kg * 8 < 584) {
                int L = (k0 >> 3) + kg;
                a = *(const bf16x8*)(arowb + (L ^ rx) * 8);
            } else {
                #pragma unroll
                for (int j = 0; j < 8; ++j) a[j] = 0;
            }
            bf16x8 b0f = *(const bf16x8*)(brow + k0);
            bf16x8 b1f = *(const bf16x8*)(brow + 16 * 608 + k0);
            acc0 = __builtin_amdgcn_mfma_f32_16x16x32_bf16(a, b0f, acc0, 0, 0, 0);
            acc1 = __builtin_amdgcn_mfma_f32_16x16x32_bf16(a, b1f, acc1, 0, 0, 0);
        }
        __syncthreads();   // featL reads done everywhere before combL/hL writes
        #pragma unroll
        for (int nt = 0; nt < 2; ++nt) {
            int n = nh * 32 + nt * 16 + col;
            float pbv = pb[n];
            f32x4 acc = nt ? acc1 : acc0;
            #pragma unroll
            for (int r = 0; r < 4; ++r) {
                // local elem = rh*16 + kg*4 + r -> batch row kg*4+r, half rh
                combL[(kg * 4 + r) * 128 + rh * 64 + n] = fmaxf(acc[r] + pbv, 0.f);
            }
        }
    }
    __syncthreads();

    // ---- phase E: h1 GEMM (M=16); waves split N (2 n-tiles each) ----
    {
        const float* arow = combL + col * 128 + kg * 8;
        f32x4 acc[2];
        acc[0][0]=0.f; acc[0][1]=0.f; acc[0][2]=0.f; acc[0][3]=0.f;
        acc[1][0]=0.f; acc[1][1]=0.f; acc[1][2]=0.f; acc[1][3]=0.f;
        #pragma unroll
        for (int s = 0; s < 5; ++s) {
            float x[8];
            if (s < 4) {
                #pragma unroll
                for (int j = 0; j < 8; ++j) x[j] = arow[s * 32 + j];
            } else {
                #pragma unroll
                for (int j = 0; j < 8; ++j) x[j] = 0.f;
                if (kg == 0) {
                    float4 f0 = fdirL[col];
                    float4 f1 = fdirL[16 + col];
                    int delta = (((int)f1.x) - ((int)f0.x) + 4) & 3;
                    const float ANG = (float)(2.0 * 3.14159 / 4.0);
                    float angle = (float)delta * ANG;
                    x[0] = sinf(angle);
                    x[1] = cosf(angle);
                    x[2] = f1.y - f0.y;
                    x[3] = f1.z - f0.z;
                }
            }
            bf16x8 ahi, alo;
            split8(x, ahi, alo);
            #pragma unroll
            for (int nt = 0; nt < 2; ++nt) {
                int n0 = (wv * 2 + nt) * 16 + col;
                bf16x8 bhiF = *(const bf16x8*)(h1hi + n0 * 160 + s * 32 + kg * 8);
                bf16x8 bloF = *(const bf16x8*)(h1lo + n0 * 160 + s * 32 + kg * 8);
                acc[nt] = __builtin_amdgcn_mfma_f32_16x16x32_bf16(ahi, bhiF, acc[nt], 0, 0, 0);
                acc[nt] = __builtin_amdgcn_mfma_f32_16x16x32_bf16(alo, bhiF, acc[nt], 0, 0, 0);
                acc[nt] = __builtin_amdgcn_mfma_f32_16x16x32_bf16(ahi, bloF, acc[nt], 0, 0, 0);
            }
        }
        #pragma unroll
        for (int nt = 0; nt < 2; ++nt) {
            int n = (wv * 2 + nt) * 16 + col;
            float bv = h1b[n];
            #pragma unroll
            for (int r = 0; r < 4; ++r)
                hL[(kg * 4 + r) * 132 + n] = acc[nt][r] + bv;
        }
    }
    __syncthreads();

    // ---- phase F: LN + relu in place (4 rows/wave) ----
    #pragma unroll
    for (int rr = 0; rr < 4; ++rr) {
        float* rp = hL + (wv * 4 + rr) * 132 + l * 2;
        float2 v = *(const float2*)rp;
        float s = v.x + v.y;
        s += __shfl_xor(s, 1, 64);
        s += __shfl_xor(s, 2, 64);
        s += __shfl_xor(s, 4, 64);
        s += __shfl_xor(s, 8, 64);
        s += __shfl_xor(s, 16, 64);
        s += __shfl_xor(s, 32, 64);
        float mu = s * (1.0f / 128.0f);
        float d0 = v.x - mu, d1 = v.y - mu;
        float vs = d0 * d0 + d1 * d1;
        vs += __shfl_xor(vs, 1, 64);
        vs += __shfl_xor(vs, 2, 64);
        vs += __shfl_xor(vs, 4, 64);
        vs += __shfl_xor(vs, 8, 64);
        vs += __shfl_xor(vs, 16, 64);
        vs += __shfl_xor(vs, 32, 64);
        float rs = rsqrtf(vs * (1.0f / 128.0f) + 1e-5f);
        float2 o;
        o.x = fmaxf(d0 * rs * lng[l * 2]     + lnb[l * 2],     0.f);
        o.y = fmaxf(d1 * rs * lng[l * 2 + 1] + lnb[l * 2 + 1], 0.f);
        *(float2*)rp = o;
    }
    __syncthreads();

    // ---- phase G: h2 GEMM (M=16); waves split N; barrier pre-epilogue --
    {
        const float* arow = hL + col * 132 + kg * 8;
        f32x4 acc[2];
        acc[0][0]=0.f; acc[0][1]=0.f; acc[0][2]=0.f; acc[0][3]=0.f;
        acc[1][0]=0.f; acc[1][1]=0.f; acc[1][2]=0.f; acc[1][3]=0.f;
        #pragma unroll
        for (int s = 0; s < 4; ++s) {
            float x[8];
            #pragma unroll
            for (int j = 0; j < 8; ++j) x[j] = arow[s * 32 + j];
            bf16x8 ahi, alo;
            split8(x, ahi, alo);
            #pragma unroll
            for (int nt = 0; nt < 2; ++nt) {
                int n0 = (wv * 2 + nt) * 16 + col;
                bf16x8 bhiF = *(const bf16x8*)(h2hi + n0 * 128 + s * 32 + kg * 8);
                bf16x8 bloF = *(const bf16x8*)(h2lo + n0 * 128 + s * 32 + kg * 8);
                acc[nt] = __builtin_amdgcn_mfma_f32_16x16x32_bf16(ahi, bhiF, acc[nt], 0, 0, 0);
                acc[nt] = __builtin_amdgcn_mfma_f32_16x16x32_bf16(alo, bhiF, acc[nt], 0, 0, 0);
                acc[nt] = __builtin_amdgcn_mfma_f32_16x16x32_bf16(ahi, bloF, acc[nt], 0, 0, 0);
            }
        }
        __syncthreads();   // all A reads done before in-place writes
        #pragma unroll
        for (int nt = 0; nt < 2; ++nt) {
            int n = (wv * 2 + nt) * 16 + col;
            float bv = h2b[n];
            #pragma unroll
            for (int r = 0; r < 4; ++r)
                hL[(kg * 4 + r) * 132 + n] = fmaxf(acc[nt][r] + bv, 0.f);
        }
    }
    __syncthreads();

    // ---- phase H: h3; t<112: (row, j) ----
    if (t < 112) {
        int row = t / 7, j = t - row * 7;
        const float* rp = hL + row * 132;
        float a0 = h3b[j];
        const float* wr0 = h3w + j * 128;
        #pragma unroll 4
        for (int c = 0; c < 32; ++c) {
            float4 v = *(const float4*)(rp + c * 4);
            a0 += v.x * wr0[c * 4 + 0];
            a0 += v.y * wr0[c * 4 + 1];
            a0 += v.z * wr0[c * 4 + 2];
            a0 += v.w * wr0[c * 4 + 3];
        }
        out[(size_t)(b0 + row) * 7 + j] = a0;
    }
}

extern "C" void kernel_launch(void* const* d_in, const int* in_sizes, int n_in,
                              void* d_out, int out_size, void* d_ws, size_t ws_size,
                              hipStream_t stream) {
    const int*   frame = (const int*)d_in[0];
    const int*   ccol  = (const int*)d_in[1];
    const int*   cobj  = (const int*)d_in[2];
    const float* w1    = (const float*)d_in[3];
    const float* b1    = (const float*)d_in[4];
    const float* w2    = (const float*)d_in[5];
    const float* b2    = (const float*)d_in[6];
    const float* w3    = (const float*)d_in[7];
    const float* b3    = (const float*)d_in[8];
    const float* pw    = (const float*)d_in[9];
    const float* pb    = (const float*)d_in[10];
    const float* h1w   = (const float*)d_in[11];
    const float* h1b   = (const float*)d_in[12];
    const float* lng   = (const float*)d_in[13];
    const float* lnb   = (const float*)d_in[14];
    const float* h2w   = (const float*)d_in[15];
    const float* h2b   = (const float*)d_in[16];
    const float* h3w   = (const float*)d_in[17];
    const float* h3b   = (const float*)d_in[18];
    float* out = (float*)d_out;

    char* ws = (char*)d_ws;
    u16*   pwT      = (u16*)(ws + 0);                    // 77824 B
    u16*   w2r      = (u16*)(ws + 131072);               // 4096 B
    u16*   w3r      = (u16*)(ws + 139264);               // 16384 B
    u16*   h2hi     = (u16*)(ws + 163840);               // 32768 B
    u16*   h2lo     = (u16*)(ws + 196608);               // 32768 B
    u16*   h1hi     = (u16*)(ws + 229376);               // 40960 B
    u16*   h1lo     = (u16*)(ws + 270336);               // 40960 B
    u16*   w1hi     = (u16*)(ws + 311296);               // 1024 B
    u16*   w1lo     = (u16*)(ws + 312320);               // 1024 B

    k0_prep<<<340, 256, 0, stream>>>(pw, w2, w3, h2w, h1w, w1,
                                     pwT, w2r, w3r, h2hi, h2lo, h1hi, h1lo,
                                     w1hi, w1lo);
    kall<<<2048, 256, 0, stream>>>(frame, w1hi, w1lo, b1, w2r, b2,
                                   w3r, b3, ccol, cobj, pwT, pb,
                                   h1hi, h1lo, h1b, lng, lnb,
                                   h2hi, h2lo, h2b, h3w, h3b, out);
}